// Round 2
// baseline (5829.659 us; speedup 1.0000x reference)
//
#include <hip/hip_runtime.h>

namespace {

constexpr int Bn = 4;
constexpr int C  = 192;
constexpr int Wd = 128;
constexpr int HW = 16384;            // 128*128
constexpr int PLANE = Bn * C * HW;   // 12582912
constexpr int NH = 6;
constexpr int HD = 32;
constexpr int NWIN = 2048;           // 4 * 16 * 32
constexpr int C4 = 4 * C;            // 768
constexpr float SCALE = 0.17677669529663687f;  // 32^-0.5

// ---------------------------------------------------------------------------
// Stage 1: windowed complex attention + proj + residual -> y into d_out.
// One workgroup per window (256 threads). 132KB static LDS.
// ---------------------------------------------------------------------------
__global__ __launch_bounds__(256, 1) void k_attn(
    const float* __restrict__ xr, const float* __restrict__ xi,
    const float* __restrict__ wqkv_r, const float* __restrict__ wqkv_i,
    const float* __restrict__ wp_r, const float* __restrict__ wp_i,
    const float* __restrict__ rpb,
    float* __restrict__ yr, float* __restrict__ yi)
{
  __shared__ float sxr[6144], sxi[6144];   // x window [192][32]
  __shared__ float sor[6144], soi[6144];   // attn output [192][32]
  __shared__ float sqr[1056], sqi[1056];   // q [32][33] (padded stride)
  __shared__ float skr[1056], ski[1056];   // k
  __shared__ float svr[1056], svi[1056];   // v
  __shared__ float sar[1056], sai[1056];   // attn weights

  const int t = threadIdx.x;
  const int win = blockIdx.x;
  const int b = win >> 9;             // 512 windows per batch
  const int rem = win & 511;
  const int r0 = (rem >> 5) << 3;     // ih*8
  const int c0 = (rem & 31) << 2;     // iw*4
  const int gbase = b * C * HW + r0 * Wd + c0;

  // load x window: [c][n], n = wr*4 + wc
  for (int e = t; e < C * 32; e += 256) {
    const int c = e >> 5, n = e & 31;
    const int g = gbase + c * HW + (n >> 2) * Wd + (n & 3);
    sxr[e] = xr[g];
    sxi[e] = xi[g];
  }
  __syncthreads();

  const int d  = t >> 3;        // 0..31
  const int n4 = (t & 7) << 2;  // 0,4,...,28

  for (int h = 0; h < NH; ++h) {
    // ---- QKV for head h: tile [32 d][32 n], thread owns (d, n4..n4+3) ----
    float aqr[4] = {}, aqi[4] = {}, akr[4] = {}, aki[4] = {}, avr[4] = {}, avi[4] = {};
    const float* wq_r = wqkv_r + (h * HD + d) * C;
    const float* wq_i = wqkv_i + (h * HD + d) * C;
    const float* wk_r = wq_r + C * C;
    const float* wk_i = wq_i + C * C;
    const float* wv_r = wq_r + 2 * C * C;
    const float* wv_i = wq_i + 2 * C * C;
    #pragma unroll 2
    for (int c = 0; c < C; ++c) {
      const float qwr = wq_r[c], qwi = wq_i[c];
      const float kwr = wk_r[c], kwi = wk_i[c];
      const float vwr = wv_r[c], vwi = wv_i[c];
      #pragma unroll
      for (int j = 0; j < 4; ++j) {
        const float xre = sxr[c * 32 + n4 + j];
        const float xim = sxi[c * 32 + n4 + j];
        aqr[j] += qwr * xre - qwi * xim;
        aqi[j] += qwr * xim + qwi * xre;
        akr[j] += kwr * xre - kwi * xim;
        aki[j] += kwr * xim + kwi * xre;
        avr[j] += vwr * xre - vwi * xim;
        avi[j] += vwr * xim + vwi * xre;
      }
    }
    #pragma unroll
    for (int j = 0; j < 4; ++j) {
      const int o = d * 33 + n4 + j;
      sqr[o] = aqr[j]; sqi[o] = aqi[j];
      skr[o] = akr[j]; ski[o] = aki[j];
      svr[o] = avr[j]; svi[o] = avi[j];
    }
    __syncthreads();

    // ---- attn = scale * q . conj(k) + bias; magnitude softmax ----
    // thread owns row n=d, cols m = n4..n4+3 (8 lanes per row, same wave)
    {
      float sre[4] = {}, sim[4] = {};
      #pragma unroll 4
      for (int dd = 0; dd < HD; ++dd) {
        const float q_r = sqr[dd * 33 + d], q_i = sqi[dd * 33 + d];
        #pragma unroll
        for (int j = 0; j < 4; ++j) {
          const float k_r = skr[dd * 33 + n4 + j], k_i = ski[dd * 33 + n4 + j];
          sre[j] += q_r * k_r + q_i * k_i;
          sim[j] += q_i * k_r - q_r * k_i;
        }
      }
      float ar4[4], ai4[4], mg[4];
      const int i1 = d >> 2, j1 = d & 3;
      #pragma unroll
      for (int j = 0; j < 4; ++j) {
        const int m = n4 + j;
        const int i2 = m >> 2, j2 = m & 3;
        const int bidx = (i1 - i2 + 7) * 7 + (j1 - j2 + 3);
        ar4[j] = sre[j] * SCALE + rpb[bidx * NH + h];
        ai4[j] = sim[j] * SCALE;
        mg[j] = sqrtf(ar4[j] * ar4[j] + ai4[j] * ai4[j]);
      }
      float mx = fmaxf(fmaxf(mg[0], mg[1]), fmaxf(mg[2], mg[3]));
      mx = fmaxf(mx, __shfl_xor(mx, 1));
      mx = fmaxf(mx, __shfl_xor(mx, 2));
      mx = fmaxf(mx, __shfl_xor(mx, 4));
      float ex[4], se = 0.f;
      #pragma unroll
      for (int j = 0; j < 4; ++j) { ex[j] = expf(mg[j] - mx); se += ex[j]; }
      se += __shfl_xor(se, 1);
      se += __shfl_xor(se, 2);
      se += __shfl_xor(se, 4);
      const float inv = 1.f / se;
      #pragma unroll
      for (int j = 0; j < 4; ++j) {
        const float f = ex[j] * inv / (mg[j] + 1e-8f);
        sar[d * 33 + n4 + j] = ar4[j] * f;
        sai[d * 33 + n4 + j] = ai4[j] * f;
      }
    }
    __syncthreads();

    // ---- PV: out[d][n] = sum_m attn[n][m] * v[d][m] ----
    {
      float por[4] = {}, poi[4] = {};
      #pragma unroll 4
      for (int m = 0; m < 32; ++m) {
        const float v_r = svr[d * 33 + m], v_i = svi[d * 33 + m];
        #pragma unroll
        for (int j = 0; j < 4; ++j) {
          const float a_r = sar[(n4 + j) * 33 + m], a_i = sai[(n4 + j) * 33 + m];
          por[j] += a_r * v_r - a_i * v_i;
          poi[j] += a_r * v_i + a_i * v_r;
        }
      }
      #pragma unroll
      for (int j = 0; j < 4; ++j) {
        sor[(h * HD + d) * 32 + n4 + j] = por[j];
        soi[(h * HD + d) * 32 + n4 + j] = poi[j];
      }
    }
    __syncthreads();
  }

  // ---- proj + residual: y = x + Wp . attnout ----
  float pr[6][4] = {}, pi[6][4] = {};
  #pragma unroll 2
  for (int c = 0; c < C; ++c) {
    float xre[4], xim[4];
    #pragma unroll
    for (int j = 0; j < 4; ++j) {
      xre[j] = sor[c * 32 + n4 + j];
      xim[j] = soi[c * 32 + n4 + j];
    }
    #pragma unroll
    for (int i = 0; i < 6; ++i) {
      const float w_r = wp_r[(d + 32 * i) * C + c];
      const float w_i = wp_i[(d + 32 * i) * C + c];
      #pragma unroll
      for (int j = 0; j < 4; ++j) {
        pr[i][j] += w_r * xre[j] - w_i * xim[j];
        pi[i][j] += w_r * xim[j] + w_i * xre[j];
      }
    }
  }
  #pragma unroll
  for (int i = 0; i < 6; ++i) {
    const int o = d + 32 * i;
    #pragma unroll
    for (int j = 0; j < 4; ++j) {
      const int n = n4 + j;
      const int g = gbase + o * HW + (n >> 2) * Wd + (n & 3);
      yr[g] = sxr[o * 32 + n] + pr[i][j];
      yi[g] = sxi[o * 32 + n] + pi[i][j];
    }
  }
}

// ---------------------------------------------------------------------------
// BN stats: one workgroup per (channel, plane). Training-mode biased var.
// ---------------------------------------------------------------------------
__global__ __launch_bounds__(256) void k_stats(
    const float* __restrict__ src_r, const float* __restrict__ src_i,
    float* __restrict__ mean, float* __restrict__ rstd)
{
  const int c = blockIdx.x;
  const int plane = blockIdx.y;
  const float* src = plane ? src_i : src_r;
  const int t = threadIdx.x;
  double s = 0.0, s2 = 0.0;
  for (int b = 0; b < Bn; ++b) {
    const float* p = src + (size_t)(b * C + c) * HW;
    for (int i = t; i < HW; i += 256) {
      const double v = (double)p[i];
      s += v;
      s2 += v * v;
    }
  }
  __shared__ double ls[256], ls2[256];
  ls[t] = s; ls2[t] = s2;
  __syncthreads();
  for (int off = 128; off > 0; off >>= 1) {
    if (t < off) { ls[t] += ls[t + off]; ls2[t] += ls2[t + off]; }
    __syncthreads();
  }
  if (t == 0) {
    const double inv = 1.0 / (double)(Bn * HW);
    const double m = ls[0] * inv;
    const double var = ls2[0] * inv - m * m;
    mean[plane * C + c] = (float)m;
    rstd[plane * C + c] = (float)(1.0 / sqrt(var + 1e-5));
  }
}

// Fold stats + gamma/beta into per-channel scale/shift (planes: 0=re, 1=im).
__global__ void k_bnpar(const float* __restrict__ mean, const float* __restrict__ rstd,
                        const float* __restrict__ g_r, const float* __restrict__ b_r,
                        const float* __restrict__ g_i, const float* __restrict__ b_i,
                        float* __restrict__ sc, float* __restrict__ sh)
{
  const int i = blockIdx.x * blockDim.x + threadIdx.x;
  if (i >= 2 * C) return;
  const int plane = i / C, c = i % C;
  const float g = plane ? g_i[c] : g_r[c];
  const float bb = plane ? b_i[c] : b_r[c];
  const float s = rstd[i] * g;
  sc[i] = s;
  sh[i] = bb - mean[i] * s;
}

// ---------------------------------------------------------------------------
// Fused MLP: x2 = bn1(y) + W2 . CGELU( W1 . bn1(y) ), in place on d_out.
// One block = 32 pixels (one batch), 256 threads. Hidden tensor never leaves
// the block: 12 chunks of 64 hidden channels round-trip through 16KB LDS.
// LDS total 64KB -> 2 blocks/CU.
// ---------------------------------------------------------------------------
__global__ __launch_bounds__(256) void k_mlp(
    float* __restrict__ outp,
    const float* __restrict__ w1_r, const float* __restrict__ w1_i,
    const float* __restrict__ w2_r, const float* __restrict__ w2_i,
    const float* __restrict__ sc1, const float* __restrict__ sh1)
{
  __shared__ float syr[C * 32], syi[C * 32];   // bn1(y) tile [192][32]
  __shared__ float shr[64 * 32], shi[64 * 32]; // h chunk [64][32]

  const int t = threadIdx.x;
  const int pix0 = blockIdx.x * 32;
  const int b = pix0 >> 14;
  const int p0 = pix0 & (HW - 1);
  const float* yrp = outp;
  const float* yip = outp + PLANE;

  // ---- load + bn1 the y tile ----
  #pragma unroll
  for (int k = 0; k < 6; ++k) {
    const int idx = t + k * 256;            // float4 index, 1536 total
    const int c = idx >> 3;
    const int q = (idx & 7) << 2;
    const size_t g = (size_t)(b * C + c) * HW + p0 + q;
    const float4 vr = *(const float4*)(yrp + g);
    const float4 vi = *(const float4*)(yip + g);
    const float s_r = sc1[c], h_r = sh1[c];
    const float s_i = sc1[C + c], h_i = sh1[C + c];
    syr[c * 32 + q + 0] = vr.x * s_r + h_r;
    syr[c * 32 + q + 1] = vr.y * s_r + h_r;
    syr[c * 32 + q + 2] = vr.z * s_r + h_r;
    syr[c * 32 + q + 3] = vr.w * s_r + h_r;
    syi[c * 32 + q + 0] = vi.x * s_i + h_i;
    syi[c * 32 + q + 1] = vi.y * s_i + h_i;
    syi[c * 32 + q + 2] = vi.z * s_i + h_i;
    syi[c * 32 + q + 3] = vi.w * s_i + h_i;
  }
  __syncthreads();

  const int oo = t >> 3;          // 0..31 (h rows / x2 row group)
  const int pp = (t & 7) << 2;    // pixel quad

  float acc2r[6][4] = {}, acc2i[6][4] = {};

  for (int oc0 = 0; oc0 < C4; oc0 += 64) {
    // ---- h chunk: rows oc0+oo and oc0+oo+32, 4 pixels, K=192 ----
    float h0r[4] = {}, h0i[4] = {}, h1r[4] = {}, h1i[4] = {};
    const float* w1r0 = w1_r + (size_t)(oc0 + oo) * C;
    const float* w1i0 = w1_i + (size_t)(oc0 + oo) * C;
    #pragma unroll 2
    for (int c = 0; c < C; ++c) {
      const float4 br = *(const float4*)(&syr[c * 32 + pp]);
      const float4 bi = *(const float4*)(&syi[c * 32 + pp]);
      const float a0r = w1r0[c],          a0i = w1i0[c];
      const float a1r = w1r0[32 * C + c], a1i = w1i0[32 * C + c];
      const float brx[4] = {br.x, br.y, br.z, br.w};
      const float bix[4] = {bi.x, bi.y, bi.z, bi.w};
      #pragma unroll
      for (int j = 0; j < 4; ++j) {
        h0r[j] += a0r * brx[j] - a0i * bix[j];
        h0i[j] += a0r * bix[j] + a0i * brx[j];
        h1r[j] += a1r * brx[j] - a1i * bix[j];
        h1i[j] += a1r * bix[j] + a1i * brx[j];
      }
    }
    // ---- magnitude GELU (exact erf) ----
    float g0r[4], g0i[4], g1r[4], g1i[4];
    #pragma unroll
    for (int j = 0; j < 4; ++j) {
      const float m0 = sqrtf(h0r[j] * h0r[j] + h0i[j] * h0i[j]);
      const float f0 = 0.5f * m0 * (1.0f + erff(m0 * 0.70710678f)) / (m0 + 1e-8f);
      g0r[j] = h0r[j] * f0;
      g0i[j] = h0i[j] * f0;
      const float m1 = sqrtf(h1r[j] * h1r[j] + h1i[j] * h1i[j]);
      const float f1 = 0.5f * m1 * (1.0f + erff(m1 * 0.70710678f)) / (m1 + 1e-8f);
      g1r[j] = h1r[j] * f1;
      g1i[j] = h1i[j] * f1;
    }
    __syncthreads();   // previous chunk fully consumed before overwrite
    *(float4*)(&shr[oo * 32 + pp])        = make_float4(g0r[0], g0r[1], g0r[2], g0r[3]);
    *(float4*)(&shi[oo * 32 + pp])        = make_float4(g0i[0], g0i[1], g0i[2], g0i[3]);
    *(float4*)(&shr[(oo + 32) * 32 + pp]) = make_float4(g1r[0], g1r[1], g1r[2], g1r[3]);
    *(float4*)(&shi[(oo + 32) * 32 + pp]) = make_float4(g1i[0], g1i[1], g1i[2], g1i[3]);
    __syncthreads();

    // ---- accumulate W2 . h-chunk into x2 (rows oo + 32i) ----
    #pragma unroll 2
    for (int o = 0; o < 64; ++o) {
      const float4 hr4 = *(const float4*)(&shr[o * 32 + pp]);
      const float4 hi4 = *(const float4*)(&shi[o * 32 + pp]);
      const float hrx[4] = {hr4.x, hr4.y, hr4.z, hr4.w};
      const float hix[4] = {hi4.x, hi4.y, hi4.z, hi4.w};
      #pragma unroll
      for (int i = 0; i < 6; ++i) {
        const size_t wrow = (size_t)(oo + 32 * i) * C4 + oc0 + o;
        const float w_r = w2_r[wrow];
        const float w_i = w2_i[wrow];
        #pragma unroll
        for (int j = 0; j < 4; ++j) {
          acc2r[i][j] += w_r * hrx[j] - w_i * hix[j];
          acc2i[i][j] += w_r * hix[j] + w_i * hrx[j];
        }
      }
    }
  }

  // ---- x2 = bn1(y) + acc2, write in place ----
  #pragma unroll
  for (int i = 0; i < 6; ++i) {
    const int c = oo + 32 * i;
    const size_t g = (size_t)(b * C + c) * HW + p0 + pp;
    float4 rr, ri;
    rr.x = syr[c * 32 + pp + 0] + acc2r[i][0];
    rr.y = syr[c * 32 + pp + 1] + acc2r[i][1];
    rr.z = syr[c * 32 + pp + 2] + acc2r[i][2];
    rr.w = syr[c * 32 + pp + 3] + acc2r[i][3];
    ri.x = syi[c * 32 + pp + 0] + acc2i[i][0];
    ri.y = syi[c * 32 + pp + 1] + acc2i[i][1];
    ri.z = syi[c * 32 + pp + 2] + acc2i[i][2];
    ri.w = syi[c * 32 + pp + 3] + acc2i[i][3];
    *(float4*)(outp + g) = rr;
    *(float4*)(outp + PLANE + g) = ri;
  }
}

// In-place BN2 apply over d_out (both planes).
__global__ __launch_bounds__(256) void k_bnfinal(
    float* __restrict__ xo, const float* __restrict__ sc, const float* __restrict__ sh)
{
  const int total4 = (2 * PLANE) / 4;
  for (int i = blockIdx.x * blockDim.x + threadIdx.x; i < total4; i += gridDim.x * blockDim.x) {
    const int e = i * 4;
    const int plane = (e >= PLANE) ? 1 : 0;
    const int w = plane ? (e - PLANE) : e;
    const int ch = (w >> 14) % C;
    const float s = sc[plane * C + ch], hh = sh[plane * C + ch];
    float4 v = *(float4*)(xo + e);
    v.x = v.x * s + hh;
    v.y = v.y * s + hh;
    v.z = v.z * s + hh;
    v.w = v.w * s + hh;
    *(float4*)(xo + e) = v;
  }
}

}  // namespace

extern "C" void kernel_launch(void* const* d_in, const int* in_sizes, int n_in,
                              void* d_out, int out_size, void* d_ws, size_t ws_size,
                              hipStream_t stream)
{
  (void)in_sizes; (void)n_in; (void)out_size; (void)ws_size;
  const float* x_real  = (const float*)d_in[0];
  const float* x_imag  = (const float*)d_in[1];
  const float* qkv_wr  = (const float*)d_in[2];
  const float* qkv_wi  = (const float*)d_in[3];
  const float* proj_wr = (const float*)d_in[4];
  const float* proj_wi = (const float*)d_in[5];
  const float* rpb     = (const float*)d_in[6];
  const float* n1_gr   = (const float*)d_in[7];
  const float* n1_br   = (const float*)d_in[8];
  const float* n1_gi   = (const float*)d_in[9];
  const float* n1_bi   = (const float*)d_in[10];
  const float* mlp1_wr = (const float*)d_in[11];
  const float* mlp1_wi = (const float*)d_in[12];
  const float* mlp2_wr = (const float*)d_in[13];
  const float* mlp2_wi = (const float*)d_in[14];
  const float* n2_gr   = (const float*)d_in[15];
  const float* n2_br   = (const float*)d_in[16];
  const float* n2_gi   = (const float*)d_in[17];
  const float* n2_bi   = (const float*)d_in[18];

  // Workspace: stats only (~12 KB).
  float* st = (float*)d_ws;
  float* mean1 = st;          float* rstd1 = st + 384;
  float* sc1   = st + 768;    float* sh1   = st + 1152;
  float* mean2 = st + 1536;   float* rstd2 = st + 1920;
  float* sc2   = st + 2304;   float* sh2   = st + 2688;

  float* outp = (float*)d_out;
  float* yr = outp;            // y lives in d_out between k_attn and k_mlp
  float* yi = outp + PLANE;

  k_attn<<<NWIN, 256, 0, stream>>>(x_real, x_imag, qkv_wr, qkv_wi,
                                   proj_wr, proj_wi, rpb, yr, yi);
  k_stats<<<dim3(C, 2), 256, 0, stream>>>(yr, yi, mean1, rstd1);
  k_bnpar<<<2, 192, 0, stream>>>(mean1, rstd1, n1_gr, n1_br, n1_gi, n1_bi, sc1, sh1);
  k_mlp<<<Bn * HW / 32, 256, 0, stream>>>(outp, mlp1_wr, mlp1_wi,
                                          mlp2_wr, mlp2_wi, sc1, sh1);
  k_stats<<<dim3(C, 2), 256, 0, stream>>>(outp, outp + PLANE, mean2, rstd2);
  k_bnpar<<<2, 192, 0, stream>>>(mean2, rstd2, n2_gr, n2_br, n2_gi, n2_bi, sc2, sh2);
  k_bnfinal<<<2048, 256, 0, stream>>>(outp, sc2, sh2);
}

// Round 3
// 2729.130 us; speedup vs baseline: 2.1361x; 2.1361x over previous
//
#include <hip/hip_runtime.h>

namespace {

constexpr int Bn = 4;
constexpr int C  = 192;
constexpr int Wd = 128;
constexpr int HW = 16384;            // 128*128
constexpr int PLANE = Bn * C * HW;   // 12582912
constexpr int NH = 6;
constexpr int HD = 32;
constexpr int NWIN = 2048;           // 4 * 16 * 32
constexpr int C4 = 4 * C;            // 768
constexpr float SCALE = 0.17677669529663687f;  // 32^-0.5

typedef short bf16x8 __attribute__((ext_vector_type(8)));
typedef float f32x4 __attribute__((ext_vector_type(4)));

__device__ inline unsigned short f2bf(float f) {
  union { float f; unsigned u; } v; v.f = f;
  const unsigned r = v.u + 0x7FFFu + ((v.u >> 16) & 1u);
  return (unsigned short)(r >> 16);
}

__device__ inline bf16x8 pack8(const float* f) {
  union { bf16x8 v; unsigned short s[8]; } x;
#pragma unroll
  for (int j = 0; j < 8; ++j) x.s[j] = f2bf(f[j]);
  return x.v;
}

__device__ inline bf16x8 negb(bf16x8 a) {
  union { bf16x8 v; unsigned u[4]; } x;
  x.v = a;
#pragma unroll
  for (int j = 0; j < 4; ++j) x.u[j] ^= 0x80008000u;
  return x.v;
}

// ---------------------------------------------------------------------------
// Stage 1: windowed complex attention + proj + residual -> y into d_out.
// One workgroup per window (256 threads). 132KB static LDS. (unchanged R2)
// ---------------------------------------------------------------------------
__global__ __launch_bounds__(256, 1) void k_attn(
    const float* __restrict__ xr, const float* __restrict__ xi,
    const float* __restrict__ wqkv_r, const float* __restrict__ wqkv_i,
    const float* __restrict__ wp_r, const float* __restrict__ wp_i,
    const float* __restrict__ rpb,
    float* __restrict__ yr, float* __restrict__ yi)
{
  __shared__ float sxr[6144], sxi[6144];   // x window [192][32]
  __shared__ float sor[6144], soi[6144];   // attn output [192][32]
  __shared__ float sqr[1056], sqi[1056];   // q [32][33] (padded stride)
  __shared__ float skr[1056], ski[1056];   // k
  __shared__ float svr[1056], svi[1056];   // v
  __shared__ float sar[1056], sai[1056];   // attn weights

  const int t = threadIdx.x;
  const int win = blockIdx.x;
  const int b = win >> 9;             // 512 windows per batch
  const int rem = win & 511;
  const int r0 = (rem >> 5) << 3;     // ih*8
  const int c0 = (rem & 31) << 2;     // iw*4
  const int gbase = b * C * HW + r0 * Wd + c0;

  for (int e = t; e < C * 32; e += 256) {
    const int c = e >> 5, n = e & 31;
    const int g = gbase + c * HW + (n >> 2) * Wd + (n & 3);
    sxr[e] = xr[g];
    sxi[e] = xi[g];
  }
  __syncthreads();

  const int d  = t >> 3;        // 0..31
  const int n4 = (t & 7) << 2;  // 0,4,...,28

  for (int h = 0; h < NH; ++h) {
    float aqr[4] = {}, aqi[4] = {}, akr[4] = {}, aki[4] = {}, avr[4] = {}, avi[4] = {};
    const float* wq_r = wqkv_r + (h * HD + d) * C;
    const float* wq_i = wqkv_i + (h * HD + d) * C;
    const float* wk_r = wq_r + C * C;
    const float* wk_i = wq_i + C * C;
    const float* wv_r = wq_r + 2 * C * C;
    const float* wv_i = wq_i + 2 * C * C;
    #pragma unroll 2
    for (int c = 0; c < C; ++c) {
      const float qwr = wq_r[c], qwi = wq_i[c];
      const float kwr = wk_r[c], kwi = wk_i[c];
      const float vwr = wv_r[c], vwi = wv_i[c];
      #pragma unroll
      for (int j = 0; j < 4; ++j) {
        const float xre = sxr[c * 32 + n4 + j];
        const float xim = sxi[c * 32 + n4 + j];
        aqr[j] += qwr * xre - qwi * xim;
        aqi[j] += qwr * xim + qwi * xre;
        akr[j] += kwr * xre - kwi * xim;
        aki[j] += kwr * xim + kwi * xre;
        avr[j] += vwr * xre - vwi * xim;
        avi[j] += vwr * xim + vwi * xre;
      }
    }
    #pragma unroll
    for (int j = 0; j < 4; ++j) {
      const int o = d * 33 + n4 + j;
      sqr[o] = aqr[j]; sqi[o] = aqi[j];
      skr[o] = akr[j]; ski[o] = aki[j];
      svr[o] = avr[j]; svi[o] = avi[j];
    }
    __syncthreads();

    {
      float sre[4] = {}, sim[4] = {};
      #pragma unroll 4
      for (int dd = 0; dd < HD; ++dd) {
        const float q_r = sqr[dd * 33 + d], q_i = sqi[dd * 33 + d];
        #pragma unroll
        for (int j = 0; j < 4; ++j) {
          const float k_r = skr[dd * 33 + n4 + j], k_i = ski[dd * 33 + n4 + j];
          sre[j] += q_r * k_r + q_i * k_i;
          sim[j] += q_i * k_r - q_r * k_i;
        }
      }
      float ar4[4], ai4[4], mg[4];
      const int i1 = d >> 2, j1 = d & 3;
      #pragma unroll
      for (int j = 0; j < 4; ++j) {
        const int m = n4 + j;
        const int i2 = m >> 2, j2 = m & 3;
        const int bidx = (i1 - i2 + 7) * 7 + (j1 - j2 + 3);
        ar4[j] = sre[j] * SCALE + rpb[bidx * NH + h];
        ai4[j] = sim[j] * SCALE;
        mg[j] = sqrtf(ar4[j] * ar4[j] + ai4[j] * ai4[j]);
      }
      float mx = fmaxf(fmaxf(mg[0], mg[1]), fmaxf(mg[2], mg[3]));
      mx = fmaxf(mx, __shfl_xor(mx, 1));
      mx = fmaxf(mx, __shfl_xor(mx, 2));
      mx = fmaxf(mx, __shfl_xor(mx, 4));
      float ex[4], se = 0.f;
      #pragma unroll
      for (int j = 0; j < 4; ++j) { ex[j] = expf(mg[j] - mx); se += ex[j]; }
      se += __shfl_xor(se, 1);
      se += __shfl_xor(se, 2);
      se += __shfl_xor(se, 4);
      const float inv = 1.f / se;
      #pragma unroll
      for (int j = 0; j < 4; ++j) {
        const float f = ex[j] * inv / (mg[j] + 1e-8f);
        sar[d * 33 + n4 + j] = ar4[j] * f;
        sai[d * 33 + n4 + j] = ai4[j] * f;
      }
    }
    __syncthreads();

    {
      float por[4] = {}, poi[4] = {};
      #pragma unroll 4
      for (int m = 0; m < 32; ++m) {
        const float v_r = svr[d * 33 + m], v_i = svi[d * 33 + m];
        #pragma unroll
        for (int j = 0; j < 4; ++j) {
          const float a_r = sar[(n4 + j) * 33 + m], a_i = sai[(n4 + j) * 33 + m];
          por[j] += a_r * v_r - a_i * v_i;
          poi[j] += a_r * v_i + a_i * v_r;
        }
      }
      #pragma unroll
      for (int j = 0; j < 4; ++j) {
        sor[(h * HD + d) * 32 + n4 + j] = por[j];
        soi[(h * HD + d) * 32 + n4 + j] = poi[j];
      }
    }
    __syncthreads();
  }

  float pr[6][4] = {}, pi[6][4] = {};
  #pragma unroll 2
  for (int c = 0; c < C; ++c) {
    float xre[4], xim[4];
    #pragma unroll
    for (int j = 0; j < 4; ++j) {
      xre[j] = sor[c * 32 + n4 + j];
      xim[j] = soi[c * 32 + n4 + j];
    }
    #pragma unroll
    for (int i = 0; i < 6; ++i) {
      const float w_r = wp_r[(d + 32 * i) * C + c];
      const float w_i = wp_i[(d + 32 * i) * C + c];
      #pragma unroll
      for (int j = 0; j < 4; ++j) {
        pr[i][j] += w_r * xre[j] - w_i * xim[j];
        pi[i][j] += w_r * xim[j] + w_i * xre[j];
      }
    }
  }
  #pragma unroll
  for (int i = 0; i < 6; ++i) {
    const int o = d + 32 * i;
    #pragma unroll
    for (int j = 0; j < 4; ++j) {
      const int n = n4 + j;
      const int g = gbase + o * HW + (n >> 2) * Wd + (n & 3);
      yr[g] = sxr[o * 32 + n] + pr[i][j];
      yi[g] = sxi[o * 32 + n] + pi[i][j];
    }
  }
}

// ---------------------------------------------------------------------------
// BN stats (unchanged R2)
// ---------------------------------------------------------------------------
__global__ __launch_bounds__(256) void k_stats(
    const float* __restrict__ src_r, const float* __restrict__ src_i,
    float* __restrict__ mean, float* __restrict__ rstd)
{
  const int c = blockIdx.x;
  const int plane = blockIdx.y;
  const float* src = plane ? src_i : src_r;
  const int t = threadIdx.x;
  double s = 0.0, s2 = 0.0;
  for (int b = 0; b < Bn; ++b) {
    const float* p = src + (size_t)(b * C + c) * HW;
    for (int i = t; i < HW; i += 256) {
      const double v = (double)p[i];
      s += v;
      s2 += v * v;
    }
  }
  __shared__ double ls[256], ls2[256];
  ls[t] = s; ls2[t] = s2;
  __syncthreads();
  for (int off = 128; off > 0; off >>= 1) {
    if (t < off) { ls[t] += ls[t + off]; ls2[t] += ls2[t + off]; }
    __syncthreads();
  }
  if (t == 0) {
    const double inv = 1.0 / (double)(Bn * HW);
    const double m = ls[0] * inv;
    const double var = ls2[0] * inv - m * m;
    mean[plane * C + c] = (float)m;
    rstd[plane * C + c] = (float)(1.0 / sqrt(var + 1e-5));
  }
}

__global__ void k_bnpar(const float* __restrict__ mean, const float* __restrict__ rstd,
                        const float* __restrict__ g_r, const float* __restrict__ b_r,
                        const float* __restrict__ g_i, const float* __restrict__ b_i,
                        float* __restrict__ sc, float* __restrict__ sh)
{
  const int i = blockIdx.x * blockDim.x + threadIdx.x;
  if (i >= 2 * C) return;
  const int plane = i / C, c = i % C;
  const float g = plane ? g_i[c] : g_r[c];
  const float bb = plane ? b_i[c] : b_r[c];
  const float s = rstd[i] * g;
  sc[i] = s;
  sh[i] = bb - mean[i] * s;
}

// ---------------------------------------------------------------------------
// Fused MFMA MLP: x2 = bn1(y) + W2 . CGELU( W1 . bn1(y) ), in place on d_out.
// Block = 64 pixels, 4 waves. bf16 MFMA 16x16x32, fp32 accumulate.
// LDS: Xt (bn1(y) transposed, swizzled) 48KB + Ht double-buffered 32KB.
// ---------------------------------------------------------------------------
__global__ __launch_bounds__(256, 1) void k_mlp(
    float* __restrict__ outp,
    const float* __restrict__ w1_r, const float* __restrict__ w1_i,
    const float* __restrict__ w2_r, const float* __restrict__ w2_i,
    const float* __restrict__ sc1, const float* __restrict__ sh1)
{
  __shared__ short sX[2][64 * 192];      // [plane][p*192 + (k ^ ((p&7)<<3))]
  __shared__ short sH[2][2][64 * 64];    // [buf][plane][p*64 + (k ^ ((p&7)<<3))]

  const int t = threadIdx.x;
  const int pix0 = blockIdx.x * 64;
  const int b = pix0 >> 14;
  const int p0 = pix0 & (HW - 1);
  const float* yrp = outp;               // y lives in d_out (written by k_attn)
  const float* yip = outp + PLANE;

  // ---- stage Xt = bf16(bn1(y)), transposed [p][k], XOR-swizzled ----
  #pragma unroll
  for (int it = 0; it < 12; ++it) {
    const int idx = t + it * 256;        // 3072 quads: c = idx>>4, quad = idx&15
    const int c = idx >> 4;
    const int q = (idx & 15) << 2;
    const size_t g = (size_t)(b * C + c) * HW + p0 + q;
    const float4 vr = *(const float4*)(yrp + g);
    const float4 vi = *(const float4*)(yip + g);
    const float srr = sc1[c], hrr = sh1[c];
    const float sii = sc1[C + c], hii = sh1[C + c];
    const float fr[4] = {vr.x * srr + hrr, vr.y * srr + hrr, vr.z * srr + hrr, vr.w * srr + hrr};
    const float fi[4] = {vi.x * sii + hii, vi.y * sii + hii, vi.z * sii + hii, vi.w * sii + hii};
    #pragma unroll
    for (int i2 = 0; i2 < 4; ++i2) {
      const int p = q + i2;
      const int s = (p & 7) << 3;
      sX[0][p * 192 + (c ^ s)] = (short)f2bf(fr[i2]);
      sX[1][p * 192 + (c ^ s)] = (short)f2bf(fi[i2]);
    }
  }
  __syncthreads();

  const int lane = t & 63;
  const int w = t >> 6;          // wave 0..3
  const int lr = lane & 15;
  const int lg = lane >> 4;      // 0..3

  f32x4 acc2r[3][4] = {};        // [ob][cb] output rows (w*3+ob)*16, px cb*16
  f32x4 acc2i[3][4] = {};

  for (int hc = 0; hc < 12; ++hc) {
    const int buf = hc & 1;

    // ---- GEMM1: h rows [hc*64 + w*16, +16) x 64 px, K=192 ----
    f32x4 hfr[4] = {}, hfi[4] = {};
    const float* w1rp = w1_r + (size_t)(hc * 64 + w * 16 + lr) * C;
    const float* w1ip = w1_i + (size_t)(hc * 64 + w * 16 + lr) * C;
    #pragma unroll
    for (int ks = 0; ks < 6; ++ks) {
      const int k8 = ks * 32 + lg * 8;
      float a[8];
      *(float4*)&a[0] = *(const float4*)(w1rp + k8);
      *(float4*)&a[4] = *(const float4*)(w1rp + k8 + 4);
      const bf16x8 a1r = pack8(a);
      *(float4*)&a[0] = *(const float4*)(w1ip + k8);
      *(float4*)&a[4] = *(const float4*)(w1ip + k8 + 4);
      const bf16x8 a1i = pack8(a);
      const bf16x8 a1in = negb(a1i);
      #pragma unroll
      for (int cb = 0; cb < 4; ++cb) {
        const int p = cb * 16 + lr;
        const int s = (p & 7) << 3;
        const bf16x8 br = *(const bf16x8*)&sX[0][p * 192 + (k8 ^ s)];
        const bf16x8 bi = *(const bf16x8*)&sX[1][p * 192 + (k8 ^ s)];
        hfr[cb] = __builtin_amdgcn_mfma_f32_16x16x32_bf16(a1r,  br, hfr[cb], 0, 0, 0);
        hfr[cb] = __builtin_amdgcn_mfma_f32_16x16x32_bf16(a1in, bi, hfr[cb], 0, 0, 0);
        hfi[cb] = __builtin_amdgcn_mfma_f32_16x16x32_bf16(a1r,  bi, hfi[cb], 0, 0, 0);
        hfi[cb] = __builtin_amdgcn_mfma_f32_16x16x32_bf16(a1i,  br, hfi[cb], 0, 0, 0);
      }
    }

    // ---- magnitude GELU + pack to Ht[buf] (swizzled, 8B writes) ----
    #pragma unroll
    for (int cb = 0; cb < 4; ++cb) {
      const int p = cb * 16 + lr;
      const int s = (p & 7) << 3;
      float outr[4], outi[4];
      #pragma unroll
      for (int r = 0; r < 4; ++r) {
        const float re = hfr[cb][r], im = hfi[cb][r];
        const float m = sqrtf(re * re + im * im);
        const float f = 0.5f * m * (1.0f + erff(m * 0.70710678f)) / (m + 1e-8f);
        outr[r] = re * f;
        outi[r] = im * f;
      }
      const int kb = w * 16 + lg * 4;
      const int e = p * 64 + (kb ^ s);
      *(uint2*)&sH[buf][0][e] = make_uint2(
          (unsigned)f2bf(outr[0]) | ((unsigned)f2bf(outr[1]) << 16),
          (unsigned)f2bf(outr[2]) | ((unsigned)f2bf(outr[3]) << 16));
      *(uint2*)&sH[buf][1][e] = make_uint2(
          (unsigned)f2bf(outi[0]) | ((unsigned)f2bf(outi[1]) << 16),
          (unsigned)f2bf(outi[2]) | ((unsigned)f2bf(outi[3]) << 16));
    }
    __syncthreads();

    // ---- GEMM2: acc2 += W2[:, chunk] . Ht, K=64 ----
    #pragma unroll
    for (int ks2 = 0; ks2 < 2; ++ks2) {
      const int k8 = ks2 * 32 + lg * 8;
      bf16x8 br2[4], bi2[4];
      #pragma unroll
      for (int cb = 0; cb < 4; ++cb) {
        const int p = cb * 16 + lr;
        const int s = (p & 7) << 3;
        br2[cb] = *(const bf16x8*)&sH[buf][0][p * 64 + (k8 ^ s)];
        bi2[cb] = *(const bf16x8*)&sH[buf][1][p * 64 + (k8 ^ s)];
      }
      #pragma unroll
      for (int ob = 0; ob < 3; ++ob) {
        const int row = (w * 3 + ob) * 16 + lr;
        const size_t wbase = (size_t)row * C4 + hc * 64 + k8;
        float a[8];
        *(float4*)&a[0] = *(const float4*)(w2_r + wbase);
        *(float4*)&a[4] = *(const float4*)(w2_r + wbase + 4);
        const bf16x8 a2r = pack8(a);
        *(float4*)&a[0] = *(const float4*)(w2_i + wbase);
        *(float4*)&a[4] = *(const float4*)(w2_i + wbase + 4);
        const bf16x8 a2i = pack8(a);
        const bf16x8 a2in = negb(a2i);
        #pragma unroll
        for (int cb = 0; cb < 4; ++cb) {
          acc2r[ob][cb] = __builtin_amdgcn_mfma_f32_16x16x32_bf16(a2r,  br2[cb], acc2r[ob][cb], 0, 0, 0);
          acc2r[ob][cb] = __builtin_amdgcn_mfma_f32_16x16x32_bf16(a2in, bi2[cb], acc2r[ob][cb], 0, 0, 0);
          acc2i[ob][cb] = __builtin_amdgcn_mfma_f32_16x16x32_bf16(a2r,  bi2[cb], acc2i[ob][cb], 0, 0, 0);
          acc2i[ob][cb] = __builtin_amdgcn_mfma_f32_16x16x32_bf16(a2i,  br2[cb], acc2i[ob][cb], 0, 0, 0);
        }
      }
    }
    // no trailing barrier: next chunk writes sH[buf^1]; the per-chunk barrier
    // above bounds wave skew to <1 iteration.
  }

  // ---- epilogue: x2 = bn1(y) + acc2, in place (fp32 residual) ----
  #pragma unroll
  for (int ob = 0; ob < 3; ++ob) {
    #pragma unroll
    for (int cb = 0; cb < 4; ++cb) {
      const int px = p0 + cb * 16 + lr;
      #pragma unroll
      for (int r = 0; r < 4; ++r) {
        const int ch = (w * 3 + ob) * 16 + lg * 4 + r;
        const size_t g = (size_t)(b * C + ch) * HW + px;
        const float res_r = yrp[g] * sc1[ch] + sh1[ch];
        const float res_i = yip[g] * sc1[C + ch] + sh1[C + ch];
        outp[g] = res_r + acc2r[ob][cb][r];
        outp[PLANE + g] = res_i + acc2i[ob][cb][r];
      }
    }
  }
}

// In-place BN2 apply over d_out (both planes). (unchanged R2)
__global__ __launch_bounds__(256) void k_bnfinal(
    float* __restrict__ xo, const float* __restrict__ sc, const float* __restrict__ sh)
{
  const int total4 = (2 * PLANE) / 4;
  for (int i = blockIdx.x * blockDim.x + threadIdx.x; i < total4; i += gridDim.x * blockDim.x) {
    const int e = i * 4;
    const int plane = (e >= PLANE) ? 1 : 0;
    const int w = plane ? (e - PLANE) : e;
    const int ch = (w >> 14) % C;
    const float s = sc[plane * C + ch], hh = sh[plane * C + ch];
    float4 v = *(float4*)(xo + e);
    v.x = v.x * s + hh;
    v.y = v.y * s + hh;
    v.z = v.z * s + hh;
    v.w = v.w * s + hh;
    *(float4*)(xo + e) = v;
  }
}

}  // namespace

extern "C" void kernel_launch(void* const* d_in, const int* in_sizes, int n_in,
                              void* d_out, int out_size, void* d_ws, size_t ws_size,
                              hipStream_t stream)
{
  (void)in_sizes; (void)n_in; (void)out_size; (void)ws_size;
  const float* x_real  = (const float*)d_in[0];
  const float* x_imag  = (const float*)d_in[1];
  const float* qkv_wr  = (const float*)d_in[2];
  const float* qkv_wi  = (const float*)d_in[3];
  const float* proj_wr = (const float*)d_in[4];
  const float* proj_wi = (const float*)d_in[5];
  const float* rpb     = (const float*)d_in[6];
  const float* n1_gr   = (const float*)d_in[7];
  const float* n1_br   = (const float*)d_in[8];
  const float* n1_gi   = (const float*)d_in[9];
  const float* n1_bi   = (const float*)d_in[10];
  const float* mlp1_wr = (const float*)d_in[11];
  const float* mlp1_wi = (const float*)d_in[12];
  const float* mlp2_wr = (const float*)d_in[13];
  const float* mlp2_wi = (const float*)d_in[14];
  const float* n2_gr   = (const float*)d_in[15];
  const float* n2_br   = (const float*)d_in[16];
  const float* n2_gi   = (const float*)d_in[17];
  const float* n2_bi   = (const float*)d_in[18];

  // Workspace: stats only (~12 KB).
  float* st = (float*)d_ws;
  float* mean1 = st;          float* rstd1 = st + 384;
  float* sc1   = st + 768;    float* sh1   = st + 1152;
  float* mean2 = st + 1536;   float* rstd2 = st + 1920;
  float* sc2   = st + 2304;   float* sh2   = st + 2688;

  float* outp = (float*)d_out;
  float* yr = outp;            // y lives in d_out between k_attn and k_mlp
  float* yi = outp + PLANE;

  k_attn<<<NWIN, 256, 0, stream>>>(x_real, x_imag, qkv_wr, qkv_wi,
                                   proj_wr, proj_wi, rpb, yr, yi);
  k_stats<<<dim3(C, 2), 256, 0, stream>>>(yr, yi, mean1, rstd1);
  k_bnpar<<<2, 192, 0, stream>>>(mean1, rstd1, n1_gr, n1_br, n1_gi, n1_bi, sc1, sh1);
  k_mlp<<<Bn * HW / 64, 256, 0, stream>>>(outp, mlp1_wr, mlp1_wi,
                                          mlp2_wr, mlp2_wi, sc1, sh1);
  k_stats<<<dim3(C, 2), 256, 0, stream>>>(outp, outp + PLANE, mean2, rstd2);
  k_bnpar<<<2, 192, 0, stream>>>(mean2, rstd2, n2_gr, n2_br, n2_gi, n2_bi, sc2, sh2);
  k_bnfinal<<<2048, 256, 0, stream>>>(outp, sc2, sh2);
}

// Round 4
// 1342.978 us; speedup vs baseline: 4.3408x; 2.0321x over previous
//
#include <hip/hip_runtime.h>

namespace {

constexpr int Bn = 4;
constexpr int C  = 192;
constexpr int Wd = 128;
constexpr int HW = 16384;            // 128*128
constexpr int PLANE = Bn * C * HW;   // 12582912
constexpr int NH = 6;
constexpr int HD = 32;
constexpr int C4 = 4 * C;            // 768
constexpr float SCALE = 0.17677669529663687f;  // 32^-0.5

typedef short bf16x8 __attribute__((ext_vector_type(8)));
typedef float f32x4 __attribute__((ext_vector_type(4)));

__device__ inline unsigned short f2bf(float f) {
  union { float f; unsigned u; } v; v.f = f;
  const unsigned r = v.u + 0x7FFFu + ((v.u >> 16) & 1u);
  return (unsigned short)(r >> 16);
}

__device__ inline bf16x8 pack8(const float* f) {
  union { bf16x8 v; unsigned short s[8]; } x;
#pragma unroll
  for (int j = 0; j < 8; ++j) x.s[j] = f2bf(f[j]);
  return x.v;
}

__device__ inline uint2 pack4(const f32x4 v) {
  return make_uint2((unsigned)f2bf(v[0]) | ((unsigned)f2bf(v[1]) << 16),
                    (unsigned)f2bf(v[2]) | ((unsigned)f2bf(v[3]) << 16));
}

__device__ inline bf16x8 negb(bf16x8 a) {
  union { bf16x8 v; unsigned u[4]; } x;
  x.v = a;
#pragma unroll
  for (int j = 0; j < 4; ++j) x.u[j] ^= 0x80008000u;
  return x.v;
}

// ---------------------------------------------------------------------------
// Stage 1 (MFMA): windowed complex attention + proj + residual -> y in d_out.
// Block = 2 windows (64 px), 256 threads (4 waves), 3 head-pair groups.
// ---------------------------------------------------------------------------
__global__ __launch_bounds__(256, 1) void k_attn(
    const float* __restrict__ xr, const float* __restrict__ xi,
    const float* __restrict__ wqkv_r, const float* __restrict__ wqkv_i,
    const float* __restrict__ wp_r, const float* __restrict__ wp_i,
    const float* __restrict__ rpb,
    float* __restrict__ yr, float* __restrict__ yi)
{
  // swizzles: sX key px&7 on c; sQ/sK/sAO key px&7 on cc; sV key dd&7 on px;
  // sAttn key n&3 on m.
  __shared__ short sX[2][64 * 192];   // x window bf16 [px][c^s]
  __shared__ short sQ[2][64 * 64];    // q head-pair [px][cc^s]
  __shared__ short sK[2][64 * 64];    // k head-pair [px][cc^s]
  __shared__ short sV[2][64 * 64];    // v head-pair [cc][px^s]
  __shared__ short sAO[2][64 * 64];   // attn-out head-pair [px][cc^s]
  __shared__ short sAT[2][4][1024];   // attn weights per wave [n][m^s]
  __shared__ float sB[640];           // rpb table

  const int t = threadIdx.x;
  const int b = blockIdx.x >> 8;
  const int rem = blockIdx.x & 255;
  const int r0 = (rem >> 4) << 3;
  const int c0 = (rem & 15) << 3;     // two 4-wide windows: c0, c0+4
  const int gbase = b * C * HW + r0 * Wd + c0;

  // ---- stage x window as bf16, [px][c] swizzled; px = wv*32 + row*4 + wcol
  #pragma unroll
  for (int it = 0; it < 12; ++it) {
    const int idx = t + it * 256;          // 0..3071
    const int c = idx >> 4;
    const int q4 = (idx & 15) << 2;        // px base, mult of 4
    const int wv = q4 >> 5;
    const int row = (q4 & 31) >> 2;
    const int goff = gbase + c * HW + row * Wd + wv * 4;
    const float4 vr = *(const float4*)(xr + goff);
    const float4 vi = *(const float4*)(xi + goff);
    const float fr[4] = {vr.x, vr.y, vr.z, vr.w};
    const float fi[4] = {vi.x, vi.y, vi.z, vi.w};
    #pragma unroll
    for (int j = 0; j < 4; ++j) {
      const int p = q4 + j;
      const int s = (p & 7) << 3;
      sX[0][p * 192 + (c ^ s)] = (short)f2bf(fr[j]);
      sX[1][p * 192 + (c ^ s)] = (short)f2bf(fi[j]);
    }
  }
  for (int i = t; i < 630; i += 256) sB[i] = rpb[i];
  __syncthreads();

  const int lane = t & 63;
  const int w = t >> 6;
  const int lr = lane & 15;
  const int lg = lane >> 4;

  const int hloc = w >> 1;        // head within pair
  const int wv = w & 1;           // window handled by this wave
  const int ccq = hloc * 32;

  f32x4 apr[3][4] = {}, api[3][4] = {};   // proj accumulators (persist)

  for (int g = 0; g < 3; ++g) {
    // ======== QKV GEMM: 192 rows (q64,k64,v64 of head pair) x 64 px ========
    #pragma unroll
    for (int ob = 0; ob < 3; ++ob) {
      const int lrow = w * 48 + ob * 16;
      const int sec = lrow >> 6;           // 0=q 1=k 2=v
      const int ccb = lrow & 63;
      const int R = sec * 192 + g * 64 + ccb + lr;
      f32x4 dr[4] = {}, di[4] = {};
      const float* wrp = wqkv_r + (size_t)R * C;
      const float* wip = wqkv_i + (size_t)R * C;
      #pragma unroll
      for (int ks = 0; ks < 6; ++ks) {
        const int k8 = ks * 32 + lg * 8;
        float a[8];
        *(float4*)&a[0] = *(const float4*)(wrp + k8);
        *(float4*)&a[4] = *(const float4*)(wrp + k8 + 4);
        const bf16x8 ar = pack8(a);
        *(float4*)&a[0] = *(const float4*)(wip + k8);
        *(float4*)&a[4] = *(const float4*)(wip + k8 + 4);
        const bf16x8 ai = pack8(a);
        const bf16x8 ain = negb(ai);
        #pragma unroll
        for (int cb = 0; cb < 4; ++cb) {
          const int px = cb * 16 + lr;
          const int s = (px & 7) << 3;
          const bf16x8 br = *(const bf16x8*)&sX[0][px * 192 + (k8 ^ s)];
          const bf16x8 bi = *(const bf16x8*)&sX[1][px * 192 + (k8 ^ s)];
          dr[cb] = __builtin_amdgcn_mfma_f32_16x16x32_bf16(ar,  br, dr[cb], 0, 0, 0);
          dr[cb] = __builtin_amdgcn_mfma_f32_16x16x32_bf16(ain, bi, dr[cb], 0, 0, 0);
          di[cb] = __builtin_amdgcn_mfma_f32_16x16x32_bf16(ar,  bi, di[cb], 0, 0, 0);
          di[cb] = __builtin_amdgcn_mfma_f32_16x16x32_bf16(ai,  br, di[cb], 0, 0, 0);
        }
      }
      // write D to sQ/sK ([px][cc]) or sV ([cc][px])
      if (sec < 2) {
        short* d0 = sec ? sK[0] : sQ[0];
        short* d1 = sec ? sK[1] : sQ[1];
        #pragma unroll
        for (int cb = 0; cb < 4; ++cb) {
          const int px = cb * 16 + lr;
          const int e = px * 64 + ((ccb + lg * 4) ^ ((px & 7) << 3));
          *(uint2*)&d0[e] = pack4(dr[cb]);
          *(uint2*)&d1[e] = pack4(di[cb]);
        }
      } else {
        #pragma unroll
        for (int cb = 0; cb < 4; ++cb) {
          const int px = cb * 16 + lr;
          #pragma unroll
          for (int r = 0; r < 4; ++r) {
            const int dd = ccb + lg * 4 + r;
            const int e = dd * 64 + (px ^ ((dd & 7) << 3));
            sV[0][e] = (short)f2bf(dr[cb][r]);
            sV[1][e] = (short)f2bf(di[cb][r]);
          }
        }
      }
    }
    __syncthreads();   // bar A: qkv visible

    // ======== attention: wave handles head (2g+hloc), window wv ========
    const int h = 2 * g + hloc;
    {
      // Q A-frags / K B-frags: same addressing ([px][d] layout)
      bf16x8 aqr[2], aqi[2], bkr[2], bki[2];
      #pragma unroll
      for (int i = 0; i < 2; ++i) {
        const int px = wv * 32 + i * 16 + lr;
        const int e = px * 64 + ((ccq + lg * 8) ^ ((px & 7) << 3));
        aqr[i] = *(const bf16x8*)&sQ[0][e];
        aqi[i] = *(const bf16x8*)&sQ[1][e];
        bkr[i] = *(const bf16x8*)&sK[0][e];
        bki[i] = *(const bf16x8*)&sK[1][e];
      }
      f32x4 sre[2][2], sim[2][2];
      #pragma unroll
      for (int i = 0; i < 2; ++i) {
        #pragma unroll
        for (int j = 0; j < 2; ++j) {
          f32x4 z = {};
          f32x4 re = __builtin_amdgcn_mfma_f32_16x16x32_bf16(aqr[i], bkr[j], z, 0, 0, 0);
          re = __builtin_amdgcn_mfma_f32_16x16x32_bf16(aqi[i], bki[j], re, 0, 0, 0);
          f32x4 im = __builtin_amdgcn_mfma_f32_16x16x32_bf16(aqi[i], bkr[j], z, 0, 0, 0);
          im = __builtin_amdgcn_mfma_f32_16x16x32_bf16(negb(aqr[i]), bki[j], im, 0, 0, 0);
          sre[i][j] = re;
          sim[i][j] = im;
        }
      }
      // bias + magnitude + row softmax + store attn bf16
      float re_[2][2][4], im_[2][2][4], mg_[2][2][4];
      #pragma unroll
      for (int i = 0; i < 2; ++i) {
        #pragma unroll
        for (int j = 0; j < 2; ++j) {
          const int m = j * 16 + lr;
          #pragma unroll
          for (int r = 0; r < 4; ++r) {
            const int n = i * 16 + lg * 4 + r;
            const int bidx = ((n >> 2) - (m >> 2) + 7) * 7 + ((n & 3) - (m & 3) + 3);
            const float re = sre[i][j][r] * SCALE + sB[bidx * NH + h];
            const float im = sim[i][j][r] * SCALE;
            re_[i][j][r] = re;
            im_[i][j][r] = im;
            mg_[i][j][r] = sqrtf(re * re + im * im);
          }
        }
      }
      #pragma unroll
      for (int i = 0; i < 2; ++i) {
        #pragma unroll
        for (int r = 0; r < 4; ++r) {
          float mx = fmaxf(mg_[i][0][r], mg_[i][1][r]);
          mx = fmaxf(mx, __shfl_xor(mx, 1));
          mx = fmaxf(mx, __shfl_xor(mx, 2));
          mx = fmaxf(mx, __shfl_xor(mx, 4));
          mx = fmaxf(mx, __shfl_xor(mx, 8));
          const float e0 = expf(mg_[i][0][r] - mx);
          const float e1 = expf(mg_[i][1][r] - mx);
          float se = e0 + e1;
          se += __shfl_xor(se, 1);
          se += __shfl_xor(se, 2);
          se += __shfl_xor(se, 4);
          se += __shfl_xor(se, 8);
          const float inv = 1.f / se;
          const float f0 = e0 * inv / (mg_[i][0][r] + 1e-8f);
          const float f1 = e1 * inv / (mg_[i][1][r] + 1e-8f);
          const int n = i * 16 + lg * 4 + r;
          const int sw = (n & 3) << 3;
          sAT[0][w][n * 32 + (lr ^ sw)]        = (short)f2bf(re_[i][0][r] * f0);
          sAT[1][w][n * 32 + (lr ^ sw)]        = (short)f2bf(im_[i][0][r] * f0);
          sAT[0][w][n * 32 + ((16 + lr) ^ sw)] = (short)f2bf(re_[i][1][r] * f1);
          sAT[1][w][n * 32 + ((16 + lr) ^ sw)] = (short)f2bf(im_[i][1][r] * f1);
        }
      }
      // PV: out[dd][n] = sum_m v[dd][m] * attn[n][m]
      bf16x8 bar_[2], bai_[2];
      #pragma unroll
      for (int j2 = 0; j2 < 2; ++j2) {
        const int n = j2 * 16 + lr;
        const int e = n * 32 + ((lg * 8) ^ ((n & 3) << 3));
        bar_[j2] = *(const bf16x8*)&sAT[0][w][e];
        bai_[j2] = *(const bf16x8*)&sAT[1][w][e];
      }
      #pragma unroll
      for (int i2 = 0; i2 < 2; ++i2) {
        const int dd = ccq + i2 * 16 + lr;
        const int e = dd * 64 + ((wv * 32 + lg * 8) ^ ((dd & 7) << 3));
        const bf16x8 avr = *(const bf16x8*)&sV[0][e];
        const bf16x8 avi = *(const bf16x8*)&sV[1][e];
        const bf16x8 avin = negb(avi);
        #pragma unroll
        for (int j2 = 0; j2 < 2; ++j2) {
          f32x4 z = {};
          f32x4 pr = __builtin_amdgcn_mfma_f32_16x16x32_bf16(avr, bar_[j2], z, 0, 0, 0);
          pr = __builtin_amdgcn_mfma_f32_16x16x32_bf16(avin, bai_[j2], pr, 0, 0, 0);
          f32x4 pi = __builtin_amdgcn_mfma_f32_16x16x32_bf16(avr, bai_[j2], z, 0, 0, 0);
          pi = __builtin_amdgcn_mfma_f32_16x16x32_bf16(avi, bar_[j2], pi, 0, 0, 0);
          const int px = wv * 32 + j2 * 16 + lr;
          const int e2 = px * 64 + ((ccq + i2 * 16 + lg * 4) ^ ((px & 7) << 3));
          *(uint2*)&sAO[0][e2] = pack4(pr);
          *(uint2*)&sAO[1][e2] = pack4(pi);
        }
      }
    }
    __syncthreads();   // bar B: attn-out visible

    // ======== proj accumulation: K = 64 (head pair) ========
    #pragma unroll
    for (int ks = 0; ks < 2; ++ks) {
      const int k8 = ks * 32 + lg * 8;
      bf16x8 pbr[4], pbi[4];
      #pragma unroll
      for (int cb = 0; cb < 4; ++cb) {
        const int px = cb * 16 + lr;
        const int e = px * 64 + (k8 ^ ((px & 7) << 3));
        pbr[cb] = *(const bf16x8*)&sAO[0][e];
        pbi[cb] = *(const bf16x8*)&sAO[1][e];
      }
      #pragma unroll
      for (int ob = 0; ob < 3; ++ob) {
        const int o = w * 48 + ob * 16 + lr;
        const size_t wb = (size_t)o * C + g * 64 + k8;
        float a[8];
        *(float4*)&a[0] = *(const float4*)(wp_r + wb);
        *(float4*)&a[4] = *(const float4*)(wp_r + wb + 4);
        const bf16x8 ar = pack8(a);
        *(float4*)&a[0] = *(const float4*)(wp_i + wb);
        *(float4*)&a[4] = *(const float4*)(wp_i + wb + 4);
        const bf16x8 ai = pack8(a);
        const bf16x8 ain = negb(ai);
        #pragma unroll
        for (int cb = 0; cb < 4; ++cb) {
          apr[ob][cb] = __builtin_amdgcn_mfma_f32_16x16x32_bf16(ar,  pbr[cb], apr[ob][cb], 0, 0, 0);
          apr[ob][cb] = __builtin_amdgcn_mfma_f32_16x16x32_bf16(ain, pbi[cb], apr[ob][cb], 0, 0, 0);
          api[ob][cb] = __builtin_amdgcn_mfma_f32_16x16x32_bf16(ar,  pbi[cb], api[ob][cb], 0, 0, 0);
          api[ob][cb] = __builtin_amdgcn_mfma_f32_16x16x32_bf16(ai,  pbr[cb], api[ob][cb], 0, 0, 0);
        }
      }
    }
    // no barrier needed: next QKV writes sQ/sK/sV (disjoint from sAO);
    // bar A of next group orders attn-out overwrite after these reads.
  }

  // ======== epilogue: y = x + proj_out (fp32 residual from global) ========
  #pragma unroll
  for (int ob = 0; ob < 3; ++ob) {
    #pragma unroll
    for (int cb = 0; cb < 4; ++cb) {
      const int px = cb * 16 + lr;
      const int n = px & 31;
      const int off0 = gbase + (r0 ? 0 : 0) * 0 + (n >> 2) * Wd + (px >> 5) * 4 + (n & 3);
      #pragma unroll
      for (int r = 0; r < 4; ++r) {
        const int c = w * 48 + ob * 16 + lg * 4 + r;
        const size_t gg = (size_t)off0 + (size_t)c * HW;
        yr[gg] = xr[gg] + apr[ob][cb][r];
        yi[gg] = xi[gg] + api[ob][cb][r];
      }
    }
  }
}

// ---------------------------------------------------------------------------
// BN stats (unchanged)
// ---------------------------------------------------------------------------
__global__ __launch_bounds__(256) void k_stats(
    const float* __restrict__ src_r, const float* __restrict__ src_i,
    float* __restrict__ mean, float* __restrict__ rstd)
{
  const int c = blockIdx.x;
  const int plane = blockIdx.y;
  const float* src = plane ? src_i : src_r;
  const int t = threadIdx.x;
  double s = 0.0, s2 = 0.0;
  for (int b = 0; b < Bn; ++b) {
    const float* p = src + (size_t)(b * C + c) * HW;
    for (int i = t; i < HW; i += 256) {
      const double v = (double)p[i];
      s += v;
      s2 += v * v;
    }
  }
  __shared__ double ls[256], ls2[256];
  ls[t] = s; ls2[t] = s2;
  __syncthreads();
  for (int off = 128; off > 0; off >>= 1) {
    if (t < off) { ls[t] += ls[t + off]; ls2[t] += ls2[t + off]; }
    __syncthreads();
  }
  if (t == 0) {
    const double inv = 1.0 / (double)(Bn * HW);
    const double m = ls[0] * inv;
    const double var = ls2[0] * inv - m * m;
    mean[plane * C + c] = (float)m;
    rstd[plane * C + c] = (float)(1.0 / sqrt(var + 1e-5));
  }
}

__global__ void k_bnpar(const float* __restrict__ mean, const float* __restrict__ rstd,
                        const float* __restrict__ g_r, const float* __restrict__ b_r,
                        const float* __restrict__ g_i, const float* __restrict__ b_i,
                        float* __restrict__ sc, float* __restrict__ sh)
{
  const int i = blockIdx.x * blockDim.x + threadIdx.x;
  if (i >= 2 * C) return;
  const int plane = i / C, c = i % C;
  const float g = plane ? g_i[c] : g_r[c];
  const float bb = plane ? b_i[c] : b_r[c];
  const float s = rstd[i] * g;
  sc[i] = s;
  sh[i] = bb - mean[i] * s;
}

// ---------------------------------------------------------------------------
// Fused MFMA MLP (unchanged R3)
// ---------------------------------------------------------------------------
__global__ __launch_bounds__(256, 1) void k_mlp(
    float* __restrict__ outp,
    const float* __restrict__ w1_r, const float* __restrict__ w1_i,
    const float* __restrict__ w2_r, const float* __restrict__ w2_i,
    const float* __restrict__ sc1, const float* __restrict__ sh1)
{
  __shared__ short sXm[2][64 * 192];
  __shared__ short sH[2][2][64 * 64];

  const int t = threadIdx.x;
  const int pix0 = blockIdx.x * 64;
  const int b = pix0 >> 14;
  const int p0 = pix0 & (HW - 1);
  const float* yrp = outp;
  const float* yip = outp + PLANE;

  #pragma unroll
  for (int it = 0; it < 12; ++it) {
    const int idx = t + it * 256;
    const int c = idx >> 4;
    const int q = (idx & 15) << 2;
    const size_t g = (size_t)(b * C + c) * HW + p0 + q;
    const float4 vr = *(const float4*)(yrp + g);
    const float4 vi = *(const float4*)(yip + g);
    const float srr = sc1[c], hrr = sh1[c];
    const float sii = sc1[C + c], hii = sh1[C + c];
    const float fr[4] = {vr.x * srr + hrr, vr.y * srr + hrr, vr.z * srr + hrr, vr.w * srr + hrr};
    const float fi[4] = {vi.x * sii + hii, vi.y * sii + hii, vi.z * sii + hii, vi.w * sii + hii};
    #pragma unroll
    for (int i2 = 0; i2 < 4; ++i2) {
      const int p = q + i2;
      const int s = (p & 7) << 3;
      sXm[0][p * 192 + (c ^ s)] = (short)f2bf(fr[i2]);
      sXm[1][p * 192 + (c ^ s)] = (short)f2bf(fi[i2]);
    }
  }
  __syncthreads();

  const int lane = t & 63;
  const int w = t >> 6;
  const int lr = lane & 15;
  const int lg = lane >> 4;

  f32x4 acc2r[3][4] = {};
  f32x4 acc2i[3][4] = {};

  for (int hc = 0; hc < 12; ++hc) {
    const int buf = hc & 1;

    f32x4 hfr[4] = {}, hfi[4] = {};
    const float* w1rp = w1_r + (size_t)(hc * 64 + w * 16 + lr) * C;
    const float* w1ip = w1_i + (size_t)(hc * 64 + w * 16 + lr) * C;
    #pragma unroll
    for (int ks = 0; ks < 6; ++ks) {
      const int k8 = ks * 32 + lg * 8;
      float a[8];
      *(float4*)&a[0] = *(const float4*)(w1rp + k8);
      *(float4*)&a[4] = *(const float4*)(w1rp + k8 + 4);
      const bf16x8 a1r = pack8(a);
      *(float4*)&a[0] = *(const float4*)(w1ip + k8);
      *(float4*)&a[4] = *(const float4*)(w1ip + k8 + 4);
      const bf16x8 a1i = pack8(a);
      const bf16x8 a1in = negb(a1i);
      #pragma unroll
      for (int cb = 0; cb < 4; ++cb) {
        const int p = cb * 16 + lr;
        const int s = (p & 7) << 3;
        const bf16x8 br = *(const bf16x8*)&sXm[0][p * 192 + (k8 ^ s)];
        const bf16x8 bi = *(const bf16x8*)&sXm[1][p * 192 + (k8 ^ s)];
        hfr[cb] = __builtin_amdgcn_mfma_f32_16x16x32_bf16(a1r,  br, hfr[cb], 0, 0, 0);
        hfr[cb] = __builtin_amdgcn_mfma_f32_16x16x32_bf16(a1in, bi, hfr[cb], 0, 0, 0);
        hfi[cb] = __builtin_amdgcn_mfma_f32_16x16x32_bf16(a1r,  bi, hfi[cb], 0, 0, 0);
        hfi[cb] = __builtin_amdgcn_mfma_f32_16x16x32_bf16(a1i,  br, hfi[cb], 0, 0, 0);
      }
    }

    #pragma unroll
    for (int cb = 0; cb < 4; ++cb) {
      const int p = cb * 16 + lr;
      const int s = (p & 7) << 3;
      float outr[4], outi[4];
      #pragma unroll
      for (int r = 0; r < 4; ++r) {
        const float re = hfr[cb][r], im = hfi[cb][r];
        const float m = sqrtf(re * re + im * im);
        const float f = 0.5f * m * (1.0f + erff(m * 0.70710678f)) / (m + 1e-8f);
        outr[r] = re * f;
        outi[r] = im * f;
      }
      const int kb = w * 16 + lg * 4;
      const int e = p * 64 + (kb ^ s);
      *(uint2*)&sH[buf][0][e] = make_uint2(
          (unsigned)f2bf(outr[0]) | ((unsigned)f2bf(outr[1]) << 16),
          (unsigned)f2bf(outr[2]) | ((unsigned)f2bf(outr[3]) << 16));
      *(uint2*)&sH[buf][1][e] = make_uint2(
          (unsigned)f2bf(outi[0]) | ((unsigned)f2bf(outi[1]) << 16),
          (unsigned)f2bf(outi[2]) | ((unsigned)f2bf(outi[3]) << 16));
    }
    __syncthreads();

    #pragma unroll
    for (int ks2 = 0; ks2 < 2; ++ks2) {
      const int k8 = ks2 * 32 + lg * 8;
      bf16x8 br2[4], bi2[4];
      #pragma unroll
      for (int cb = 0; cb < 4; ++cb) {
        const int p = cb * 16 + lr;
        const int s = (p & 7) << 3;
        br2[cb] = *(const bf16x8*)&sH[buf][0][p * 64 + (k8 ^ s)];
        bi2[cb] = *(const bf16x8*)&sH[buf][1][p * 64 + (k8 ^ s)];
      }
      #pragma unroll
      for (int ob = 0; ob < 3; ++ob) {
        const int row = (w * 3 + ob) * 16 + lr;
        const size_t wbase = (size_t)row * C4 + hc * 64 + k8;
        float a[8];
        *(float4*)&a[0] = *(const float4*)(w2_r + wbase);
        *(float4*)&a[4] = *(const float4*)(w2_r + wbase + 4);
        const bf16x8 a2r = pack8(a);
        *(float4*)&a[0] = *(const float4*)(w2_i + wbase);
        *(float4*)&a[4] = *(const float4*)(w2_i + wbase + 4);
        const bf16x8 a2i = pack8(a);
        const bf16x8 a2in = negb(a2i);
        #pragma unroll
        for (int cb = 0; cb < 4; ++cb) {
          acc2r[ob][cb] = __builtin_amdgcn_mfma_f32_16x16x32_bf16(a2r,  br2[cb], acc2r[ob][cb], 0, 0, 0);
          acc2r[ob][cb] = __builtin_amdgcn_mfma_f32_16x16x32_bf16(a2in, bi2[cb], acc2r[ob][cb], 0, 0, 0);
          acc2i[ob][cb] = __builtin_amdgcn_mfma_f32_16x16x32_bf16(a2r,  bi2[cb], acc2i[ob][cb], 0, 0, 0);
          acc2i[ob][cb] = __builtin_amdgcn_mfma_f32_16x16x32_bf16(a2i,  br2[cb], acc2i[ob][cb], 0, 0, 0);
        }
      }
    }
  }

  #pragma unroll
  for (int ob = 0; ob < 3; ++ob) {
    #pragma unroll
    for (int cb = 0; cb < 4; ++cb) {
      const int px = p0 + cb * 16 + lr;
      #pragma unroll
      for (int r = 0; r < 4; ++r) {
        const int ch = (w * 3 + ob) * 16 + lg * 4 + r;
        const size_t g = (size_t)(b * C + ch) * HW + px;
        const float res_r = yrp[g] * sc1[ch] + sh1[ch];
        const float res_i = yip[g] * sc1[C + ch] + sh1[C + ch];
        outp[g] = res_r + acc2r[ob][cb][r];
        outp[PLANE + g] = res_i + acc2i[ob][cb][r];
      }
    }
  }
}

// In-place BN2 apply over d_out (both planes). (unchanged)
__global__ __launch_bounds__(256) void k_bnfinal(
    float* __restrict__ xo, const float* __restrict__ sc, const float* __restrict__ sh)
{
  const int total4 = (2 * PLANE) / 4;
  for (int i = blockIdx.x * blockDim.x + threadIdx.x; i < total4; i += gridDim.x * blockDim.x) {
    const int e = i * 4;
    const int plane = (e >= PLANE) ? 1 : 0;
    const int w = plane ? (e - PLANE) : e;
    const int ch = (w >> 14) % C;
    const float s = sc[plane * C + ch], hh = sh[plane * C + ch];
    float4 v = *(float4*)(xo + e);
    v.x = v.x * s + hh;
    v.y = v.y * s + hh;
    v.z = v.z * s + hh;
    v.w = v.w * s + hh;
    *(float4*)(xo + e) = v;
  }
}

}  // namespace

extern "C" void kernel_launch(void* const* d_in, const int* in_sizes, int n_in,
                              void* d_out, int out_size, void* d_ws, size_t ws_size,
                              hipStream_t stream)
{
  (void)in_sizes; (void)n_in; (void)out_size; (void)ws_size;
  const float* x_real  = (const float*)d_in[0];
  const float* x_imag  = (const float*)d_in[1];
  const float* qkv_wr  = (const float*)d_in[2];
  const float* qkv_wi  = (const float*)d_in[3];
  const float* proj_wr = (const float*)d_in[4];
  const float* proj_wi = (const float*)d_in[5];
  const float* rpb     = (const float*)d_in[6];
  const float* n1_gr   = (const float*)d_in[7];
  const float* n1_br   = (const float*)d_in[8];
  const float* n1_gi   = (const float*)d_in[9];
  const float* n1_bi   = (const float*)d_in[10];
  const float* mlp1_wr = (const float*)d_in[11];
  const float* mlp1_wi = (const float*)d_in[12];
  const float* mlp2_wr = (const float*)d_in[13];
  const float* mlp2_wi = (const float*)d_in[14];
  const float* n2_gr   = (const float*)d_in[15];
  const float* n2_br   = (const float*)d_in[16];
  const float* n2_gi   = (const float*)d_in[17];
  const float* n2_bi   = (const float*)d_in[18];

  float* st = (float*)d_ws;
  float* mean1 = st;          float* rstd1 = st + 384;
  float* sc1   = st + 768;    float* sh1   = st + 1152;
  float* mean2 = st + 1536;   float* rstd2 = st + 1920;
  float* sc2   = st + 2304;   float* sh2   = st + 2688;

  float* outp = (float*)d_out;
  float* yr = outp;
  float* yi = outp + PLANE;

  k_attn<<<1024, 256, 0, stream>>>(x_real, x_imag, qkv_wr, qkv_wi,
                                   proj_wr, proj_wi, rpb, yr, yi);
  k_stats<<<dim3(C, 2), 256, 0, stream>>>(yr, yi, mean1, rstd1);
  k_bnpar<<<2, 192, 0, stream>>>(mean1, rstd1, n1_gr, n1_br, n1_gi, n1_bi, sc1, sh1);
  k_mlp<<<Bn * HW / 64, 256, 0, stream>>>(outp, mlp1_wr, mlp1_wi,
                                          mlp2_wr, mlp2_wi, sc1, sh1);
  k_stats<<<dim3(C, 2), 256, 0, stream>>>(outp, outp + PLANE, mean2, rstd2);
  k_bnpar<<<2, 192, 0, stream>>>(mean2, rstd2, n2_gr, n2_br, n2_gi, n2_bi, sc2, sh2);
  k_bnfinal<<<2048, 256, 0, stream>>>(outp, sc2, sh2);
}

// Round 5
// 947.888 us; speedup vs baseline: 6.1502x; 1.4168x over previous
//
#include <hip/hip_runtime.h>

namespace {

constexpr int Bn = 4;
constexpr int C  = 192;
constexpr int Wd = 128;
constexpr int HW = 16384;            // 128*128
constexpr int PLANE = Bn * C * HW;   // 12582912
constexpr int NH = 6;
constexpr int HD = 32;
constexpr int C4 = 4 * C;            // 768
constexpr float SCALE = 0.17677669529663687f;  // 32^-0.5

// packed bf16 weight layout in d_ws (short offsets)
constexpr int OQKV_R = 0;            // 576*192
constexpr int OQKV_I = 110592;
constexpr int OPROJ_R = 221184;      // 192*192
constexpr int OPROJ_I = 258048;
constexpr int OW1_R = 294912;        // 768*192
constexpr int OW1_I = 442368;
constexpr int OW2_R = 589824;        // 192*768
constexpr int OW2_I = 737280;
constexpr int PK_TOTAL = 884736;

typedef short bf16x8 __attribute__((ext_vector_type(8)));
typedef float f32x4 __attribute__((ext_vector_type(4)));

__device__ inline unsigned short f2bf(float f) {
  union { float f; unsigned u; } v; v.f = f;
  const unsigned r = v.u + 0x7FFFu + ((v.u >> 16) & 1u);
  return (unsigned short)(r >> 16);
}

__device__ inline bf16x8 pack8(const float* f) {
  union { bf16x8 v; unsigned short s[8]; } x;
#pragma unroll
  for (int j = 0; j < 8; ++j) x.s[j] = f2bf(f[j]);
  return x.v;
}

__device__ inline uint2 pack4(const f32x4 v) {
  return make_uint2((unsigned)f2bf(v[0]) | ((unsigned)f2bf(v[1]) << 16),
                    (unsigned)f2bf(v[2]) | ((unsigned)f2bf(v[3]) << 16));
}

__device__ inline bf16x8 negb(bf16x8 a) {
  union { bf16x8 v; unsigned u[4]; } x;
  x.v = a;
#pragma unroll
  for (int j = 0; j < 4; ++j) x.u[j] ^= 0x80008000u;
  return x.v;
}

// ---------------------------------------------------------------------------
// Pack all weights to bf16 into ws (one pass, ~900K elements).
// ---------------------------------------------------------------------------
__global__ __launch_bounds__(256) void k_pack(
    const float* __restrict__ s0, const float* __restrict__ s1,
    const float* __restrict__ s2, const float* __restrict__ s3,
    const float* __restrict__ s4, const float* __restrict__ s5,
    const float* __restrict__ s6, const float* __restrict__ s7,
    short* __restrict__ dst)
{
  for (int i = blockIdx.x * 256 + threadIdx.x; i < PK_TOTAL; i += gridDim.x * 256) {
    const float* s; int off;
    if (i < OPROJ_R) {
      if (i < OQKV_I) { s = s0; off = i; } else { s = s1; off = i - OQKV_I; }
    } else if (i < OW1_R) {
      if (i < OPROJ_I) { s = s2; off = i - OPROJ_R; } else { s = s3; off = i - OPROJ_I; }
    } else if (i < OW2_R) {
      if (i < OW1_I) { s = s4; off = i - OW1_R; } else { s = s5; off = i - OW1_I; }
    } else {
      if (i < OW2_I) { s = s6; off = i - OW2_R; } else { s = s7; off = i - OW2_I; }
    }
    dst[i] = (short)f2bf(s[off]);
  }
}

// ---------------------------------------------------------------------------
// Stage 1 (MFMA): windowed complex attention + proj + residual -> y in d_out.
// Block = 2 windows (64 px), 256 threads (4 waves), 3 head-pair groups.
// PK=true: A-fragments loaded directly from pre-packed bf16 weights.
// ---------------------------------------------------------------------------
template <bool PK>
__global__ __launch_bounds__(256, 1) void k_attn(
    const float* __restrict__ xr, const float* __restrict__ xi,
    const float* __restrict__ wqkv_r, const float* __restrict__ wqkv_i,
    const float* __restrict__ wp_r, const float* __restrict__ wp_i,
    const short* __restrict__ wpk,
    const float* __restrict__ rpb,
    float* __restrict__ yr, float* __restrict__ yi)
{
  __shared__ short sX[2][64 * 192];   // x window bf16 [px][c^s]
  __shared__ short sQ[2][64 * 64];    // q head-pair [px][cc^s]
  __shared__ short sK[2][64 * 64];    // k head-pair [px][cc^s]
  __shared__ short sV[2][64 * 64];    // v head-pair [cc][px^s]
  __shared__ short sAO[2][64 * 64];   // attn-out head-pair [px][cc^s]
  __shared__ short sAT[2][4][1024];   // attn weights per wave [n][m^s]
  __shared__ float sB[640];           // rpb table

  const int t = threadIdx.x;
  const int b = blockIdx.x >> 8;
  const int rem = blockIdx.x & 255;
  const int r0 = (rem >> 4) << 3;
  const int c0 = (rem & 15) << 3;     // two 4-wide windows: c0, c0+4
  const int gbase = b * C * HW + r0 * Wd + c0;

  // ---- stage x window as bf16, [px][c] swizzled; px = wv*32 + row*4 + wcol
  #pragma unroll
  for (int it = 0; it < 12; ++it) {
    const int idx = t + it * 256;          // 0..3071
    const int c = idx >> 4;
    const int q4 = (idx & 15) << 2;        // px base, mult of 4
    const int wv = q4 >> 5;
    const int row = (q4 & 31) >> 2;
    const int goff = gbase + c * HW + row * Wd + wv * 4;
    const float4 vr = *(const float4*)(xr + goff);
    const float4 vi = *(const float4*)(xi + goff);
    const float fr[4] = {vr.x, vr.y, vr.z, vr.w};
    const float fi[4] = {vi.x, vi.y, vi.z, vi.w};
    #pragma unroll
    for (int j = 0; j < 4; ++j) {
      const int p = q4 + j;
      const int s = (p & 7) << 3;
      sX[0][p * 192 + (c ^ s)] = (short)f2bf(fr[j]);
      sX[1][p * 192 + (c ^ s)] = (short)f2bf(fi[j]);
    }
  }
  for (int i = t; i < 630; i += 256) sB[i] = rpb[i];
  __syncthreads();

  const int lane = t & 63;
  const int w = t >> 6;
  const int lr = lane & 15;
  const int lg = lane >> 4;

  const int hloc = w >> 1;        // head within pair
  const int wv = w & 1;           // window handled by this wave
  const int ccq = hloc * 32;

  f32x4 apr[3][4] = {}, api[3][4] = {};   // proj accumulators (persist)

  for (int g = 0; g < 3; ++g) {
    // ======== QKV GEMM: 192 rows (q64,k64,v64 of head pair) x 64 px ========
    #pragma unroll
    for (int ob = 0; ob < 3; ++ob) {
      const int lrow = w * 48 + ob * 16;
      const int sec = lrow >> 6;           // 0=q 1=k 2=v
      const int ccb = lrow & 63;
      const int R = sec * 192 + g * 64 + ccb + lr;
      f32x4 dr[4] = {}, di[4] = {};
      #pragma unroll
      for (int ks = 0; ks < 6; ++ks) {
        const int k8 = ks * 32 + lg * 8;
        bf16x8 ar, ai;
        if constexpr (PK) {
          ar = *(const bf16x8*)(wpk + OQKV_R + (size_t)R * C + k8);
          ai = *(const bf16x8*)(wpk + OQKV_I + (size_t)R * C + k8);
        } else {
          const float* wrp = wqkv_r + (size_t)R * C;
          const float* wip = wqkv_i + (size_t)R * C;
          float a[8];
          *(float4*)&a[0] = *(const float4*)(wrp + k8);
          *(float4*)&a[4] = *(const float4*)(wrp + k8 + 4);
          ar = pack8(a);
          *(float4*)&a[0] = *(const float4*)(wip + k8);
          *(float4*)&a[4] = *(const float4*)(wip + k8 + 4);
          ai = pack8(a);
        }
        const bf16x8 ain = negb(ai);
        #pragma unroll
        for (int cb = 0; cb < 4; ++cb) {
          const int px = cb * 16 + lr;
          const int s = (px & 7) << 3;
          const bf16x8 br = *(const bf16x8*)&sX[0][px * 192 + (k8 ^ s)];
          const bf16x8 bi = *(const bf16x8*)&sX[1][px * 192 + (k8 ^ s)];
          dr[cb] = __builtin_amdgcn_mfma_f32_16x16x32_bf16(ar,  br, dr[cb], 0, 0, 0);
          dr[cb] = __builtin_amdgcn_mfma_f32_16x16x32_bf16(ain, bi, dr[cb], 0, 0, 0);
          di[cb] = __builtin_amdgcn_mfma_f32_16x16x32_bf16(ar,  bi, di[cb], 0, 0, 0);
          di[cb] = __builtin_amdgcn_mfma_f32_16x16x32_bf16(ai,  br, di[cb], 0, 0, 0);
        }
      }
      // write D to sQ/sK ([px][cc]) or sV ([cc][px])
      if (sec < 2) {
        short* d0 = sec ? sK[0] : sQ[0];
        short* d1 = sec ? sK[1] : sQ[1];
        #pragma unroll
        for (int cb = 0; cb < 4; ++cb) {
          const int px = cb * 16 + lr;
          const int e = px * 64 + ((ccb + lg * 4) ^ ((px & 7) << 3));
          *(uint2*)&d0[e] = pack4(dr[cb]);
          *(uint2*)&d1[e] = pack4(di[cb]);
        }
      } else {
        #pragma unroll
        for (int cb = 0; cb < 4; ++cb) {
          const int px = cb * 16 + lr;
          #pragma unroll
          for (int r = 0; r < 4; ++r) {
            const int dd = ccb + lg * 4 + r;
            const int e = dd * 64 + (px ^ ((dd & 7) << 3));
            sV[0][e] = (short)f2bf(dr[cb][r]);
            sV[1][e] = (short)f2bf(di[cb][r]);
          }
        }
      }
    }
    __syncthreads();   // bar A: qkv visible

    // ======== attention: wave handles head (2g+hloc), window wv ========
    const int h = 2 * g + hloc;
    {
      bf16x8 aqr[2], aqi[2], bkr[2], bki[2];
      #pragma unroll
      for (int i = 0; i < 2; ++i) {
        const int px = wv * 32 + i * 16 + lr;
        const int e = px * 64 + ((ccq + lg * 8) ^ ((px & 7) << 3));
        aqr[i] = *(const bf16x8*)&sQ[0][e];
        aqi[i] = *(const bf16x8*)&sQ[1][e];
        bkr[i] = *(const bf16x8*)&sK[0][e];
        bki[i] = *(const bf16x8*)&sK[1][e];
      }
      f32x4 sre[2][2], sim[2][2];
      #pragma unroll
      for (int i = 0; i < 2; ++i) {
        #pragma unroll
        for (int j = 0; j < 2; ++j) {
          f32x4 z = {};
          f32x4 re = __builtin_amdgcn_mfma_f32_16x16x32_bf16(aqr[i], bkr[j], z, 0, 0, 0);
          re = __builtin_amdgcn_mfma_f32_16x16x32_bf16(aqi[i], bki[j], re, 0, 0, 0);
          f32x4 im = __builtin_amdgcn_mfma_f32_16x16x32_bf16(aqi[i], bkr[j], z, 0, 0, 0);
          im = __builtin_amdgcn_mfma_f32_16x16x32_bf16(negb(aqr[i]), bki[j], im, 0, 0, 0);
          sre[i][j] = re;
          sim[i][j] = im;
        }
      }
      float re_[2][2][4], im_[2][2][4], mg_[2][2][4];
      #pragma unroll
      for (int i = 0; i < 2; ++i) {
        #pragma unroll
        for (int j = 0; j < 2; ++j) {
          const int m = j * 16 + lr;
          #pragma unroll
          for (int r = 0; r < 4; ++r) {
            const int n = i * 16 + lg * 4 + r;
            const int bidx = ((n >> 2) - (m >> 2) + 7) * 7 + ((n & 3) - (m & 3) + 3);
            const float re = sre[i][j][r] * SCALE + sB[bidx * NH + h];
            const float im = sim[i][j][r] * SCALE;
            re_[i][j][r] = re;
            im_[i][j][r] = im;
            mg_[i][j][r] = sqrtf(re * re + im * im);
          }
        }
      }
      #pragma unroll
      for (int i = 0; i < 2; ++i) {
        #pragma unroll
        for (int r = 0; r < 4; ++r) {
          float mx = fmaxf(mg_[i][0][r], mg_[i][1][r]);
          mx = fmaxf(mx, __shfl_xor(mx, 1));
          mx = fmaxf(mx, __shfl_xor(mx, 2));
          mx = fmaxf(mx, __shfl_xor(mx, 4));
          mx = fmaxf(mx, __shfl_xor(mx, 8));
          const float e0 = expf(mg_[i][0][r] - mx);
          const float e1 = expf(mg_[i][1][r] - mx);
          float se = e0 + e1;
          se += __shfl_xor(se, 1);
          se += __shfl_xor(se, 2);
          se += __shfl_xor(se, 4);
          se += __shfl_xor(se, 8);
          const float inv = 1.f / se;
          const float f0 = e0 * inv / (mg_[i][0][r] + 1e-8f);
          const float f1 = e1 * inv / (mg_[i][1][r] + 1e-8f);
          const int n = i * 16 + lg * 4 + r;
          const int sw = (n & 3) << 3;
          sAT[0][w][n * 32 + (lr ^ sw)]        = (short)f2bf(re_[i][0][r] * f0);
          sAT[1][w][n * 32 + (lr ^ sw)]        = (short)f2bf(im_[i][0][r] * f0);
          sAT[0][w][n * 32 + ((16 + lr) ^ sw)] = (short)f2bf(re_[i][1][r] * f1);
          sAT[1][w][n * 32 + ((16 + lr) ^ sw)] = (short)f2bf(im_[i][1][r] * f1);
        }
      }
      // PV: out[dd][n] = sum_m v[dd][m] * attn[n][m]
      bf16x8 bar_[2], bai_[2];
      #pragma unroll
      for (int j2 = 0; j2 < 2; ++j2) {
        const int n = j2 * 16 + lr;
        const int e = n * 32 + ((lg * 8) ^ ((n & 3) << 3));
        bar_[j2] = *(const bf16x8*)&sAT[0][w][e];
        bai_[j2] = *(const bf16x8*)&sAT[1][w][e];
      }
      #pragma unroll
      for (int i2 = 0; i2 < 2; ++i2) {
        const int dd = ccq + i2 * 16 + lr;
        const int e = dd * 64 + ((wv * 32 + lg * 8) ^ ((dd & 7) << 3));
        const bf16x8 avr = *(const bf16x8*)&sV[0][e];
        const bf16x8 avi = *(const bf16x8*)&sV[1][e];
        const bf16x8 avin = negb(avi);
        #pragma unroll
        for (int j2 = 0; j2 < 2; ++j2) {
          f32x4 z = {};
          f32x4 pr = __builtin_amdgcn_mfma_f32_16x16x32_bf16(avr, bar_[j2], z, 0, 0, 0);
          pr = __builtin_amdgcn_mfma_f32_16x16x32_bf16(avin, bai_[j2], pr, 0, 0, 0);
          f32x4 pi = __builtin_amdgcn_mfma_f32_16x16x32_bf16(avr, bai_[j2], z, 0, 0, 0);
          pi = __builtin_amdgcn_mfma_f32_16x16x32_bf16(avi, bar_[j2], pi, 0, 0, 0);
          const int px = wv * 32 + j2 * 16 + lr;
          const int e2 = px * 64 + ((ccq + i2 * 16 + lg * 4) ^ ((px & 7) << 3));
          *(uint2*)&sAO[0][e2] = pack4(pr);
          *(uint2*)&sAO[1][e2] = pack4(pi);
        }
      }
    }
    __syncthreads();   // bar B: attn-out visible

    // ======== proj accumulation: K = 64 (head pair) ========
    #pragma unroll
    for (int ks = 0; ks < 2; ++ks) {
      const int k8 = ks * 32 + lg * 8;
      bf16x8 pbr[4], pbi[4];
      #pragma unroll
      for (int cb = 0; cb < 4; ++cb) {
        const int px = cb * 16 + lr;
        const int e = px * 64 + (k8 ^ ((px & 7) << 3));
        pbr[cb] = *(const bf16x8*)&sAO[0][e];
        pbi[cb] = *(const bf16x8*)&sAO[1][e];
      }
      #pragma unroll
      for (int ob = 0; ob < 3; ++ob) {
        const int o = w * 48 + ob * 16 + lr;
        bf16x8 ar, ai;
        if constexpr (PK) {
          ar = *(const bf16x8*)(wpk + OPROJ_R + (size_t)o * C + g * 64 + k8);
          ai = *(const bf16x8*)(wpk + OPROJ_I + (size_t)o * C + g * 64 + k8);
        } else {
          const size_t wb = (size_t)o * C + g * 64 + k8;
          float a[8];
          *(float4*)&a[0] = *(const float4*)(wp_r + wb);
          *(float4*)&a[4] = *(const float4*)(wp_r + wb + 4);
          ar = pack8(a);
          *(float4*)&a[0] = *(const float4*)(wp_i + wb);
          *(float4*)&a[4] = *(const float4*)(wp_i + wb + 4);
          ai = pack8(a);
        }
        const bf16x8 ain = negb(ai);
        #pragma unroll
        for (int cb = 0; cb < 4; ++cb) {
          apr[ob][cb] = __builtin_amdgcn_mfma_f32_16x16x32_bf16(ar,  pbr[cb], apr[ob][cb], 0, 0, 0);
          apr[ob][cb] = __builtin_amdgcn_mfma_f32_16x16x32_bf16(ain, pbi[cb], apr[ob][cb], 0, 0, 0);
          api[ob][cb] = __builtin_amdgcn_mfma_f32_16x16x32_bf16(ar,  pbi[cb], api[ob][cb], 0, 0, 0);
          api[ob][cb] = __builtin_amdgcn_mfma_f32_16x16x32_bf16(ai,  pbr[cb], api[ob][cb], 0, 0, 0);
        }
      }
    }
  }

  // ======== epilogue: y = x + proj_out (fp32 residual from global) ========
  #pragma unroll
  for (int ob = 0; ob < 3; ++ob) {
    #pragma unroll
    for (int cb = 0; cb < 4; ++cb) {
      const int px = cb * 16 + lr;
      const int n = px & 31;
      const int off0 = gbase + (n >> 2) * Wd + (px >> 5) * 4 + (n & 3);
      #pragma unroll
      for (int r = 0; r < 4; ++r) {
        const int c = w * 48 + ob * 16 + lg * 4 + r;
        const size_t gg = (size_t)off0 + (size_t)c * HW;
        yr[gg] = xr[gg] + apr[ob][cb][r];
        yi[gg] = xi[gg] + api[ob][cb][r];
      }
    }
  }
}

// ---------------------------------------------------------------------------
// BN stats (unchanged)
// ---------------------------------------------------------------------------
__global__ __launch_bounds__(256) void k_stats(
    const float* __restrict__ src_r, const float* __restrict__ src_i,
    float* __restrict__ mean, float* __restrict__ rstd)
{
  const int c = blockIdx.x;
  const int plane = blockIdx.y;
  const float* src = plane ? src_i : src_r;
  const int t = threadIdx.x;
  double s = 0.0, s2 = 0.0;
  for (int b = 0; b < Bn; ++b) {
    const float* p = src + (size_t)(b * C + c) * HW;
    for (int i = t; i < HW; i += 256) {
      const double v = (double)p[i];
      s += v;
      s2 += v * v;
    }
  }
  __shared__ double ls[256], ls2[256];
  ls[t] = s; ls2[t] = s2;
  __syncthreads();
  for (int off = 128; off > 0; off >>= 1) {
    if (t < off) { ls[t] += ls[t + off]; ls2[t] += ls2[t + off]; }
    __syncthreads();
  }
  if (t == 0) {
    const double inv = 1.0 / (double)(Bn * HW);
    const double m = ls[0] * inv;
    const double var = ls2[0] * inv - m * m;
    mean[plane * C + c] = (float)m;
    rstd[plane * C + c] = (float)(1.0 / sqrt(var + 1e-5));
  }
}

__global__ void k_bnpar(const float* __restrict__ mean, const float* __restrict__ rstd,
                        const float* __restrict__ g_r, const float* __restrict__ b_r,
                        const float* __restrict__ g_i, const float* __restrict__ b_i,
                        float* __restrict__ sc, float* __restrict__ sh)
{
  const int i = blockIdx.x * blockDim.x + threadIdx.x;
  if (i >= 2 * C) return;
  const int plane = i / C, c = i % C;
  const float g = plane ? g_i[c] : g_r[c];
  const float bb = plane ? b_i[c] : b_r[c];
  const float s = rstd[i] * g;
  sc[i] = s;
  sh[i] = bb - mean[i] * s;
}

// ---------------------------------------------------------------------------
// Fused MFMA MLP. Single-buffered sH -> 64KB LDS -> 2 blocks/CU.
// PK=true: direct bf16 weight loads.
// ---------------------------------------------------------------------------
template <bool PK>
__global__ __launch_bounds__(256, 1) void k_mlp(
    float* __restrict__ outp,
    const float* __restrict__ w1_r, const float* __restrict__ w1_i,
    const float* __restrict__ w2_r, const float* __restrict__ w2_i,
    const short* __restrict__ wpk,
    const float* __restrict__ sc1, const float* __restrict__ sh1)
{
  __shared__ short sXm[2][64 * 192];
  __shared__ short sH[2][64 * 64];     // single buffer [plane][p*64 + k^s]

  const int t = threadIdx.x;
  const int pix0 = blockIdx.x * 64;
  const int b = pix0 >> 14;
  const int p0 = pix0 & (HW - 1);
  const float* yrp = outp;
  const float* yip = outp + PLANE;

  #pragma unroll
  for (int it = 0; it < 12; ++it) {
    const int idx = t + it * 256;
    const int c = idx >> 4;
    const int q = (idx & 15) << 2;
    const size_t g = (size_t)(b * C + c) * HW + p0 + q;
    const float4 vr = *(const float4*)(yrp + g);
    const float4 vi = *(const float4*)(yip + g);
    const float srr = sc1[c], hrr = sh1[c];
    const float sii = sc1[C + c], hii = sh1[C + c];
    const float fr[4] = {vr.x * srr + hrr, vr.y * srr + hrr, vr.z * srr + hrr, vr.w * srr + hrr};
    const float fi[4] = {vi.x * sii + hii, vi.y * sii + hii, vi.z * sii + hii, vi.w * sii + hii};
    #pragma unroll
    for (int i2 = 0; i2 < 4; ++i2) {
      const int p = q + i2;
      const int s = (p & 7) << 3;
      sXm[0][p * 192 + (c ^ s)] = (short)f2bf(fr[i2]);
      sXm[1][p * 192 + (c ^ s)] = (short)f2bf(fi[i2]);
    }
  }
  __syncthreads();

  const int lane = t & 63;
  const int w = t >> 6;
  const int lr = lane & 15;
  const int lg = lane >> 4;

  f32x4 acc2r[3][4] = {};
  f32x4 acc2i[3][4] = {};

  for (int hc = 0; hc < 12; ++hc) {
    // ---- GEMM1: h rows [hc*64 + w*16, +16) x 64 px, K=192 ----
    f32x4 hfr[4] = {}, hfi[4] = {};
    #pragma unroll
    for (int ks = 0; ks < 6; ++ks) {
      const int k8 = ks * 32 + lg * 8;
      bf16x8 a1r, a1i;
      if constexpr (PK) {
        a1r = *(const bf16x8*)(wpk + OW1_R + (size_t)(hc * 64 + w * 16 + lr) * C + k8);
        a1i = *(const bf16x8*)(wpk + OW1_I + (size_t)(hc * 64 + w * 16 + lr) * C + k8);
      } else {
        const float* w1rp = w1_r + (size_t)(hc * 64 + w * 16 + lr) * C;
        const float* w1ip = w1_i + (size_t)(hc * 64 + w * 16 + lr) * C;
        float a[8];
        *(float4*)&a[0] = *(const float4*)(w1rp + k8);
        *(float4*)&a[4] = *(const float4*)(w1rp + k8 + 4);
        a1r = pack8(a);
        *(float4*)&a[0] = *(const float4*)(w1ip + k8);
        *(float4*)&a[4] = *(const float4*)(w1ip + k8 + 4);
        a1i = pack8(a);
      }
      const bf16x8 a1in = negb(a1i);
      #pragma unroll
      for (int cb = 0; cb < 4; ++cb) {
        const int p = cb * 16 + lr;
        const int s = (p & 7) << 3;
        const bf16x8 br = *(const bf16x8*)&sXm[0][p * 192 + (k8 ^ s)];
        const bf16x8 bi = *(const bf16x8*)&sXm[1][p * 192 + (k8 ^ s)];
        hfr[cb] = __builtin_amdgcn_mfma_f32_16x16x32_bf16(a1r,  br, hfr[cb], 0, 0, 0);
        hfr[cb] = __builtin_amdgcn_mfma_f32_16x16x32_bf16(a1in, bi, hfr[cb], 0, 0, 0);
        hfi[cb] = __builtin_amdgcn_mfma_f32_16x16x32_bf16(a1r,  bi, hfi[cb], 0, 0, 0);
        hfi[cb] = __builtin_amdgcn_mfma_f32_16x16x32_bf16(a1i,  br, hfi[cb], 0, 0, 0);
      }
    }

    // ---- magnitude GELU; wait for previous GEMM2 reads; write sH ----
    float outr[4][4], outi[4][4];
    #pragma unroll
    for (int cb = 0; cb < 4; ++cb) {
      #pragma unroll
      for (int r = 0; r < 4; ++r) {
        const float re = hfr[cb][r], im = hfi[cb][r];
        const float m = sqrtf(re * re + im * im);
        const float f = 0.5f * m * (1.0f + erff(m * 0.70710678f)) / (m + 1e-8f);
        outr[cb][r] = re * f;
        outi[cb][r] = im * f;
      }
    }
    __syncthreads();   // previous chunk's GEMM2 reads complete
    #pragma unroll
    for (int cb = 0; cb < 4; ++cb) {
      const int p = cb * 16 + lr;
      const int s = (p & 7) << 3;
      const int kb = w * 16 + lg * 4;
      const int e = p * 64 + (kb ^ s);
      *(uint2*)&sH[0][e] = make_uint2(
          (unsigned)f2bf(outr[cb][0]) | ((unsigned)f2bf(outr[cb][1]) << 16),
          (unsigned)f2bf(outr[cb][2]) | ((unsigned)f2bf(outr[cb][3]) << 16));
      *(uint2*)&sH[1][e] = make_uint2(
          (unsigned)f2bf(outi[cb][0]) | ((unsigned)f2bf(outi[cb][1]) << 16),
          (unsigned)f2bf(outi[cb][2]) | ((unsigned)f2bf(outi[cb][3]) << 16));
    }
    __syncthreads();   // sH visible

    // ---- GEMM2: acc2 += W2[:, chunk] . Ht, K=64 ----
    #pragma unroll
    for (int ks2 = 0; ks2 < 2; ++ks2) {
      const int k8 = ks2 * 32 + lg * 8;
      bf16x8 br2[4], bi2[4];
      #pragma unroll
      for (int cb = 0; cb < 4; ++cb) {
        const int p = cb * 16 + lr;
        const int s = (p & 7) << 3;
        br2[cb] = *(const bf16x8*)&sH[0][p * 64 + (k8 ^ s)];
        bi2[cb] = *(const bf16x8*)&sH[1][p * 64 + (k8 ^ s)];
      }
      #pragma unroll
      for (int ob = 0; ob < 3; ++ob) {
        const int row = (w * 3 + ob) * 16 + lr;
        bf16x8 a2r, a2i;
        if constexpr (PK) {
          a2r = *(const bf16x8*)(wpk + OW2_R + (size_t)row * C4 + hc * 64 + k8);
          a2i = *(const bf16x8*)(wpk + OW2_I + (size_t)row * C4 + hc * 64 + k8);
        } else {
          const size_t wbase = (size_t)row * C4 + hc * 64 + k8;
          float a[8];
          *(float4*)&a[0] = *(const float4*)(w2_r + wbase);
          *(float4*)&a[4] = *(const float4*)(w2_r + wbase + 4);
          a2r = pack8(a);
          *(float4*)&a[0] = *(const float4*)(w2_i + wbase);
          *(float4*)&a[4] = *(const float4*)(w2_i + wbase + 4);
          a2i = pack8(a);
        }
        const bf16x8 a2in = negb(a2i);
        #pragma unroll
        for (int cb = 0; cb < 4; ++cb) {
          acc2r[ob][cb] = __builtin_amdgcn_mfma_f32_16x16x32_bf16(a2r,  br2[cb], acc2r[ob][cb], 0, 0, 0);
          acc2r[ob][cb] = __builtin_amdgcn_mfma_f32_16x16x32_bf16(a2in, bi2[cb], acc2r[ob][cb], 0, 0, 0);
          acc2i[ob][cb] = __builtin_amdgcn_mfma_f32_16x16x32_bf16(a2r,  bi2[cb], acc2i[ob][cb], 0, 0, 0);
          acc2i[ob][cb] = __builtin_amdgcn_mfma_f32_16x16x32_bf16(a2i,  br2[cb], acc2i[ob][cb], 0, 0, 0);
        }
      }
    }
  }

  #pragma unroll
  for (int ob = 0; ob < 3; ++ob) {
    #pragma unroll
    for (int cb = 0; cb < 4; ++cb) {
      const int px = p0 + cb * 16 + lr;
      #pragma unroll
      for (int r = 0; r < 4; ++r) {
        const int ch = (w * 3 + ob) * 16 + lg * 4 + r;
        const size_t g = (size_t)(b * C + ch) * HW + px;
        const float res_r = yrp[g] * sc1[ch] + sh1[ch];
        const float res_i = yip[g] * sc1[C + ch] + sh1[C + ch];
        outp[g] = res_r + acc2r[ob][cb][r];
        outp[PLANE + g] = res_i + acc2i[ob][cb][r];
      }
    }
  }
}

// In-place BN2 apply over d_out (both planes).
__global__ __launch_bounds__(256) void k_bnfinal(
    float* __restrict__ xo, const float* __restrict__ sc, const float* __restrict__ sh)
{
  const int total4 = (2 * PLANE) / 4;
  for (int i = blockIdx.x * blockDim.x + threadIdx.x; i < total4; i += gridDim.x * blockDim.x) {
    const int e = i * 4;
    const int plane = (e >= PLANE) ? 1 : 0;
    const int w = plane ? (e - PLANE) : e;
    const int ch = (w >> 14) % C;
    const float s = sc[plane * C + ch], hh = sh[plane * C + ch];
    float4 v = *(float4*)(xo + e);
    v.x = v.x * s + hh;
    v.y = v.y * s + hh;
    v.z = v.z * s + hh;
    v.w = v.w * s + hh;
    *(float4*)(xo + e) = v;
  }
}

}  // namespace

extern "C" void kernel_launch(void* const* d_in, const int* in_sizes, int n_in,
                              void* d_out, int out_size, void* d_ws, size_t ws_size,
                              hipStream_t stream)
{
  (void)in_sizes; (void)n_in; (void)out_size;
  const float* x_real  = (const float*)d_in[0];
  const float* x_imag  = (const float*)d_in[1];
  const float* qkv_wr  = (const float*)d_in[2];
  const float* qkv_wi  = (const float*)d_in[3];
  const float* proj_wr = (const float*)d_in[4];
  const float* proj_wi = (const float*)d_in[5];
  const float* rpb     = (const float*)d_in[6];
  const float* n1_gr   = (const float*)d_in[7];
  const float* n1_br   = (const float*)d_in[8];
  const float* n1_gi   = (const float*)d_in[9];
  const float* n1_bi   = (const float*)d_in[10];
  const float* mlp1_wr = (const float*)d_in[11];
  const float* mlp1_wi = (const float*)d_in[12];
  const float* mlp2_wr = (const float*)d_in[13];
  const float* mlp2_wi = (const float*)d_in[14];
  const float* n2_gr   = (const float*)d_in[15];
  const float* n2_br   = (const float*)d_in[16];
  const float* n2_gi   = (const float*)d_in[17];
  const float* n2_bi   = (const float*)d_in[18];

  const size_t pkBytes = (size_t)PK_TOTAL * 2;          // 1769472
  const bool pk = ws_size >= pkBytes + 3072 * 4;

  short* wpk = (short*)d_ws;
  float* st = pk ? (float*)((char*)d_ws + pkBytes) : (float*)d_ws;
  float* mean1 = st;          float* rstd1 = st + 384;
  float* sc1   = st + 768;    float* sh1   = st + 1152;
  float* mean2 = st + 1536;   float* rstd2 = st + 1920;
  float* sc2   = st + 2304;   float* sh2   = st + 2688;

  float* outp = (float*)d_out;
  float* yr = outp;
  float* yi = outp + PLANE;

  if (pk) {
    k_pack<<<1024, 256, 0, stream>>>(qkv_wr, qkv_wi, proj_wr, proj_wi,
                                     mlp1_wr, mlp1_wi, mlp2_wr, mlp2_wi, wpk);
    k_attn<true><<<1024, 256, 0, stream>>>(x_real, x_imag, qkv_wr, qkv_wi,
                                           proj_wr, proj_wi, wpk, rpb, yr, yi);
  } else {
    k_attn<false><<<1024, 256, 0, stream>>>(x_real, x_imag, qkv_wr, qkv_wi,
                                            proj_wr, proj_wi, nullptr, rpb, yr, yi);
  }
  k_stats<<<dim3(C, 2), 256, 0, stream>>>(yr, yi, mean1, rstd1);
  k_bnpar<<<2, 192, 0, stream>>>(mean1, rstd1, n1_gr, n1_br, n1_gi, n1_bi, sc1, sh1);
  if (pk) {
    k_mlp<true><<<Bn * HW / 64, 256, 0, stream>>>(outp, mlp1_wr, mlp1_wi,
                                                  mlp2_wr, mlp2_wi, wpk, sc1, sh1);
  } else {
    k_mlp<false><<<Bn * HW / 64, 256, 0, stream>>>(outp, mlp1_wr, mlp1_wi,
                                                   mlp2_wr, mlp2_wi, nullptr, sc1, sh1);
  }
  k_stats<<<dim3(C, 2), 256, 0, stream>>>(outp, outp + PLANE, mean2, rstd2);
  k_bnpar<<<2, 192, 0, stream>>>(mean2, rstd2, n2_gr, n2_br, n2_gi, n2_bi, sc2, sh2);
  k_bnfinal<<<2048, 256, 0, stream>>>(outp, sc2, sh2);
}

// Round 6
// 792.849 us; speedup vs baseline: 7.3528x; 1.1955x over previous
//
#include <hip/hip_runtime.h>

namespace {

constexpr int Bn = 4;
constexpr int C  = 192;
constexpr int Wd = 128;
constexpr int HW = 16384;            // 128*128
constexpr int PLANE = Bn * C * HW;   // 12582912
constexpr int NH = 6;
constexpr int HD = 32;
constexpr int C4 = 4 * C;            // 768
constexpr float SCALE = 0.17677669529663687f;  // 32^-0.5

// packed bf16 weight layout in d_ws (short offsets)
constexpr int OQKV_R = 0;            // 576*192
constexpr int OQKV_I = 110592;
constexpr int OPROJ_R = 221184;      // 192*192
constexpr int OPROJ_I = 258048;
constexpr int OW1_R = 294912;        // 768*192
constexpr int OW1_I = 442368;
constexpr int OW2_R = 589824;        // 192*768
constexpr int OW2_I = 737280;
constexpr int PK_TOTAL = 884736;

typedef short bf16x8 __attribute__((ext_vector_type(8)));
typedef float f32x4 __attribute__((ext_vector_type(4)));

__device__ inline unsigned short f2bf(float f) {
  union { float f; unsigned u; } v; v.f = f;
  const unsigned r = v.u + 0x7FFFu + ((v.u >> 16) & 1u);
  return (unsigned short)(r >> 16);
}

__device__ inline bf16x8 pack8(const float* f) {
  union { bf16x8 v; unsigned short s[8]; } x;
#pragma unroll
  for (int j = 0; j < 8; ++j) x.s[j] = f2bf(f[j]);
  return x.v;
}

__device__ inline uint2 pack4(const f32x4 v) {
  return make_uint2((unsigned)f2bf(v[0]) | ((unsigned)f2bf(v[1]) << 16),
                    (unsigned)f2bf(v[2]) | ((unsigned)f2bf(v[3]) << 16));
}

__device__ inline bf16x8 negb(bf16x8 a) {
  union { bf16x8 v; unsigned u[4]; } x;
  x.v = a;
#pragma unroll
  for (int j = 0; j < 4; ++j) x.u[j] ^= 0x80008000u;
  return x.v;
}

// ---------------------------------------------------------------------------
// Pack all weights to bf16 into ws (one pass, ~900K elements).
// ---------------------------------------------------------------------------
__global__ __launch_bounds__(256) void k_pack(
    const float* __restrict__ s0, const float* __restrict__ s1,
    const float* __restrict__ s2, const float* __restrict__ s3,
    const float* __restrict__ s4, const float* __restrict__ s5,
    const float* __restrict__ s6, const float* __restrict__ s7,
    short* __restrict__ dst)
{
  for (int i = blockIdx.x * 256 + threadIdx.x; i < PK_TOTAL; i += gridDim.x * 256) {
    const float* s; int off;
    if (i < OPROJ_R) {
      if (i < OQKV_I) { s = s0; off = i; } else { s = s1; off = i - OQKV_I; }
    } else if (i < OW1_R) {
      if (i < OPROJ_I) { s = s2; off = i - OPROJ_R; } else { s = s3; off = i - OPROJ_I; }
    } else if (i < OW2_R) {
      if (i < OW1_I) { s = s4; off = i - OW1_R; } else { s = s5; off = i - OW1_I; }
    } else {
      if (i < OW2_I) { s = s6; off = i - OW2_R; } else { s = s7; off = i - OW2_I; }
    }
    dst[i] = (short)f2bf(s[off]);
  }
}

// ---------------------------------------------------------------------------
// Stage 1 (MFMA): windowed complex attention + proj + residual -> y in d_out.
// Block = 2 windows (64 px), 512 threads (8 waves => 2 waves/SIMD).
// Wave split: (wr,wc)=(w>>1,w&1): wr owns row-tiles, wc owns a pixel half.
// ---------------------------------------------------------------------------
template <bool PK>
__global__ __launch_bounds__(512, 2) void k_attn(
    const float* __restrict__ xr, const float* __restrict__ xi,
    const float* __restrict__ wqkv_r, const float* __restrict__ wqkv_i,
    const float* __restrict__ wp_r, const float* __restrict__ wp_i,
    const short* __restrict__ wpk,
    const float* __restrict__ rpb,
    float* __restrict__ yr, float* __restrict__ yi)
{
  __shared__ short sX[2][64 * 192];   // x window bf16 [px][c^s]
  __shared__ short sQ[2][64 * 64];    // q head-pair [px][cc^s]
  __shared__ short sK[2][64 * 64];    // k head-pair [px][cc^s]
  __shared__ short sV[2][64 * 64];    // v head-pair [cc][px^s]
  __shared__ short sAO[2][64 * 64];   // attn-out head-pair [px][cc^s]
  __shared__ short sAT[2][4][1024];   // attn weights per task [n][m^s]
  __shared__ float sB[640];           // rpb table

  const int t = threadIdx.x;
  const int b = blockIdx.x >> 8;
  const int rem = blockIdx.x & 255;
  const int r0 = (rem >> 4) << 3;
  const int c0 = (rem & 15) << 3;     // two 4-wide windows: c0, c0+4
  const int gbase = b * C * HW + r0 * Wd + c0;

  // ---- stage x window as bf16, [px][c] swizzled; px = wv*32 + row*4 + wcol
  #pragma unroll
  for (int it = 0; it < 6; ++it) {
    const int idx = t + it * 512;          // 0..3071
    const int c = idx >> 4;
    const int q4 = (idx & 15) << 2;        // px base, mult of 4
    const int wvs = q4 >> 5;
    const int row = (q4 & 31) >> 2;
    const int goff = gbase + c * HW + row * Wd + wvs * 4;
    const float4 vr = *(const float4*)(xr + goff);
    const float4 vi = *(const float4*)(xi + goff);
    const float fr[4] = {vr.x, vr.y, vr.z, vr.w};
    const float fi[4] = {vi.x, vi.y, vi.z, vi.w};
    #pragma unroll
    for (int j = 0; j < 4; ++j) {
      const int p = q4 + j;
      const int s = (p & 7) << 3;
      sX[0][p * 192 + (c ^ s)] = (short)f2bf(fr[j]);
      sX[1][p * 192 + (c ^ s)] = (short)f2bf(fi[j]);
    }
  }
  for (int i = t; i < 630; i += 512) sB[i] = rpb[i];
  __syncthreads();

  const int lane = t & 63;
  const int w = t >> 6;           // 0..7
  const int lr = lane & 15;
  const int lg = lane >> 4;

  const int wr = w >> 1;          // 0..3 row-tile group
  const int wc = w & 1;           // 0..1 pixel half
  // attention mapping
  const int task = w >> 1;        // 0..3 = (hloc, wv)
  const int half = w & 1;         // n-tile half
  const int hloc = task >> 1;
  const int wv = task & 1;
  const int ccq = hloc * 32;

  f32x4 apr[3][2] = {}, api[3][2] = {};   // proj accumulators (persist)

  for (int g = 0; g < 3; ++g) {
    // ======== QKV GEMM: 192 rows (q64,k64,v64 of head pair) x 64 px ========
    #pragma unroll
    for (int ob = 0; ob < 3; ++ob) {
      const int lrow = wr * 48 + ob * 16;
      const int sec = lrow >> 6;           // 0=q 1=k 2=v
      const int ccb = lrow & 63;
      const int R = sec * 192 + g * 64 + ccb + lr;
      f32x4 dr[2] = {}, di[2] = {};
      #pragma unroll
      for (int ks = 0; ks < 6; ++ks) {
        const int k8 = ks * 32 + lg * 8;
        bf16x8 ar, ai;
        if constexpr (PK) {
          ar = *(const bf16x8*)(wpk + OQKV_R + (size_t)R * C + k8);
          ai = *(const bf16x8*)(wpk + OQKV_I + (size_t)R * C + k8);
        } else {
          const float* wrp = wqkv_r + (size_t)R * C;
          const float* wip = wqkv_i + (size_t)R * C;
          float a[8];
          *(float4*)&a[0] = *(const float4*)(wrp + k8);
          *(float4*)&a[4] = *(const float4*)(wrp + k8 + 4);
          ar = pack8(a);
          *(float4*)&a[0] = *(const float4*)(wip + k8);
          *(float4*)&a[4] = *(const float4*)(wip + k8 + 4);
          ai = pack8(a);
        }
        const bf16x8 ain = negb(ai);
        #pragma unroll
        for (int cb = 0; cb < 2; ++cb) {
          const int px = (wc * 2 + cb) * 16 + lr;
          const int s = (px & 7) << 3;
          const bf16x8 br = *(const bf16x8*)&sX[0][px * 192 + (k8 ^ s)];
          const bf16x8 bi = *(const bf16x8*)&sX[1][px * 192 + (k8 ^ s)];
          dr[cb] = __builtin_amdgcn_mfma_f32_16x16x32_bf16(ar,  br, dr[cb], 0, 0, 0);
          dr[cb] = __builtin_amdgcn_mfma_f32_16x16x32_bf16(ain, bi, dr[cb], 0, 0, 0);
          di[cb] = __builtin_amdgcn_mfma_f32_16x16x32_bf16(ar,  bi, di[cb], 0, 0, 0);
          di[cb] = __builtin_amdgcn_mfma_f32_16x16x32_bf16(ai,  br, di[cb], 0, 0, 0);
        }
      }
      // write D to sQ/sK ([px][cc]) or sV ([cc][px])
      if (sec < 2) {
        short* d0 = sec ? sK[0] : sQ[0];
        short* d1 = sec ? sK[1] : sQ[1];
        #pragma unroll
        for (int cb = 0; cb < 2; ++cb) {
          const int px = (wc * 2 + cb) * 16 + lr;
          const int e = px * 64 + ((ccb + lg * 4) ^ ((px & 7) << 3));
          *(uint2*)&d0[e] = pack4(dr[cb]);
          *(uint2*)&d1[e] = pack4(di[cb]);
        }
      } else {
        #pragma unroll
        for (int cb = 0; cb < 2; ++cb) {
          const int px = (wc * 2 + cb) * 16 + lr;
          #pragma unroll
          for (int r = 0; r < 4; ++r) {
            const int dd = ccb + lg * 4 + r;
            const int e = dd * 64 + (px ^ ((dd & 7) << 3));
            sV[0][e] = (short)f2bf(dr[cb][r]);
            sV[1][e] = (short)f2bf(di[cb][r]);
          }
        }
      }
    }
    __syncthreads();   // bar A: qkv visible

    // ======== attention: wave = (task, half) = head (2g+hloc), window wv,
    //          n-tile half ========
    const int h = 2 * g + hloc;
    {
      // Q A-frag (n rows of this half) / K B-frags (m cols 0..31)
      bf16x8 aqr, aqi, bkr[2], bki[2];
      {
        const int pxq = wv * 32 + half * 16 + lr;
        const int eq = pxq * 64 + ((ccq + lg * 8) ^ ((pxq & 7) << 3));
        aqr = *(const bf16x8*)&sQ[0][eq];
        aqi = *(const bf16x8*)&sQ[1][eq];
      }
      #pragma unroll
      for (int j = 0; j < 2; ++j) {
        const int pxk = wv * 32 + j * 16 + lr;
        const int ek = pxk * 64 + ((ccq + lg * 8) ^ ((pxk & 7) << 3));
        bkr[j] = *(const bf16x8*)&sK[0][ek];
        bki[j] = *(const bf16x8*)&sK[1][ek];
      }
      f32x4 sre[2], sim[2];
      #pragma unroll
      for (int j = 0; j < 2; ++j) {
        f32x4 z = {};
        f32x4 re = __builtin_amdgcn_mfma_f32_16x16x32_bf16(aqr, bkr[j], z, 0, 0, 0);
        re = __builtin_amdgcn_mfma_f32_16x16x32_bf16(aqi, bki[j], re, 0, 0, 0);
        f32x4 im = __builtin_amdgcn_mfma_f32_16x16x32_bf16(aqi, bkr[j], z, 0, 0, 0);
        im = __builtin_amdgcn_mfma_f32_16x16x32_bf16(negb(aqr), bki[j], im, 0, 0, 0);
        sre[j] = re;
        sim[j] = im;
      }
      float re_[2][4], im_[2][4], mg_[2][4];
      #pragma unroll
      for (int j = 0; j < 2; ++j) {
        const int m = j * 16 + lr;
        #pragma unroll
        for (int r = 0; r < 4; ++r) {
          const int n = half * 16 + lg * 4 + r;
          const int bidx = ((n >> 2) - (m >> 2) + 7) * 7 + ((n & 3) - (m & 3) + 3);
          const float re = sre[j][r] * SCALE + sB[bidx * NH + h];
          const float im = sim[j][r] * SCALE;
          re_[j][r] = re;
          im_[j][r] = im;
          mg_[j][r] = sqrtf(re * re + im * im);
        }
      }
      #pragma unroll
      for (int r = 0; r < 4; ++r) {
        float mx = fmaxf(mg_[0][r], mg_[1][r]);
        mx = fmaxf(mx, __shfl_xor(mx, 1));
        mx = fmaxf(mx, __shfl_xor(mx, 2));
        mx = fmaxf(mx, __shfl_xor(mx, 4));
        mx = fmaxf(mx, __shfl_xor(mx, 8));
        const float e0 = expf(mg_[0][r] - mx);
        const float e1 = expf(mg_[1][r] - mx);
        float se = e0 + e1;
        se += __shfl_xor(se, 1);
        se += __shfl_xor(se, 2);
        se += __shfl_xor(se, 4);
        se += __shfl_xor(se, 8);
        const float inv = 1.f / se;
        const float f0 = e0 * inv / (mg_[0][r] + 1e-8f);
        const float f1 = e1 * inv / (mg_[1][r] + 1e-8f);
        const int n = half * 16 + lg * 4 + r;
        const int sw = (n & 3) << 3;
        sAT[0][task][n * 32 + (lr ^ sw)]        = (short)f2bf(re_[0][r] * f0);
        sAT[1][task][n * 32 + (lr ^ sw)]        = (short)f2bf(im_[0][r] * f0);
        sAT[0][task][n * 32 + ((16 + lr) ^ sw)] = (short)f2bf(re_[1][r] * f1);
        sAT[1][task][n * 32 + ((16 + lr) ^ sw)] = (short)f2bf(im_[1][r] * f1);
      }
      // PV: out[dd][n] = sum_m v[dd][m] * attn[n][m], n in this half
      bf16x8 bar_, bai_;
      {
        const int n = half * 16 + lr;
        const int e = n * 32 + ((lg * 8) ^ ((n & 3) << 3));
        bar_ = *(const bf16x8*)&sAT[0][task][e];
        bai_ = *(const bf16x8*)&sAT[1][task][e];
      }
      #pragma unroll
      for (int i2 = 0; i2 < 2; ++i2) {
        const int dd = ccq + i2 * 16 + lr;
        const int e = dd * 64 + ((wv * 32 + lg * 8) ^ ((dd & 7) << 3));
        const bf16x8 avr = *(const bf16x8*)&sV[0][e];
        const bf16x8 avi = *(const bf16x8*)&sV[1][e];
        const bf16x8 avin = negb(avi);
        f32x4 z = {};
        f32x4 pr = __builtin_amdgcn_mfma_f32_16x16x32_bf16(avr, bar_, z, 0, 0, 0);
        pr = __builtin_amdgcn_mfma_f32_16x16x32_bf16(avin, bai_, pr, 0, 0, 0);
        f32x4 pi = __builtin_amdgcn_mfma_f32_16x16x32_bf16(avr, bai_, z, 0, 0, 0);
        pi = __builtin_amdgcn_mfma_f32_16x16x32_bf16(avi, bar_, pi, 0, 0, 0);
        const int px = wv * 32 + half * 16 + lr;
        const int e2 = px * 64 + ((ccq + i2 * 16 + lg * 4) ^ ((px & 7) << 3));
        *(uint2*)&sAO[0][e2] = pack4(pr);
        *(uint2*)&sAO[1][e2] = pack4(pi);
      }
    }
    __syncthreads();   // bar B: attn-out visible

    // ======== proj accumulation: K = 64 (head pair) ========
    #pragma unroll
    for (int ks = 0; ks < 2; ++ks) {
      const int k8 = ks * 32 + lg * 8;
      bf16x8 pbr[2], pbi[2];
      #pragma unroll
      for (int cb = 0; cb < 2; ++cb) {
        const int px = (wc * 2 + cb) * 16 + lr;
        const int e = px * 64 + (k8 ^ ((px & 7) << 3));
        pbr[cb] = *(const bf16x8*)&sAO[0][e];
        pbi[cb] = *(const bf16x8*)&sAO[1][e];
      }
      #pragma unroll
      for (int ob = 0; ob < 3; ++ob) {
        const int o = wr * 48 + ob * 16 + lr;
        bf16x8 ar, ai;
        if constexpr (PK) {
          ar = *(const bf16x8*)(wpk + OPROJ_R + (size_t)o * C + g * 64 + k8);
          ai = *(const bf16x8*)(wpk + OPROJ_I + (size_t)o * C + g * 64 + k8);
        } else {
          const size_t wb = (size_t)o * C + g * 64 + k8;
          float a[8];
          *(float4*)&a[0] = *(const float4*)(wp_r + wb);
          *(float4*)&a[4] = *(const float4*)(wp_r + wb + 4);
          ar = pack8(a);
          *(float4*)&a[0] = *(const float4*)(wp_i + wb);
          *(float4*)&a[4] = *(const float4*)(wp_i + wb + 4);
          ai = pack8(a);
        }
        const bf16x8 ain = negb(ai);
        #pragma unroll
        for (int cb = 0; cb < 2; ++cb) {
          apr[ob][cb] = __builtin_amdgcn_mfma_f32_16x16x32_bf16(ar,  pbr[cb], apr[ob][cb], 0, 0, 0);
          apr[ob][cb] = __builtin_amdgcn_mfma_f32_16x16x32_bf16(ain, pbi[cb], apr[ob][cb], 0, 0, 0);
          api[ob][cb] = __builtin_amdgcn_mfma_f32_16x16x32_bf16(ar,  pbi[cb], api[ob][cb], 0, 0, 0);
          api[ob][cb] = __builtin_amdgcn_mfma_f32_16x16x32_bf16(ai,  pbr[cb], api[ob][cb], 0, 0, 0);
        }
      }
    }
  }

  // ======== epilogue: y = x + proj_out (fp32 residual from global) ========
  #pragma unroll
  for (int ob = 0; ob < 3; ++ob) {
    #pragma unroll
    for (int cb = 0; cb < 2; ++cb) {
      const int px = (wc * 2 + cb) * 16 + lr;
      const int n = px & 31;
      const int off0 = gbase + (n >> 2) * Wd + (px >> 5) * 4 + (n & 3);
      #pragma unroll
      for (int r = 0; r < 4; ++r) {
        const int c = wr * 48 + ob * 16 + lg * 4 + r;
        const size_t gg = (size_t)off0 + (size_t)c * HW;
        yr[gg] = xr[gg] + apr[ob][cb][r];
        yi[gg] = xi[gg] + api[ob][cb][r];
      }
    }
  }
}

// ---------------------------------------------------------------------------
// BN stats (unchanged)
// ---------------------------------------------------------------------------
__global__ __launch_bounds__(256) void k_stats(
    const float* __restrict__ src_r, const float* __restrict__ src_i,
    float* __restrict__ mean, float* __restrict__ rstd)
{
  const int c = blockIdx.x;
  const int plane = blockIdx.y;
  const float* src = plane ? src_i : src_r;
  const int t = threadIdx.x;
  double s = 0.0, s2 = 0.0;
  for (int b = 0; b < Bn; ++b) {
    const float* p = src + (size_t)(b * C + c) * HW;
    for (int i = t; i < HW; i += 256) {
      const double v = (double)p[i];
      s += v;
      s2 += v * v;
    }
  }
  __shared__ double ls[256], ls2[256];
  ls[t] = s; ls2[t] = s2;
  __syncthreads();
  for (int off = 128; off > 0; off >>= 1) {
    if (t < off) { ls[t] += ls[t + off]; ls2[t] += ls2[t + off]; }
    __syncthreads();
  }
  if (t == 0) {
    const double inv = 1.0 / (double)(Bn * HW);
    const double m = ls[0] * inv;
    const double var = ls2[0] * inv - m * m;
    mean[plane * C + c] = (float)m;
    rstd[plane * C + c] = (float)(1.0 / sqrt(var + 1e-5));
  }
}

__global__ void k_bnpar(const float* __restrict__ mean, const float* __restrict__ rstd,
                        const float* __restrict__ g_r, const float* __restrict__ b_r,
                        const float* __restrict__ g_i, const float* __restrict__ b_i,
                        float* __restrict__ sc, float* __restrict__ sh)
{
  const int i = blockIdx.x * blockDim.x + threadIdx.x;
  if (i >= 2 * C) return;
  const int plane = i / C, c = i % C;
  const float g = plane ? g_i[c] : g_r[c];
  const float bb = plane ? b_i[c] : b_r[c];
  const float s = rstd[i] * g;
  sc[i] = s;
  sh[i] = bb - mean[i] * s;
}

// ---------------------------------------------------------------------------
// Fused MFMA MLP. 512 threads (8 waves => 2 waves/SIMD), 64KB LDS.
// Wave split: (wr,wc)=(w>>1,w&1): wr row-tiles, wc pixel half.
// ---------------------------------------------------------------------------
template <bool PK>
__global__ __launch_bounds__(512, 2) void k_mlp(
    float* __restrict__ outp,
    const float* __restrict__ w1_r, const float* __restrict__ w1_i,
    const float* __restrict__ w2_r, const float* __restrict__ w2_i,
    const short* __restrict__ wpk,
    const float* __restrict__ sc1, const float* __restrict__ sh1)
{
  __shared__ short sXm[2][64 * 192];
  __shared__ short sH[2][64 * 64];     // single buffer [plane][p*64 + k^s]

  const int t = threadIdx.x;
  const int pix0 = blockIdx.x * 64;
  const int b = pix0 >> 14;
  const int p0 = pix0 & (HW - 1);
  const float* yrp = outp;
  const float* yip = outp + PLANE;

  #pragma unroll
  for (int it = 0; it < 6; ++it) {
    const int idx = t + it * 512;
    const int c = idx >> 4;
    const int q = (idx & 15) << 2;
    const size_t g = (size_t)(b * C + c) * HW + p0 + q;
    const float4 vr = *(const float4*)(yrp + g);
    const float4 vi = *(const float4*)(yip + g);
    const float srr = sc1[c], hrr = sh1[c];
    const float sii = sc1[C + c], hii = sh1[C + c];
    const float fr[4] = {vr.x * srr + hrr, vr.y * srr + hrr, vr.z * srr + hrr, vr.w * srr + hrr};
    const float fi[4] = {vi.x * sii + hii, vi.y * sii + hii, vi.z * sii + hii, vi.w * sii + hii};
    #pragma unroll
    for (int i2 = 0; i2 < 4; ++i2) {
      const int p = q + i2;
      const int s = (p & 7) << 3;
      sXm[0][p * 192 + (c ^ s)] = (short)f2bf(fr[i2]);
      sXm[1][p * 192 + (c ^ s)] = (short)f2bf(fi[i2]);
    }
  }
  __syncthreads();

  const int lane = t & 63;
  const int w = t >> 6;         // 0..7
  const int lr = lane & 15;
  const int lg = lane >> 4;
  const int wr = w >> 1;        // 0..3
  const int wc = w & 1;         // 0..1

  f32x4 acc2r[3][2] = {};
  f32x4 acc2i[3][2] = {};

  for (int hc = 0; hc < 12; ++hc) {
    // ---- GEMM1: h rows [hc*64 + wr*16, +16) x 32 px (wc half), K=192 ----
    f32x4 hfr[2] = {}, hfi[2] = {};
    #pragma unroll
    for (int ks = 0; ks < 6; ++ks) {
      const int k8 = ks * 32 + lg * 8;
      bf16x8 a1r, a1i;
      if constexpr (PK) {
        a1r = *(const bf16x8*)(wpk + OW1_R + (size_t)(hc * 64 + wr * 16 + lr) * C + k8);
        a1i = *(const bf16x8*)(wpk + OW1_I + (size_t)(hc * 64 + wr * 16 + lr) * C + k8);
      } else {
        const float* w1rp = w1_r + (size_t)(hc * 64 + wr * 16 + lr) * C;
        const float* w1ip = w1_i + (size_t)(hc * 64 + wr * 16 + lr) * C;
        float a[8];
        *(float4*)&a[0] = *(const float4*)(w1rp + k8);
        *(float4*)&a[4] = *(const float4*)(w1rp + k8 + 4);
        a1r = pack8(a);
        *(float4*)&a[0] = *(const float4*)(w1ip + k8);
        *(float4*)&a[4] = *(const float4*)(w1ip + k8 + 4);
        a1i = pack8(a);
      }
      const bf16x8 a1in = negb(a1i);
      #pragma unroll
      for (int cb = 0; cb < 2; ++cb) {
        const int p = (wc * 2 + cb) * 16 + lr;
        const int s = (p & 7) << 3;
        const bf16x8 br = *(const bf16x8*)&sXm[0][p * 192 + (k8 ^ s)];
        const bf16x8 bi = *(const bf16x8*)&sXm[1][p * 192 + (k8 ^ s)];
        hfr[cb] = __builtin_amdgcn_mfma_f32_16x16x32_bf16(a1r,  br, hfr[cb], 0, 0, 0);
        hfr[cb] = __builtin_amdgcn_mfma_f32_16x16x32_bf16(a1in, bi, hfr[cb], 0, 0, 0);
        hfi[cb] = __builtin_amdgcn_mfma_f32_16x16x32_bf16(a1r,  bi, hfi[cb], 0, 0, 0);
        hfi[cb] = __builtin_amdgcn_mfma_f32_16x16x32_bf16(a1i,  br, hfi[cb], 0, 0, 0);
      }
    }

    // ---- magnitude GELU (h * Phi(m); the /(m+eps)*m factor is within 1e-8)
    float outr[2][4], outi[2][4];
    #pragma unroll
    for (int cb = 0; cb < 2; ++cb) {
      #pragma unroll
      for (int r = 0; r < 4; ++r) {
        const float re = hfr[cb][r], im = hfi[cb][r];
        const float m = sqrtf(re * re + im * im);
        const float f = 0.5f * (1.0f + erff(m * 0.70710678f));
        outr[cb][r] = re * f;
        outi[cb][r] = im * f;
      }
    }
    __syncthreads();   // previous chunk's GEMM2 reads complete
    #pragma unroll
    for (int cb = 0; cb < 2; ++cb) {
      const int p = (wc * 2 + cb) * 16 + lr;
      const int s = (p & 7) << 3;
      const int kb = wr * 16 + lg * 4;
      const int e = p * 64 + (kb ^ s);
      *(uint2*)&sH[0][e] = make_uint2(
          (unsigned)f2bf(outr[cb][0]) | ((unsigned)f2bf(outr[cb][1]) << 16),
          (unsigned)f2bf(outr[cb][2]) | ((unsigned)f2bf(outr[cb][3]) << 16));
      *(uint2*)&sH[1][e] = make_uint2(
          (unsigned)f2bf(outi[cb][0]) | ((unsigned)f2bf(outi[cb][1]) << 16),
          (unsigned)f2bf(outi[cb][2]) | ((unsigned)f2bf(outi[cb][3]) << 16));
    }
    __syncthreads();   // sH visible

    // ---- GEMM2: acc2 += W2[:, chunk] . Ht, K=64 ----
    #pragma unroll
    for (int ks2 = 0; ks2 < 2; ++ks2) {
      const int k8 = ks2 * 32 + lg * 8;
      bf16x8 br2[2], bi2[2];
      #pragma unroll
      for (int cb = 0; cb < 2; ++cb) {
        const int p = (wc * 2 + cb) * 16 + lr;
        const int s = (p & 7) << 3;
        br2[cb] = *(const bf16x8*)&sH[0][p * 64 + (k8 ^ s)];
        bi2[cb] = *(const bf16x8*)&sH[1][p * 64 + (k8 ^ s)];
      }
      #pragma unroll
      for (int ob = 0; ob < 3; ++ob) {
        const int row = (wr * 3 + ob) * 16 + lr;
        bf16x8 a2r, a2i;
        if constexpr (PK) {
          a2r = *(const bf16x8*)(wpk + OW2_R + (size_t)row * C4 + hc * 64 + k8);
          a2i = *(const bf16x8*)(wpk + OW2_I + (size_t)row * C4 + hc * 64 + k8);
        } else {
          const size_t wbase = (size_t)row * C4 + hc * 64 + k8;
          float a[8];
          *(float4*)&a[0] = *(const float4*)(w2_r + wbase);
          *(float4*)&a[4] = *(const float4*)(w2_r + wbase + 4);
          a2r = pack8(a);
          *(float4*)&a[0] = *(const float4*)(w2_i + wbase);
          *(float4*)&a[4] = *(const float4*)(w2_i + wbase + 4);
          a2i = pack8(a);
        }
        const bf16x8 a2in = negb(a2i);
        #pragma unroll
        for (int cb = 0; cb < 2; ++cb) {
          acc2r[ob][cb] = __builtin_amdgcn_mfma_f32_16x16x32_bf16(a2r,  br2[cb], acc2r[ob][cb], 0, 0, 0);
          acc2r[ob][cb] = __builtin_amdgcn_mfma_f32_16x16x32_bf16(a2in, bi2[cb], acc2r[ob][cb], 0, 0, 0);
          acc2i[ob][cb] = __builtin_amdgcn_mfma_f32_16x16x32_bf16(a2r,  bi2[cb], acc2i[ob][cb], 0, 0, 0);
          acc2i[ob][cb] = __builtin_amdgcn_mfma_f32_16x16x32_bf16(a2i,  br2[cb], acc2i[ob][cb], 0, 0, 0);
        }
      }
    }
  }

  #pragma unroll
  for (int ob = 0; ob < 3; ++ob) {
    #pragma unroll
    for (int cb = 0; cb < 2; ++cb) {
      const int px = p0 + (wc * 2 + cb) * 16 + lr;
      #pragma unroll
      for (int r = 0; r < 4; ++r) {
        const int ch = (wr * 3 + ob) * 16 + lg * 4 + r;
        const size_t g = (size_t)(b * C + ch) * HW + px;
        const float res_r = yrp[g] * sc1[ch] + sh1[ch];
        const float res_i = yip[g] * sc1[C + ch] + sh1[C + ch];
        outp[g] = res_r + acc2r[ob][cb][r];
        outp[PLANE + g] = res_i + acc2i[ob][cb][r];
      }
    }
  }
}

// In-place BN2 apply over d_out (both planes).
__global__ __launch_bounds__(256) void k_bnfinal(
    float* __restrict__ xo, const float* __restrict__ sc, const float* __restrict__ sh)
{
  const int total4 = (2 * PLANE) / 4;
  for (int i = blockIdx.x * blockDim.x + threadIdx.x; i < total4; i += gridDim.x * blockDim.x) {
    const int e = i * 4;
    const int plane = (e >= PLANE) ? 1 : 0;
    const int w = plane ? (e - PLANE) : e;
    const int ch = (w >> 14) % C;
    const float s = sc[plane * C + ch], hh = sh[plane * C + ch];
    float4 v = *(float4*)(xo + e);
    v.x = v.x * s + hh;
    v.y = v.y * s + hh;
    v.z = v.z * s + hh;
    v.w = v.w * s + hh;
    *(float4*)(xo + e) = v;
  }
}

}  // namespace

extern "C" void kernel_launch(void* const* d_in, const int* in_sizes, int n_in,
                              void* d_out, int out_size, void* d_ws, size_t ws_size,
                              hipStream_t stream)
{
  (void)in_sizes; (void)n_in; (void)out_size;
  const float* x_real  = (const float*)d_in[0];
  const float* x_imag  = (const float*)d_in[1];
  const float* qkv_wr  = (const float*)d_in[2];
  const float* qkv_wi  = (const float*)d_in[3];
  const float* proj_wr = (const float*)d_in[4];
  const float* proj_wi = (const float*)d_in[5];
  const float* rpb     = (const float*)d_in[6];
  const float* n1_gr   = (const float*)d_in[7];
  const float* n1_br   = (const float*)d_in[8];
  const float* n1_gi   = (const float*)d_in[9];
  const float* n1_bi   = (const float*)d_in[10];
  const float* mlp1_wr = (const float*)d_in[11];
  const float* mlp1_wi = (const float*)d_in[12];
  const float* mlp2_wr = (const float*)d_in[13];
  const float* mlp2_wi = (const float*)d_in[14];
  const float* n2_gr   = (const float*)d_in[15];
  const float* n2_br   = (const float*)d_in[16];
  const float* n2_gi   = (const float*)d_in[17];
  const float* n2_bi   = (const float*)d_in[18];

  const size_t pkBytes = (size_t)PK_TOTAL * 2;          // 1769472
  const bool pk = ws_size >= pkBytes + 3072 * 4;

  short* wpk = (short*)d_ws;
  float* st = pk ? (float*)((char*)d_ws + pkBytes) : (float*)d_ws;
  float* mean1 = st;          float* rstd1 = st + 384;
  float* sc1   = st + 768;    float* sh1   = st + 1152;
  float* mean2 = st + 1536;   float* rstd2 = st + 1920;
  float* sc2   = st + 2304;   float* sh2   = st + 2688;

  float* outp = (float*)d_out;
  float* yr = outp;
  float* yi = outp + PLANE;

  if (pk) {
    k_pack<<<1024, 256, 0, stream>>>(qkv_wr, qkv_wi, proj_wr, proj_wi,
                                     mlp1_wr, mlp1_wi, mlp2_wr, mlp2_wi, wpk);
    k_attn<true><<<1024, 512, 0, stream>>>(x_real, x_imag, qkv_wr, qkv_wi,
                                           proj_wr, proj_wi, wpk, rpb, yr, yi);
  } else {
    k_attn<false><<<1024, 512, 0, stream>>>(x_real, x_imag, qkv_wr, qkv_wi,
                                            proj_wr, proj_wi, nullptr, rpb, yr, yi);
  }
  k_stats<<<dim3(C, 2), 256, 0, stream>>>(yr, yi, mean1, rstd1);
  k_bnpar<<<2, 192, 0, stream>>>(mean1, rstd1, n1_gr, n1_br, n1_gi, n1_bi, sc1, sh1);
  if (pk) {
    k_mlp<true><<<Bn * HW / 64, 512, 0, stream>>>(outp, mlp1_wr, mlp1_wi,
                                                  mlp2_wr, mlp2_wi, wpk, sc1, sh1);
  } else {
    k_mlp<false><<<Bn * HW / 64, 512, 0, stream>>>(outp, mlp1_wr, mlp1_wi,
                                                   mlp2_wr, mlp2_wi, nullptr, sc1, sh1);
  }
  k_stats<<<dim3(C, 2), 256, 0, stream>>>(outp, outp + PLANE, mean2, rstd2);
  k_bnpar<<<2, 192, 0, stream>>>(mean2, rstd2, n2_gr, n2_br, n2_gi, n2_bi, sc2, sh2);
  k_bnfinal<<<2048, 256, 0, stream>>>(outp, sc2, sh2);
}

// Round 7
// 737.587 us; speedup vs baseline: 7.9037x; 1.0749x over previous
//
#include <hip/hip_runtime.h>

namespace {

constexpr int Bn = 4;
constexpr int C  = 192;
constexpr int Wd = 128;
constexpr int HW = 16384;            // 128*128
constexpr int PLANE = Bn * C * HW;   // 12582912
constexpr int NH = 6;
constexpr int HD = 32;
constexpr int C4 = 4 * C;            // 768
constexpr float SCALE = 0.17677669529663687f;  // 32^-0.5

// packed bf16 weight layout in d_ws (short offsets)
constexpr int OQKV_R = 0;            // 576*192
constexpr int OQKV_I = 110592;
constexpr int OPROJ_R = 221184;      // 192*192
constexpr int OPROJ_I = 258048;
constexpr int OW1_R = 294912;        // 768*192
constexpr int OW1_I = 442368;
constexpr int OW2_R = 589824;        // 192*768
constexpr int OW2_I = 737280;
constexpr int PK_TOTAL = 884736;

typedef short bf16x8 __attribute__((ext_vector_type(8)));
typedef float f32x4 __attribute__((ext_vector_type(4)));

__device__ inline unsigned short f2bf(float f) {
  union { float f; unsigned u; } v; v.f = f;
  const unsigned r = v.u + 0x7FFFu + ((v.u >> 16) & 1u);
  return (unsigned short)(r >> 16);
}

__device__ inline float bf2f(short s) {
  union { unsigned u; float f; } v;
  v.u = ((unsigned)(unsigned short)s) << 16;
  return v.f;
}

__device__ inline bf16x8 pack8(const float* f) {
  union { bf16x8 v; unsigned short s[8]; } x;
#pragma unroll
  for (int j = 0; j < 8; ++j) x.s[j] = f2bf(f[j]);
  return x.v;
}

__device__ inline uint2 pack4(const f32x4 v) {
  return make_uint2((unsigned)f2bf(v[0]) | ((unsigned)f2bf(v[1]) << 16),
                    (unsigned)f2bf(v[2]) | ((unsigned)f2bf(v[3]) << 16));
}

__device__ inline bf16x8 negb(bf16x8 a) {
  union { bf16x8 v; unsigned u[4]; } x;
  x.v = a;
#pragma unroll
  for (int j = 0; j < 4; ++j) x.u[j] ^= 0x80008000u;
  return x.v;
}

// ---------------------------------------------------------------------------
// Pack all weights to bf16 into ws (one pass, ~900K elements).
// ---------------------------------------------------------------------------
__global__ __launch_bounds__(256) void k_pack(
    const float* __restrict__ s0, const float* __restrict__ s1,
    const float* __restrict__ s2, const float* __restrict__ s3,
    const float* __restrict__ s4, const float* __restrict__ s5,
    const float* __restrict__ s6, const float* __restrict__ s7,
    short* __restrict__ dst)
{
  for (int i = blockIdx.x * 256 + threadIdx.x; i < PK_TOTAL; i += gridDim.x * 256) {
    const float* s; int off;
    if (i < OPROJ_R) {
      if (i < OQKV_I) { s = s0; off = i; } else { s = s1; off = i - OQKV_I; }
    } else if (i < OW1_R) {
      if (i < OPROJ_I) { s = s2; off = i - OPROJ_R; } else { s = s3; off = i - OPROJ_I; }
    } else if (i < OW2_R) {
      if (i < OW1_I) { s = s4; off = i - OW1_R; } else { s = s5; off = i - OW1_I; }
    } else {
      if (i < OW2_I) { s = s6; off = i - OW2_R; } else { s = s7; off = i - OW2_I; }
    }
    dst[i] = (short)f2bf(s[off]);
  }
}

// ---------------------------------------------------------------------------
// Stage 1 (MFMA): windowed complex attention + proj + residual -> y in d_out.
// Block = 2 windows (64 px), 768 threads (12 waves => 3 waves/SIMD).
// QKV/proj: wave w owns one 16-row tile, all 4 px tiles.
// Attention: 8 tasks on waves 0..7 (waves 8..11 idle through that phase).
// ---------------------------------------------------------------------------
template <bool PK>
__global__ __launch_bounds__(768) void k_attn(
    const float* __restrict__ xr, const float* __restrict__ xi,
    const float* __restrict__ wqkv_r, const float* __restrict__ wqkv_i,
    const float* __restrict__ wp_r, const float* __restrict__ wp_i,
    const short* __restrict__ wpk,
    const float* __restrict__ rpb,
    float* __restrict__ yr, float* __restrict__ yi)
{
  __shared__ short sX[2][64 * 192];   // x window bf16 [px][c^s]
  __shared__ short sQ[2][64 * 64];    // q head-pair [px][cc^s]
  __shared__ short sK[2][64 * 64];    // k head-pair [px][cc^s]
  __shared__ short sV[2][64 * 64];    // v head-pair [cc][px^s]
  __shared__ short sAO[2][64 * 64];   // attn-out head-pair [px][cc^s]
  __shared__ short sAT[2][4][1024];   // attn weights per task [n][m^s]
  __shared__ float sB[640];           // rpb table

  const int t = threadIdx.x;
  const int b = blockIdx.x >> 8;
  const int rem = blockIdx.x & 255;
  const int r0 = (rem >> 4) << 3;
  const int c0 = (rem & 15) << 3;     // two 4-wide windows: c0, c0+4
  const int gbase = b * C * HW + r0 * Wd + c0;

  // ---- stage x window as bf16, [px][c] swizzled; px = wv*32 + row*4 + wcol
  #pragma unroll
  for (int it = 0; it < 4; ++it) {
    const int idx = t + it * 768;          // 0..3071
    const int c = idx >> 4;
    const int q4 = (idx & 15) << 2;        // px base, mult of 4
    const int wvs = q4 >> 5;
    const int row = (q4 & 31) >> 2;
    const int goff = gbase + c * HW + row * Wd + wvs * 4;
    const float4 vr = *(const float4*)(xr + goff);
    const float4 vi = *(const float4*)(xi + goff);
    const float fr[4] = {vr.x, vr.y, vr.z, vr.w};
    const float fi[4] = {vi.x, vi.y, vi.z, vi.w};
    #pragma unroll
    for (int j = 0; j < 4; ++j) {
      const int p = q4 + j;
      const int s = (p & 7) << 3;
      sX[0][p * 192 + (c ^ s)] = (short)f2bf(fr[j]);
      sX[1][p * 192 + (c ^ s)] = (short)f2bf(fi[j]);
    }
  }
  for (int i = t; i < 630; i += 768) sB[i] = rpb[i];
  __syncthreads();

  const int lane = t & 63;
  const int w = t >> 6;           // 0..11
  const int lr = lane & 15;
  const int lg = lane >> 4;

  f32x4 apr[4] = {}, api[4] = {};   // proj accumulators (persist; rows w*16)

  for (int g = 0; g < 3; ++g) {
    // ======== QKV GEMM: 192 rows (q64,k64,v64 of head pair) x 64 px ========
    {
      const int lrow = w * 16;             // 0..176
      const int sec = lrow >> 6;           // 0=q 1=k 2=v
      const int ccb = lrow & 63;
      const int R = sec * 192 + g * 64 + ccb + lr;
      f32x4 dr[4] = {}, di[4] = {};
      #pragma unroll
      for (int ks = 0; ks < 6; ++ks) {
        const int k8 = ks * 32 + lg * 8;
        bf16x8 ar, ai;
        if constexpr (PK) {
          ar = *(const bf16x8*)(wpk + OQKV_R + (size_t)R * C + k8);
          ai = *(const bf16x8*)(wpk + OQKV_I + (size_t)R * C + k8);
        } else {
          const float* wrp = wqkv_r + (size_t)R * C;
          const float* wip = wqkv_i + (size_t)R * C;
          float a[8];
          *(float4*)&a[0] = *(const float4*)(wrp + k8);
          *(float4*)&a[4] = *(const float4*)(wrp + k8 + 4);
          ar = pack8(a);
          *(float4*)&a[0] = *(const float4*)(wip + k8);
          *(float4*)&a[4] = *(const float4*)(wip + k8 + 4);
          ai = pack8(a);
        }
        const bf16x8 ain = negb(ai);
        #pragma unroll
        for (int cb = 0; cb < 4; ++cb) {
          const int px = cb * 16 + lr;
          const int s = (px & 7) << 3;
          const bf16x8 br = *(const bf16x8*)&sX[0][px * 192 + (k8 ^ s)];
          const bf16x8 bi = *(const bf16x8*)&sX[1][px * 192 + (k8 ^ s)];
          dr[cb] = __builtin_amdgcn_mfma_f32_16x16x32_bf16(ar,  br, dr[cb], 0, 0, 0);
          dr[cb] = __builtin_amdgcn_mfma_f32_16x16x32_bf16(ain, bi, dr[cb], 0, 0, 0);
          di[cb] = __builtin_amdgcn_mfma_f32_16x16x32_bf16(ar,  bi, di[cb], 0, 0, 0);
          di[cb] = __builtin_amdgcn_mfma_f32_16x16x32_bf16(ai,  br, di[cb], 0, 0, 0);
        }
      }
      // write D to sQ/sK ([px][cc]) or sV ([cc][px])
      if (sec < 2) {
        short* d0 = sec ? sK[0] : sQ[0];
        short* d1 = sec ? sK[1] : sQ[1];
        #pragma unroll
        for (int cb = 0; cb < 4; ++cb) {
          const int px = cb * 16 + lr;
          const int e = px * 64 + ((ccb + lg * 4) ^ ((px & 7) << 3));
          *(uint2*)&d0[e] = pack4(dr[cb]);
          *(uint2*)&d1[e] = pack4(di[cb]);
        }
      } else {
        #pragma unroll
        for (int cb = 0; cb < 4; ++cb) {
          const int px = cb * 16 + lr;
          #pragma unroll
          for (int r = 0; r < 4; ++r) {
            const int dd = ccb + lg * 4 + r;
            const int e = dd * 64 + (px ^ ((dd & 7) << 3));
            sV[0][e] = (short)f2bf(dr[cb][r]);
            sV[1][e] = (short)f2bf(di[cb][r]);
          }
        }
      }
    }
    __syncthreads();   // bar A: qkv visible

    // ======== attention: waves 0..7 = (task, half); waves 8..11 idle ========
    if (w < 8) {
      const int task = w >> 1;
      const int half = w & 1;
      const int hloc = task >> 1;
      const int wv = task & 1;
      const int ccq = hloc * 32;
      const int h = 2 * g + hloc;
      // Q A-frag (n rows of this half) / K B-frags (m cols 0..31)
      bf16x8 aqr, aqi, bkr[2], bki[2];
      {
        const int pxq = wv * 32 + half * 16 + lr;
        const int eq = pxq * 64 + ((ccq + lg * 8) ^ ((pxq & 7) << 3));
        aqr = *(const bf16x8*)&sQ[0][eq];
        aqi = *(const bf16x8*)&sQ[1][eq];
      }
      #pragma unroll
      for (int j = 0; j < 2; ++j) {
        const int pxk = wv * 32 + j * 16 + lr;
        const int ek = pxk * 64 + ((ccq + lg * 8) ^ ((pxk & 7) << 3));
        bkr[j] = *(const bf16x8*)&sK[0][ek];
        bki[j] = *(const bf16x8*)&sK[1][ek];
      }
      f32x4 sre[2], sim[2];
      #pragma unroll
      for (int j = 0; j < 2; ++j) {
        f32x4 z = {};
        f32x4 re = __builtin_amdgcn_mfma_f32_16x16x32_bf16(aqr, bkr[j], z, 0, 0, 0);
        re = __builtin_amdgcn_mfma_f32_16x16x32_bf16(aqi, bki[j], re, 0, 0, 0);
        f32x4 im = __builtin_amdgcn_mfma_f32_16x16x32_bf16(aqi, bkr[j], z, 0, 0, 0);
        im = __builtin_amdgcn_mfma_f32_16x16x32_bf16(negb(aqr), bki[j], im, 0, 0, 0);
        sre[j] = re;
        sim[j] = im;
      }
      float re_[2][4], im_[2][4], mg_[2][4];
      #pragma unroll
      for (int j = 0; j < 2; ++j) {
        const int m = j * 16 + lr;
        #pragma unroll
        for (int r = 0; r < 4; ++r) {
          const int n = half * 16 + lg * 4 + r;
          const int bidx = ((n >> 2) - (m >> 2) + 7) * 7 + ((n & 3) - (m & 3) + 3);
          const float re = sre[j][r] * SCALE + sB[bidx * NH + h];
          const float im = sim[j][r] * SCALE;
          re_[j][r] = re;
          im_[j][r] = im;
          mg_[j][r] = sqrtf(re * re + im * im);
        }
      }
      #pragma unroll
      for (int r = 0; r < 4; ++r) {
        float mx = fmaxf(mg_[0][r], mg_[1][r]);
        mx = fmaxf(mx, __shfl_xor(mx, 1));
        mx = fmaxf(mx, __shfl_xor(mx, 2));
        mx = fmaxf(mx, __shfl_xor(mx, 4));
        mx = fmaxf(mx, __shfl_xor(mx, 8));
        const float e0 = expf(mg_[0][r] - mx);
        const float e1 = expf(mg_[1][r] - mx);
        float se = e0 + e1;
        se += __shfl_xor(se, 1);
        se += __shfl_xor(se, 2);
        se += __shfl_xor(se, 4);
        se += __shfl_xor(se, 8);
        const float inv = 1.f / se;
        const float f0 = e0 * inv / (mg_[0][r] + 1e-8f);
        const float f1 = e1 * inv / (mg_[1][r] + 1e-8f);
        const int n = half * 16 + lg * 4 + r;
        const int sw = (n & 3) << 3;
        sAT[0][task][n * 32 + (lr ^ sw)]        = (short)f2bf(re_[0][r] * f0);
        sAT[1][task][n * 32 + (lr ^ sw)]        = (short)f2bf(im_[0][r] * f0);
        sAT[0][task][n * 32 + ((16 + lr) ^ sw)] = (short)f2bf(re_[1][r] * f1);
        sAT[1][task][n * 32 + ((16 + lr) ^ sw)] = (short)f2bf(im_[1][r] * f1);
      }
      // PV: out[dd][n] = sum_m v[dd][m] * attn[n][m], n in this half
      bf16x8 bar_, bai_;
      {
        const int n = half * 16 + lr;
        const int e = n * 32 + ((lg * 8) ^ ((n & 3) << 3));
        bar_ = *(const bf16x8*)&sAT[0][task][e];
        bai_ = *(const bf16x8*)&sAT[1][task][e];
      }
      #pragma unroll
      for (int i2 = 0; i2 < 2; ++i2) {
        const int dd = ccq + i2 * 16 + lr;
        const int e = dd * 64 + ((wv * 32 + lg * 8) ^ ((dd & 7) << 3));
        const bf16x8 avr = *(const bf16x8*)&sV[0][e];
        const bf16x8 avi = *(const bf16x8*)&sV[1][e];
        const bf16x8 avin = negb(avi);
        f32x4 z = {};
        f32x4 pr = __builtin_amdgcn_mfma_f32_16x16x32_bf16(avr, bar_, z, 0, 0, 0);
        pr = __builtin_amdgcn_mfma_f32_16x16x32_bf16(avin, bai_, pr, 0, 0, 0);
        f32x4 pi = __builtin_amdgcn_mfma_f32_16x16x32_bf16(avr, bai_, z, 0, 0, 0);
        pi = __builtin_amdgcn_mfma_f32_16x16x32_bf16(avi, bar_, pi, 0, 0, 0);
        const int px = wv * 32 + half * 16 + lr;
        const int e2 = px * 64 + ((ccq + i2 * 16 + lg * 4) ^ ((px & 7) << 3));
        *(uint2*)&sAO[0][e2] = pack4(pr);
        *(uint2*)&sAO[1][e2] = pack4(pi);
      }
    }

    // prefetch proj A-frags so their latency lands in bar B's drain (PK path)
    const int o = w * 16 + lr;
    bf16x8 ppr[2], ppi[2];
    if constexpr (PK) {
      #pragma unroll
      for (int ks = 0; ks < 2; ++ks) {
        const int k8 = ks * 32 + lg * 8;
        ppr[ks] = *(const bf16x8*)(wpk + OPROJ_R + (size_t)o * C + g * 64 + k8);
        ppi[ks] = *(const bf16x8*)(wpk + OPROJ_I + (size_t)o * C + g * 64 + k8);
      }
    }
    __syncthreads();   // bar B: attn-out visible

    // ======== proj accumulation: K = 64 (head pair), rows w*16 ========
    #pragma unroll
    for (int ks = 0; ks < 2; ++ks) {
      const int k8 = ks * 32 + lg * 8;
      bf16x8 pbr[4], pbi[4];
      #pragma unroll
      for (int cb = 0; cb < 4; ++cb) {
        const int px = cb * 16 + lr;
        const int e = px * 64 + (k8 ^ ((px & 7) << 3));
        pbr[cb] = *(const bf16x8*)&sAO[0][e];
        pbi[cb] = *(const bf16x8*)&sAO[1][e];
      }
      bf16x8 ar, ai;
      if constexpr (PK) {
        ar = ppr[ks];
        ai = ppi[ks];
      } else {
        const size_t wb = (size_t)o * C + g * 64 + k8;
        float a[8];
        *(float4*)&a[0] = *(const float4*)(wp_r + wb);
        *(float4*)&a[4] = *(const float4*)(wp_r + wb + 4);
        ar = pack8(a);
        *(float4*)&a[0] = *(const float4*)(wp_i + wb);
        *(float4*)&a[4] = *(const float4*)(wp_i + wb + 4);
        ai = pack8(a);
      }
      const bf16x8 ain = negb(ai);
      #pragma unroll
      for (int cb = 0; cb < 4; ++cb) {
        apr[cb] = __builtin_amdgcn_mfma_f32_16x16x32_bf16(ar,  pbr[cb], apr[cb], 0, 0, 0);
        apr[cb] = __builtin_amdgcn_mfma_f32_16x16x32_bf16(ain, pbi[cb], apr[cb], 0, 0, 0);
        api[cb] = __builtin_amdgcn_mfma_f32_16x16x32_bf16(ar,  pbi[cb], api[cb], 0, 0, 0);
        api[cb] = __builtin_amdgcn_mfma_f32_16x16x32_bf16(ai,  pbr[cb], api[cb], 0, 0, 0);
      }
    }
  }

  // ======== epilogue: y = x + proj_out (residual from sX, bf16) ========
  #pragma unroll
  for (int cb = 0; cb < 4; ++cb) {
    const int px = cb * 16 + lr;
    const int n = px & 31;
    const int off0 = gbase + (n >> 2) * Wd + (px >> 5) * 4 + (n & 3);
    const int s = (px & 7) << 3;
    #pragma unroll
    for (int r = 0; r < 4; ++r) {
      const int c = w * 16 + lg * 4 + r;
      const size_t gg = (size_t)off0 + (size_t)c * HW;
      yr[gg] = bf2f(sX[0][px * 192 + (c ^ s)]) + apr[cb][r];
      yi[gg] = bf2f(sX[1][px * 192 + (c ^ s)]) + api[cb][r];
    }
  }
}

// ---------------------------------------------------------------------------
// BN stats (unchanged)
// ---------------------------------------------------------------------------
__global__ __launch_bounds__(256) void k_stats(
    const float* __restrict__ src_r, const float* __restrict__ src_i,
    float* __restrict__ mean, float* __restrict__ rstd)
{
  const int c = blockIdx.x;
  const int plane = blockIdx.y;
  const float* src = plane ? src_i : src_r;
  const int t = threadIdx.x;
  double s = 0.0, s2 = 0.0;
  for (int b = 0; b < Bn; ++b) {
    const float* p = src + (size_t)(b * C + c) * HW;
    for (int i = t; i < HW; i += 256) {
      const double v = (double)p[i];
      s += v;
      s2 += v * v;
    }
  }
  __shared__ double ls[256], ls2[256];
  ls[t] = s; ls2[t] = s2;
  __syncthreads();
  for (int off = 128; off > 0; off >>= 1) {
    if (t < off) { ls[t] += ls[t + off]; ls2[t] += ls2[t + off]; }
    __syncthreads();
  }
  if (t == 0) {
    const double inv = 1.0 / (double)(Bn * HW);
    const double m = ls[0] * inv;
    const double var = ls2[0] * inv - m * m;
    mean[plane * C + c] = (float)m;
    rstd[plane * C + c] = (float)(1.0 / sqrt(var + 1e-5));
  }
}

__global__ void k_bnpar(const float* __restrict__ mean, const float* __restrict__ rstd,
                        const float* __restrict__ g_r, const float* __restrict__ b_r,
                        const float* __restrict__ g_i, const float* __restrict__ b_i,
                        float* __restrict__ sc, float* __restrict__ sh)
{
  const int i = blockIdx.x * blockDim.x + threadIdx.x;
  if (i >= 2 * C) return;
  const int plane = i / C, c = i % C;
  const float g = plane ? g_i[c] : g_r[c];
  const float bb = plane ? b_i[c] : b_r[c];
  const float s = rstd[i] * g;
  sc[i] = s;
  sh[i] = bb - mean[i] * s;
}

// ---------------------------------------------------------------------------
// Fused MFMA MLP. 512 threads (8 waves), 64KB LDS (2 blocks/CU).
// W2 ks2=0 A-frags prefetched before the barrier so the barrier's vmcnt
// drain absorbs their latency.
// ---------------------------------------------------------------------------
template <bool PK>
__global__ __launch_bounds__(512, 2) void k_mlp(
    float* __restrict__ outp,
    const float* __restrict__ w1_r, const float* __restrict__ w1_i,
    const float* __restrict__ w2_r, const float* __restrict__ w2_i,
    const short* __restrict__ wpk,
    const float* __restrict__ sc1, const float* __restrict__ sh1)
{
  __shared__ short sXm[2][64 * 192];
  __shared__ short sH[2][64 * 64];     // single buffer [plane][p*64 + k^s]

  const int t = threadIdx.x;
  const int pix0 = blockIdx.x * 64;
  const int b = pix0 >> 14;
  const int p0 = pix0 & (HW - 1);
  const float* yrp = outp;
  const float* yip = outp + PLANE;

  #pragma unroll
  for (int it = 0; it < 6; ++it) {
    const int idx = t + it * 512;
    const int c = idx >> 4;
    const int q = (idx & 15) << 2;
    const size_t g = (size_t)(b * C + c) * HW + p0 + q;
    const float4 vr = *(const float4*)(yrp + g);
    const float4 vi = *(const float4*)(yip + g);
    const float srr = sc1[c], hrr = sh1[c];
    const float sii = sc1[C + c], hii = sh1[C + c];
    const float fr[4] = {vr.x * srr + hrr, vr.y * srr + hrr, vr.z * srr + hrr, vr.w * srr + hrr};
    const float fi[4] = {vi.x * sii + hii, vi.y * sii + hii, vi.z * sii + hii, vi.w * sii + hii};
    #pragma unroll
    for (int i2 = 0; i2 < 4; ++i2) {
      const int p = q + i2;
      const int s = (p & 7) << 3;
      sXm[0][p * 192 + (c ^ s)] = (short)f2bf(fr[i2]);
      sXm[1][p * 192 + (c ^ s)] = (short)f2bf(fi[i2]);
    }
  }
  __syncthreads();

  const int lane = t & 63;
  const int w = t >> 6;         // 0..7
  const int lr = lane & 15;
  const int lg = lane >> 4;
  const int wr = w >> 1;        // 0..3
  const int wc = w & 1;         // 0..1

  f32x4 acc2r[3][2] = {};
  f32x4 acc2i[3][2] = {};

  for (int hc = 0; hc < 12; ++hc) {
    // ---- GEMM1: h rows [hc*64 + wr*16, +16) x 32 px (wc half), K=192 ----
    f32x4 hfr[2] = {}, hfi[2] = {};
    #pragma unroll
    for (int ks = 0; ks < 6; ++ks) {
      const int k8 = ks * 32 + lg * 8;
      bf16x8 a1r, a1i;
      if constexpr (PK) {
        a1r = *(const bf16x8*)(wpk + OW1_R + (size_t)(hc * 64 + wr * 16 + lr) * C + k8);
        a1i = *(const bf16x8*)(wpk + OW1_I + (size_t)(hc * 64 + wr * 16 + lr) * C + k8);
      } else {
        const float* w1rp = w1_r + (size_t)(hc * 64 + wr * 16 + lr) * C;
        const float* w1ip = w1_i + (size_t)(hc * 64 + wr * 16 + lr) * C;
        float a[8];
        *(float4*)&a[0] = *(const float4*)(w1rp + k8);
        *(float4*)&a[4] = *(const float4*)(w1rp + k8 + 4);
        a1r = pack8(a);
        *(float4*)&a[0] = *(const float4*)(w1ip + k8);
        *(float4*)&a[4] = *(const float4*)(w1ip + k8 + 4);
        a1i = pack8(a);
      }
      const bf16x8 a1in = negb(a1i);
      #pragma unroll
      for (int cb = 0; cb < 2; ++cb) {
        const int p = (wc * 2 + cb) * 16 + lr;
        const int s = (p & 7) << 3;
        const bf16x8 br = *(const bf16x8*)&sXm[0][p * 192 + (k8 ^ s)];
        const bf16x8 bi = *(const bf16x8*)&sXm[1][p * 192 + (k8 ^ s)];
        hfr[cb] = __builtin_amdgcn_mfma_f32_16x16x32_bf16(a1r,  br, hfr[cb], 0, 0, 0);
        hfr[cb] = __builtin_amdgcn_mfma_f32_16x16x32_bf16(a1in, bi, hfr[cb], 0, 0, 0);
        hfi[cb] = __builtin_amdgcn_mfma_f32_16x16x32_bf16(a1r,  bi, hfi[cb], 0, 0, 0);
        hfi[cb] = __builtin_amdgcn_mfma_f32_16x16x32_bf16(a1i,  br, hfi[cb], 0, 0, 0);
      }
    }

    // ---- prefetch GEMM2 ks2=0 A-frags (latency hides under GELU+barrier) --
    bf16x8 pa2r[3], pa2i[3];
    if constexpr (PK) {
      #pragma unroll
      for (int ob = 0; ob < 3; ++ob) {
        const int row = (wr * 3 + ob) * 16 + lr;
        pa2r[ob] = *(const bf16x8*)(wpk + OW2_R + (size_t)row * C4 + hc * 64 + lg * 8);
        pa2i[ob] = *(const bf16x8*)(wpk + OW2_I + (size_t)row * C4 + hc * 64 + lg * 8);
      }
    }

    // ---- magnitude GELU (h * Phi(m)) ----
    float outr[2][4], outi[2][4];
    #pragma unroll
    for (int cb = 0; cb < 2; ++cb) {
      #pragma unroll
      for (int r = 0; r < 4; ++r) {
        const float re = hfr[cb][r], im = hfi[cb][r];
        const float m = sqrtf(re * re + im * im);
        const float f = 0.5f * (1.0f + erff(m * 0.70710678f));
        outr[cb][r] = re * f;
        outi[cb][r] = im * f;
      }
    }
    __syncthreads();   // previous chunk's GEMM2 reads complete
    #pragma unroll
    for (int cb = 0; cb < 2; ++cb) {
      const int p = (wc * 2 + cb) * 16 + lr;
      const int s = (p & 7) << 3;
      const int kb = wr * 16 + lg * 4;
      const int e = p * 64 + (kb ^ s);
      *(uint2*)&sH[0][e] = make_uint2(
          (unsigned)f2bf(outr[cb][0]) | ((unsigned)f2bf(outr[cb][1]) << 16),
          (unsigned)f2bf(outr[cb][2]) | ((unsigned)f2bf(outr[cb][3]) << 16));
      *(uint2*)&sH[1][e] = make_uint2(
          (unsigned)f2bf(outi[cb][0]) | ((unsigned)f2bf(outi[cb][1]) << 16),
          (unsigned)f2bf(outi[cb][2]) | ((unsigned)f2bf(outi[cb][3]) << 16));
    }
    __syncthreads();   // sH visible

    // ---- GEMM2: acc2 += W2[:, chunk] . Ht, K=64 ----
    #pragma unroll
    for (int ks2 = 0; ks2 < 2; ++ks2) {
      const int k8 = ks2 * 32 + lg * 8;
      bf16x8 br2[2], bi2[2];
      #pragma unroll
      for (int cb = 0; cb < 2; ++cb) {
        const int p = (wc * 2 + cb) * 16 + lr;
        const int s = (p & 7) << 3;
        br2[cb] = *(const bf16x8*)&sH[0][p * 64 + (k8 ^ s)];
        bi2[cb] = *(const bf16x8*)&sH[1][p * 64 + (k8 ^ s)];
      }
      #pragma unroll
      for (int ob = 0; ob < 3; ++ob) {
        const int row = (wr * 3 + ob) * 16 + lr;
        bf16x8 a2r, a2i;
        if constexpr (PK) {
          if (ks2 == 0) {
            a2r = pa2r[ob];
            a2i = pa2i[ob];
          } else {
            a2r = *(const bf16x8*)(wpk + OW2_R + (size_t)row * C4 + hc * 64 + k8);
            a2i = *(const bf16x8*)(wpk + OW2_I + (size_t)row * C4 + hc * 64 + k8);
          }
        } else {
          const size_t wbase = (size_t)row * C4 + hc * 64 + k8;
          float a[8];
          *(float4*)&a[0] = *(const float4*)(w2_r + wbase);
          *(float4*)&a[4] = *(const float4*)(w2_r + wbase + 4);
          a2r = pack8(a);
          *(float4*)&a[0] = *(const float4*)(w2_i + wbase);
          *(float4*)&a[4] = *(const float4*)(w2_i + wbase + 4);
          a2i = pack8(a);
        }
        const bf16x8 a2in = negb(a2i);
        #pragma unroll
        for (int cb = 0; cb < 2; ++cb) {
          acc2r[ob][cb] = __builtin_amdgcn_mfma_f32_16x16x32_bf16(a2r,  br2[cb], acc2r[ob][cb], 0, 0, 0);
          acc2r[ob][cb] = __builtin_amdgcn_mfma_f32_16x16x32_bf16(a2in, bi2[cb], acc2r[ob][cb], 0, 0, 0);
          acc2i[ob][cb] = __builtin_amdgcn_mfma_f32_16x16x32_bf16(a2r,  bi2[cb], acc2i[ob][cb], 0, 0, 0);
          acc2i[ob][cb] = __builtin_amdgcn_mfma_f32_16x16x32_bf16(a2i,  br2[cb], acc2i[ob][cb], 0, 0, 0);
        }
      }
    }
  }

  #pragma unroll
  for (int ob = 0; ob < 3; ++ob) {
    #pragma unroll
    for (int cb = 0; cb < 2; ++cb) {
      const int px = p0 + (wc * 2 + cb) * 16 + lr;
      #pragma unroll
      for (int r = 0; r < 4; ++r) {
        const int ch = (wr * 3 + ob) * 16 + lg * 4 + r;
        const size_t g = (size_t)(b * C + ch) * HW + px;
        const float res_r = yrp[g] * sc1[ch] + sh1[ch];
        const float res_i = yip[g] * sc1[C + ch] + sh1[C + ch];
        outp[g] = res_r + acc2r[ob][cb][r];
        outp[PLANE + g] = res_i + acc2i[ob][cb][r];
      }
    }
  }
}

// In-place BN2 apply over d_out (both planes).
__global__ __launch_bounds__(256) void k_bnfinal(
    float* __restrict__ xo, const float* __restrict__ sc, const float* __restrict__ sh)
{
  const int total4 = (2 * PLANE) / 4;
  for (int i = blockIdx.x * blockDim.x + threadIdx.x; i < total4; i += gridDim.x * blockDim.x) {
    const int e = i * 4;
    const int plane = (e >= PLANE) ? 1 : 0;
    const int w = plane ? (e - PLANE) : e;
    const int ch = (w >> 14) % C;
    const float s = sc[plane * C + ch], hh = sh[plane * C + ch];
    float4 v = *(float4*)(xo + e);
    v.x = v.x * s + hh;
    v.y = v.y * s + hh;
    v.z = v.z * s + hh;
    v.w = v.w * s + hh;
    *(float4*)(xo + e) = v;
  }
}

}  // namespace

extern "C" void kernel_launch(void* const* d_in, const int* in_sizes, int n_in,
                              void* d_out, int out_size, void* d_ws, size_t ws_size,
                              hipStream_t stream)
{
  (void)in_sizes; (void)n_in; (void)out_size;
  const float* x_real  = (const float*)d_in[0];
  const float* x_imag  = (const float*)d_in[1];
  const float* qkv_wr  = (const float*)d_in[2];
  const float* qkv_wi  = (const float*)d_in[3];
  const float* proj_wr = (const float*)d_in[4];
  const float* proj_wi = (const float*)d_in[5];
  const float* rpb     = (const float*)d_in[6];
  const float* n1_gr   = (const float*)d_in[7];
  const float* n1_br   = (const float*)d_in[8];
  const float* n1_gi   = (const float*)d_in[9];
  const float* n1_bi   = (const float*)d_in[10];
  const float* mlp1_wr = (const float*)d_in[11];
  const float* mlp1_wi = (const float*)d_in[12];
  const float* mlp2_wr = (const float*)d_in[13];
  const float* mlp2_wi = (const float*)d_in[14];
  const float* n2_gr   = (const float*)d_in[15];
  const float* n2_br   = (const float*)d_in[16];
  const float* n2_gi   = (const float*)d_in[17];
  const float* n2_bi   = (const float*)d_in[18];

  const size_t pkBytes = (size_t)PK_TOTAL * 2;          // 1769472
  const bool pk = ws_size >= pkBytes + 3072 * 4;

  short* wpk = (short*)d_ws;
  float* st = pk ? (float*)((char*)d_ws + pkBytes) : (float*)d_ws;
  float* mean1 = st;          float* rstd1 = st + 384;
  float* sc1   = st + 768;    float* sh1   = st + 1152;
  float* mean2 = st + 1536;   float* rstd2 = st + 1920;
  float* sc2   = st + 2304;   float* sh2   = st + 2688;

  float* outp = (float*)d_out;
  float* yr = outp;
  float* yi = outp + PLANE;

  if (pk) {
    k_pack<<<1024, 256, 0, stream>>>(qkv_wr, qkv_wi, proj_wr, proj_wi,
                                     mlp1_wr, mlp1_wi, mlp2_wr, mlp2_wi, wpk);
    k_attn<true><<<1024, 768, 0, stream>>>(x_real, x_imag, qkv_wr, qkv_wi,
                                           proj_wr, proj_wi, wpk, rpb, yr, yi);
  } else {
    k_attn<false><<<1024, 768, 0, stream>>>(x_real, x_imag, qkv_wr, qkv_wi,
                                            proj_wr, proj_wi, nullptr, rpb, yr, yi);
  }
  k_stats<<<dim3(C, 2), 256, 0, stream>>>(yr, yi, mean1, rstd1);
  k_bnpar<<<2, 192, 0, stream>>>(mean1, rstd1, n1_gr, n1_br, n1_gi, n1_bi, sc1, sh1);
  if (pk) {
    k_mlp<true><<<Bn * HW / 64, 512, 0, stream>>>(outp, mlp1_wr, mlp1_wi,
                                                  mlp2_wr, mlp2_wi, wpk, sc1, sh1);
  } else {
    k_mlp<false><<<Bn * HW / 64, 512, 0, stream>>>(outp, mlp1_wr, mlp1_wi,
                                                   mlp2_wr, mlp2_wi, nullptr, sc1, sh1);
  }
  k_stats<<<dim3(C, 2), 256, 0, stream>>>(outp, outp + PLANE, mean2, rstd2);
  k_bnpar<<<2, 192, 0, stream>>>(mean2, rstd2, n2_gr, n2_br, n2_gi, n2_bi, sc2, sh2);
  k_bnfinal<<<2048, 256, 0, stream>>>(outp, sc2, sh2);
}

// Round 8
// 668.200 us; speedup vs baseline: 8.7244x; 1.1038x over previous
//
#include <hip/hip_runtime.h>

namespace {

constexpr int Bn = 4;
constexpr int C  = 192;
constexpr int Wd = 128;
constexpr int HW = 16384;            // 128*128
constexpr int PLANE = Bn * C * HW;   // 12582912
constexpr int NH = 6;
constexpr int HD = 32;
constexpr int C4 = 4 * C;            // 768
constexpr float SCALE = 0.17677669529663687f;  // 32^-0.5

// packed bf16 weight layout in d_ws (short offsets)
constexpr int OQKV_R = 0;            // 576*192
constexpr int OQKV_I = 110592;
constexpr int OPROJ_R = 221184;      // 192*192
constexpr int OPROJ_I = 258048;
constexpr int OW1_R = 294912;        // 768*192
constexpr int OW1_I = 442368;
constexpr int OW2_R = 589824;        // 192*768
constexpr int OW2_I = 737280;
constexpr int PK_TOTAL = 884736;

typedef short bf16x8 __attribute__((ext_vector_type(8)));
typedef float f32x4 __attribute__((ext_vector_type(4)));

__device__ inline unsigned short f2bf(float f) {
  union { float f; unsigned u; } v; v.f = f;
  const unsigned r = v.u + 0x7FFFu + ((v.u >> 16) & 1u);
  return (unsigned short)(r >> 16);
}

__device__ inline float bf2f(short s) {
  union { unsigned u; float f; } v;
  v.u = ((unsigned)(unsigned short)s) << 16;
  return v.f;
}

__device__ inline bf16x8 pack8(const float* f) {
  union { bf16x8 v; unsigned short s[8]; } x;
#pragma unroll
  for (int j = 0; j < 8; ++j) x.s[j] = f2bf(f[j]);
  return x.v;
}

__device__ inline uint2 pack4(const f32x4 v) {
  return make_uint2((unsigned)f2bf(v[0]) | ((unsigned)f2bf(v[1]) << 16),
                    (unsigned)f2bf(v[2]) | ((unsigned)f2bf(v[3]) << 16));
}

__device__ inline bf16x8 negb(bf16x8 a) {
  union { bf16x8 v; unsigned u[4]; } x;
  x.v = a;
#pragma unroll
  for (int j = 0; j < 4; ++j) x.u[j] ^= 0x80008000u;
  return x.v;
}

// ---------------------------------------------------------------------------
// Pack all weights to bf16 into ws (one pass, ~900K elements).
// ---------------------------------------------------------------------------
__global__ __launch_bounds__(256) void k_pack(
    const float* __restrict__ s0, const float* __restrict__ s1,
    const float* __restrict__ s2, const float* __restrict__ s3,
    const float* __restrict__ s4, const float* __restrict__ s5,
    const float* __restrict__ s6, const float* __restrict__ s7,
    short* __restrict__ dst)
{
  for (int i = blockIdx.x * 256 + threadIdx.x; i < PK_TOTAL; i += gridDim.x * 256) {
    const float* s; int off;
    if (i < OPROJ_R) {
      if (i < OQKV_I) { s = s0; off = i; } else { s = s1; off = i - OQKV_I; }
    } else if (i < OW1_R) {
      if (i < OPROJ_I) { s = s2; off = i - OPROJ_R; } else { s = s3; off = i - OPROJ_I; }
    } else if (i < OW2_R) {
      if (i < OW1_I) { s = s4; off = i - OW1_R; } else { s = s5; off = i - OW1_I; }
    } else {
      if (i < OW2_I) { s = s6; off = i - OW2_R; } else { s = s7; off = i - OW2_I; }
    }
    dst[i] = (short)f2bf(s[off]);
  }
}

// ---------------------------------------------------------------------------
// Stage 1 (MFMA): windowed complex attention + proj + residual -> y in d_out.
// Block = 2 windows (64 px), 768 threads (12 waves => 3 waves/SIMD).
// (unchanged from R7)
// ---------------------------------------------------------------------------
template <bool PK>
__global__ __launch_bounds__(768) void k_attn(
    const float* __restrict__ xr, const float* __restrict__ xi,
    const float* __restrict__ wqkv_r, const float* __restrict__ wqkv_i,
    const float* __restrict__ wp_r, const float* __restrict__ wp_i,
    const short* __restrict__ wpk,
    const float* __restrict__ rpb,
    float* __restrict__ yr, float* __restrict__ yi)
{
  __shared__ short sX[2][64 * 192];   // x window bf16 [px][c^s]
  __shared__ short sQ[2][64 * 64];    // q head-pair [px][cc^s]
  __shared__ short sK[2][64 * 64];    // k head-pair [px][cc^s]
  __shared__ short sV[2][64 * 64];    // v head-pair [cc][px^s]
  __shared__ short sAO[2][64 * 64];   // attn-out head-pair [px][cc^s]
  __shared__ short sAT[2][4][1024];   // attn weights per task [n][m^s]
  __shared__ float sB[640];           // rpb table

  const int t = threadIdx.x;
  const int b = blockIdx.x >> 8;
  const int rem = blockIdx.x & 255;
  const int r0 = (rem >> 4) << 3;
  const int c0 = (rem & 15) << 3;     // two 4-wide windows: c0, c0+4
  const int gbase = b * C * HW + r0 * Wd + c0;

  // ---- stage x window as bf16, [px][c] swizzled; px = wv*32 + row*4 + wcol
  #pragma unroll
  for (int it = 0; it < 4; ++it) {
    const int idx = t + it * 768;          // 0..3071
    const int c = idx >> 4;
    const int q4 = (idx & 15) << 2;        // px base, mult of 4
    const int wvs = q4 >> 5;
    const int row = (q4 & 31) >> 2;
    const int goff = gbase + c * HW + row * Wd + wvs * 4;
    const float4 vr = *(const float4*)(xr + goff);
    const float4 vi = *(const float4*)(xi + goff);
    const float fr[4] = {vr.x, vr.y, vr.z, vr.w};
    const float fi[4] = {vi.x, vi.y, vi.z, vi.w};
    #pragma unroll
    for (int j = 0; j < 4; ++j) {
      const int p = q4 + j;
      const int s = (p & 7) << 3;
      sX[0][p * 192 + (c ^ s)] = (short)f2bf(fr[j]);
      sX[1][p * 192 + (c ^ s)] = (short)f2bf(fi[j]);
    }
  }
  for (int i = t; i < 630; i += 768) sB[i] = rpb[i];
  __syncthreads();

  const int lane = t & 63;
  const int w = t >> 6;           // 0..11
  const int lr = lane & 15;
  const int lg = lane >> 4;

  f32x4 apr[4] = {}, api[4] = {};   // proj accumulators (persist; rows w*16)

  for (int g = 0; g < 3; ++g) {
    // ======== QKV GEMM: 192 rows (q64,k64,v64 of head pair) x 64 px ========
    {
      const int lrow = w * 16;             // 0..176
      const int sec = lrow >> 6;           // 0=q 1=k 2=v
      const int ccb = lrow & 63;
      const int R = sec * 192 + g * 64 + ccb + lr;
      f32x4 dr[4] = {}, di[4] = {};
      #pragma unroll
      for (int ks = 0; ks < 6; ++ks) {
        const int k8 = ks * 32 + lg * 8;
        bf16x8 ar, ai;
        if constexpr (PK) {
          ar = *(const bf16x8*)(wpk + OQKV_R + (size_t)R * C + k8);
          ai = *(const bf16x8*)(wpk + OQKV_I + (size_t)R * C + k8);
        } else {
          const float* wrp = wqkv_r + (size_t)R * C;
          const float* wip = wqkv_i + (size_t)R * C;
          float a[8];
          *(float4*)&a[0] = *(const float4*)(wrp + k8);
          *(float4*)&a[4] = *(const float4*)(wrp + k8 + 4);
          ar = pack8(a);
          *(float4*)&a[0] = *(const float4*)(wip + k8);
          *(float4*)&a[4] = *(const float4*)(wip + k8 + 4);
          ai = pack8(a);
        }
        const bf16x8 ain = negb(ai);
        #pragma unroll
        for (int cb = 0; cb < 4; ++cb) {
          const int px = cb * 16 + lr;
          const int s = (px & 7) << 3;
          const bf16x8 br = *(const bf16x8*)&sX[0][px * 192 + (k8 ^ s)];
          const bf16x8 bi = *(const bf16x8*)&sX[1][px * 192 + (k8 ^ s)];
          dr[cb] = __builtin_amdgcn_mfma_f32_16x16x32_bf16(ar,  br, dr[cb], 0, 0, 0);
          dr[cb] = __builtin_amdgcn_mfma_f32_16x16x32_bf16(ain, bi, dr[cb], 0, 0, 0);
          di[cb] = __builtin_amdgcn_mfma_f32_16x16x32_bf16(ar,  bi, di[cb], 0, 0, 0);
          di[cb] = __builtin_amdgcn_mfma_f32_16x16x32_bf16(ai,  br, di[cb], 0, 0, 0);
        }
      }
      // write D to sQ/sK ([px][cc]) or sV ([cc][px])
      if (sec < 2) {
        short* d0 = sec ? sK[0] : sQ[0];
        short* d1 = sec ? sK[1] : sQ[1];
        #pragma unroll
        for (int cb = 0; cb < 4; ++cb) {
          const int px = cb * 16 + lr;
          const int e = px * 64 + ((ccb + lg * 4) ^ ((px & 7) << 3));
          *(uint2*)&d0[e] = pack4(dr[cb]);
          *(uint2*)&d1[e] = pack4(di[cb]);
        }
      } else {
        #pragma unroll
        for (int cb = 0; cb < 4; ++cb) {
          const int px = cb * 16 + lr;
          #pragma unroll
          for (int r = 0; r < 4; ++r) {
            const int dd = ccb + lg * 4 + r;
            const int e = dd * 64 + (px ^ ((dd & 7) << 3));
            sV[0][e] = (short)f2bf(dr[cb][r]);
            sV[1][e] = (short)f2bf(di[cb][r]);
          }
        }
      }
    }
    __syncthreads();   // bar A: qkv visible

    // ======== attention: waves 0..7 = (task, half); waves 8..11 idle ========
    if (w < 8) {
      const int task = w >> 1;
      const int half = w & 1;
      const int hloc = task >> 1;
      const int wv = task & 1;
      const int ccq = hloc * 32;
      const int h = 2 * g + hloc;
      bf16x8 aqr, aqi, bkr[2], bki[2];
      {
        const int pxq = wv * 32 + half * 16 + lr;
        const int eq = pxq * 64 + ((ccq + lg * 8) ^ ((pxq & 7) << 3));
        aqr = *(const bf16x8*)&sQ[0][eq];
        aqi = *(const bf16x8*)&sQ[1][eq];
      }
      #pragma unroll
      for (int j = 0; j < 2; ++j) {
        const int pxk = wv * 32 + j * 16 + lr;
        const int ek = pxk * 64 + ((ccq + lg * 8) ^ ((pxk & 7) << 3));
        bkr[j] = *(const bf16x8*)&sK[0][ek];
        bki[j] = *(const bf16x8*)&sK[1][ek];
      }
      f32x4 sre[2], sim[2];
      #pragma unroll
      for (int j = 0; j < 2; ++j) {
        f32x4 z = {};
        f32x4 re = __builtin_amdgcn_mfma_f32_16x16x32_bf16(aqr, bkr[j], z, 0, 0, 0);
        re = __builtin_amdgcn_mfma_f32_16x16x32_bf16(aqi, bki[j], re, 0, 0, 0);
        f32x4 im = __builtin_amdgcn_mfma_f32_16x16x32_bf16(aqi, bkr[j], z, 0, 0, 0);
        im = __builtin_amdgcn_mfma_f32_16x16x32_bf16(negb(aqr), bki[j], im, 0, 0, 0);
        sre[j] = re;
        sim[j] = im;
      }
      float re_[2][4], im_[2][4], mg_[2][4];
      #pragma unroll
      for (int j = 0; j < 2; ++j) {
        const int m = j * 16 + lr;
        #pragma unroll
        for (int r = 0; r < 4; ++r) {
          const int n = half * 16 + lg * 4 + r;
          const int bidx = ((n >> 2) - (m >> 2) + 7) * 7 + ((n & 3) - (m & 3) + 3);
          const float re = sre[j][r] * SCALE + sB[bidx * NH + h];
          const float im = sim[j][r] * SCALE;
          re_[j][r] = re;
          im_[j][r] = im;
          mg_[j][r] = sqrtf(re * re + im * im);
        }
      }
      #pragma unroll
      for (int r = 0; r < 4; ++r) {
        float mx = fmaxf(mg_[0][r], mg_[1][r]);
        mx = fmaxf(mx, __shfl_xor(mx, 1));
        mx = fmaxf(mx, __shfl_xor(mx, 2));
        mx = fmaxf(mx, __shfl_xor(mx, 4));
        mx = fmaxf(mx, __shfl_xor(mx, 8));
        const float e0 = expf(mg_[0][r] - mx);
        const float e1 = expf(mg_[1][r] - mx);
        float se = e0 + e1;
        se += __shfl_xor(se, 1);
        se += __shfl_xor(se, 2);
        se += __shfl_xor(se, 4);
        se += __shfl_xor(se, 8);
        const float inv = 1.f / se;
        const float f0 = e0 * inv / (mg_[0][r] + 1e-8f);
        const float f1 = e1 * inv / (mg_[1][r] + 1e-8f);
        const int n = half * 16 + lg * 4 + r;
        const int sw = (n & 3) << 3;
        sAT[0][task][n * 32 + (lr ^ sw)]        = (short)f2bf(re_[0][r] * f0);
        sAT[1][task][n * 32 + (lr ^ sw)]        = (short)f2bf(im_[0][r] * f0);
        sAT[0][task][n * 32 + ((16 + lr) ^ sw)] = (short)f2bf(re_[1][r] * f1);
        sAT[1][task][n * 32 + ((16 + lr) ^ sw)] = (short)f2bf(im_[1][r] * f1);
      }
      // PV: out[dd][n] = sum_m v[dd][m] * attn[n][m], n in this half
      bf16x8 bar_, bai_;
      {
        const int n = half * 16 + lr;
        const int e = n * 32 + ((lg * 8) ^ ((n & 3) << 3));
        bar_ = *(const bf16x8*)&sAT[0][task][e];
        bai_ = *(const bf16x8*)&sAT[1][task][e];
      }
      #pragma unroll
      for (int i2 = 0; i2 < 2; ++i2) {
        const int dd = ccq + i2 * 16 + lr;
        const int e = dd * 64 + ((wv * 32 + lg * 8) ^ ((dd & 7) << 3));
        const bf16x8 avr = *(const bf16x8*)&sV[0][e];
        const bf16x8 avi = *(const bf16x8*)&sV[1][e];
        const bf16x8 avin = negb(avi);
        f32x4 z = {};
        f32x4 pr = __builtin_amdgcn_mfma_f32_16x16x32_bf16(avr, bar_, z, 0, 0, 0);
        pr = __builtin_amdgcn_mfma_f32_16x16x32_bf16(avin, bai_, pr, 0, 0, 0);
        f32x4 pi = __builtin_amdgcn_mfma_f32_16x16x32_bf16(avr, bai_, z, 0, 0, 0);
        pi = __builtin_amdgcn_mfma_f32_16x16x32_bf16(avi, bar_, pi, 0, 0, 0);
        const int px = wv * 32 + half * 16 + lr;
        const int e2 = px * 64 + ((ccq + i2 * 16 + lg * 4) ^ ((px & 7) << 3));
        *(uint2*)&sAO[0][e2] = pack4(pr);
        *(uint2*)&sAO[1][e2] = pack4(pi);
      }
    }

    // prefetch proj A-frags so their latency lands in bar B's drain (PK path)
    const int o = w * 16 + lr;
    bf16x8 ppr[2], ppi[2];
    if constexpr (PK) {
      #pragma unroll
      for (int ks = 0; ks < 2; ++ks) {
        const int k8 = ks * 32 + lg * 8;
        ppr[ks] = *(const bf16x8*)(wpk + OPROJ_R + (size_t)o * C + g * 64 + k8);
        ppi[ks] = *(const bf16x8*)(wpk + OPROJ_I + (size_t)o * C + g * 64 + k8);
      }
    }
    __syncthreads();   // bar B: attn-out visible

    // ======== proj accumulation: K = 64 (head pair), rows w*16 ========
    #pragma unroll
    for (int ks = 0; ks < 2; ++ks) {
      const int k8 = ks * 32 + lg * 8;
      bf16x8 pbr[4], pbi[4];
      #pragma unroll
      for (int cb = 0; cb < 4; ++cb) {
        const int px = cb * 16 + lr;
        const int e = px * 64 + (k8 ^ ((px & 7) << 3));
        pbr[cb] = *(const bf16x8*)&sAO[0][e];
        pbi[cb] = *(const bf16x8*)&sAO[1][e];
      }
      bf16x8 ar, ai;
      if constexpr (PK) {
        ar = ppr[ks];
        ai = ppi[ks];
      } else {
        const size_t wb = (size_t)o * C + g * 64 + k8;
        float a[8];
        *(float4*)&a[0] = *(const float4*)(wp_r + wb);
        *(float4*)&a[4] = *(const float4*)(wp_r + wb + 4);
        ar = pack8(a);
        *(float4*)&a[0] = *(const float4*)(wp_i + wb);
        *(float4*)&a[4] = *(const float4*)(wp_i + wb + 4);
        ai = pack8(a);
      }
      const bf16x8 ain = negb(ai);
      #pragma unroll
      for (int cb = 0; cb < 4; ++cb) {
        apr[cb] = __builtin_amdgcn_mfma_f32_16x16x32_bf16(ar,  pbr[cb], apr[cb], 0, 0, 0);
        apr[cb] = __builtin_amdgcn_mfma_f32_16x16x32_bf16(ain, pbi[cb], apr[cb], 0, 0, 0);
        api[cb] = __builtin_amdgcn_mfma_f32_16x16x32_bf16(ar,  pbi[cb], api[cb], 0, 0, 0);
        api[cb] = __builtin_amdgcn_mfma_f32_16x16x32_bf16(ai,  pbr[cb], api[cb], 0, 0, 0);
      }
    }
  }

  // ======== epilogue: y = x + proj_out (residual from sX, bf16) ========
  #pragma unroll
  for (int cb = 0; cb < 4; ++cb) {
    const int px = cb * 16 + lr;
    const int n = px & 31;
    const int off0 = gbase + (n >> 2) * Wd + (px >> 5) * 4 + (n & 3);
    const int s = (px & 7) << 3;
    #pragma unroll
    for (int r = 0; r < 4; ++r) {
      const int c = w * 16 + lg * 4 + r;
      const size_t gg = (size_t)off0 + (size_t)c * HW;
      yr[gg] = bf2f(sX[0][px * 192 + (c ^ s)]) + apr[cb][r];
      yi[gg] = bf2f(sX[1][px * 192 + (c ^ s)]) + api[cb][r];
    }
  }
}

// ---------------------------------------------------------------------------
// BN stats (unchanged)
// ---------------------------------------------------------------------------
__global__ __launch_bounds__(256) void k_stats(
    const float* __restrict__ src_r, const float* __restrict__ src_i,
    float* __restrict__ mean, float* __restrict__ rstd)
{
  const int c = blockIdx.x;
  const int plane = blockIdx.y;
  const float* src = plane ? src_i : src_r;
  const int t = threadIdx.x;
  double s = 0.0, s2 = 0.0;
  for (int b = 0; b < Bn; ++b) {
    const float* p = src + (size_t)(b * C + c) * HW;
    for (int i = t; i < HW; i += 256) {
      const double v = (double)p[i];
      s += v;
      s2 += v * v;
    }
  }
  __shared__ double ls[256], ls2[256];
  ls[t] = s; ls2[t] = s2;
  __syncthreads();
  for (int off = 128; off > 0; off >>= 1) {
    if (t < off) { ls[t] += ls[t + off]; ls2[t] += ls2[t + off]; }
    __syncthreads();
  }
  if (t == 0) {
    const double inv = 1.0 / (double)(Bn * HW);
    const double m = ls[0] * inv;
    const double var = ls2[0] * inv - m * m;
    mean[plane * C + c] = (float)m;
    rstd[plane * C + c] = (float)(1.0 / sqrt(var + 1e-5));
  }
}

__global__ void k_bnpar(const float* __restrict__ mean, const float* __restrict__ rstd,
                        const float* __restrict__ g_r, const float* __restrict__ b_r,
                        const float* __restrict__ g_i, const float* __restrict__ b_i,
                        float* __restrict__ sc, float* __restrict__ sh)
{
  const int i = blockIdx.x * blockDim.x + threadIdx.x;
  if (i >= 2 * C) return;
  const int plane = i / C, c = i % C;
  const float g = plane ? g_i[c] : g_r[c];
  const float bb = plane ? b_i[c] : b_r[c];
  const float s = rstd[i] * g;
  sc[i] = s;
  sh[i] = bb - mean[i] * s;
}

// ---------------------------------------------------------------------------
// Fused MFMA MLP. 512 threads (8 waves), 64KB LDS, no prefetch (VGPR<=64 for
// 2 blocks/CU — measured R6/R7: 60 VGPR -> 45% occ, 76 VGPR -> 23% occ).
// Epilogue residual read from sXm (bf16) instead of global y.
// ---------------------------------------------------------------------------
template <bool PK>
__global__ __launch_bounds__(512, 2) void k_mlp(
    float* __restrict__ outp,
    const float* __restrict__ w1_r, const float* __restrict__ w1_i,
    const float* __restrict__ w2_r, const float* __restrict__ w2_i,
    const short* __restrict__ wpk,
    const float* __restrict__ sc1, const float* __restrict__ sh1)
{
  __shared__ short sXm[2][64 * 192];
  __shared__ short sH[2][64 * 64];     // single buffer [plane][p*64 + k^s]

  const int t = threadIdx.x;
  const int pix0 = blockIdx.x * 64;
  const int b = pix0 >> 14;
  const int p0 = pix0 & (HW - 1);
  const float* yrp = outp;
  const float* yip = outp + PLANE;

  #pragma unroll
  for (int it = 0; it < 6; ++it) {
    const int idx = t + it * 512;
    const int c = idx >> 4;
    const int q = (idx & 15) << 2;
    const size_t g = (size_t)(b * C + c) * HW + p0 + q;
    const float4 vr = *(const float4*)(yrp + g);
    const float4 vi = *(const float4*)(yip + g);
    const float srr = sc1[c], hrr = sh1[c];
    const float sii = sc1[C + c], hii = sh1[C + c];
    const float fr[4] = {vr.x * srr + hrr, vr.y * srr + hrr, vr.z * srr + hrr, vr.w * srr + hrr};
    const float fi[4] = {vi.x * sii + hii, vi.y * sii + hii, vi.z * sii + hii, vi.w * sii + hii};
    #pragma unroll
    for (int i2 = 0; i2 < 4; ++i2) {
      const int p = q + i2;
      const int s = (p & 7) << 3;
      sXm[0][p * 192 + (c ^ s)] = (short)f2bf(fr[i2]);
      sXm[1][p * 192 + (c ^ s)] = (short)f2bf(fi[i2]);
    }
  }
  __syncthreads();

  const int lane = t & 63;
  const int w = t >> 6;         // 0..7
  const int lr = lane & 15;
  const int lg = lane >> 4;
  const int wr = w >> 1;        // 0..3
  const int wc = w & 1;         // 0..1

  f32x4 acc2r[3][2] = {};
  f32x4 acc2i[3][2] = {};

  for (int hc = 0; hc < 12; ++hc) {
    // ---- GEMM1: h rows [hc*64 + wr*16, +16) x 32 px (wc half), K=192 ----
    f32x4 hfr[2] = {}, hfi[2] = {};
    #pragma unroll
    for (int ks = 0; ks < 6; ++ks) {
      const int k8 = ks * 32 + lg * 8;
      bf16x8 a1r, a1i;
      if constexpr (PK) {
        a1r = *(const bf16x8*)(wpk + OW1_R + (size_t)(hc * 64 + wr * 16 + lr) * C + k8);
        a1i = *(const bf16x8*)(wpk + OW1_I + (size_t)(hc * 64 + wr * 16 + lr) * C + k8);
      } else {
        const float* w1rp = w1_r + (size_t)(hc * 64 + wr * 16 + lr) * C;
        const float* w1ip = w1_i + (size_t)(hc * 64 + wr * 16 + lr) * C;
        float a[8];
        *(float4*)&a[0] = *(const float4*)(w1rp + k8);
        *(float4*)&a[4] = *(const float4*)(w1rp + k8 + 4);
        a1r = pack8(a);
        *(float4*)&a[0] = *(const float4*)(w1ip + k8);
        *(float4*)&a[4] = *(const float4*)(w1ip + k8 + 4);
        a1i = pack8(a);
      }
      const bf16x8 a1in = negb(a1i);
      #pragma unroll
      for (int cb = 0; cb < 2; ++cb) {
        const int p = (wc * 2 + cb) * 16 + lr;
        const int s = (p & 7) << 3;
        const bf16x8 br = *(const bf16x8*)&sXm[0][p * 192 + (k8 ^ s)];
        const bf16x8 bi = *(const bf16x8*)&sXm[1][p * 192 + (k8 ^ s)];
        hfr[cb] = __builtin_amdgcn_mfma_f32_16x16x32_bf16(a1r,  br, hfr[cb], 0, 0, 0);
        hfr[cb] = __builtin_amdgcn_mfma_f32_16x16x32_bf16(a1in, bi, hfr[cb], 0, 0, 0);
        hfi[cb] = __builtin_amdgcn_mfma_f32_16x16x32_bf16(a1r,  bi, hfi[cb], 0, 0, 0);
        hfi[cb] = __builtin_amdgcn_mfma_f32_16x16x32_bf16(a1i,  br, hfi[cb], 0, 0, 0);
      }
    }

    // ---- magnitude GELU (h * Phi(m)) ----
    float outr[2][4], outi[2][4];
    #pragma unroll
    for (int cb = 0; cb < 2; ++cb) {
      #pragma unroll
      for (int r = 0; r < 4; ++r) {
        const float re = hfr[cb][r], im = hfi[cb][r];
        const float m = sqrtf(re * re + im * im);
        const float f = 0.5f * (1.0f + erff(m * 0.70710678f));
        outr[cb][r] = re * f;
        outi[cb][r] = im * f;
      }
    }
    __syncthreads();   // previous chunk's GEMM2 reads complete
    #pragma unroll
    for (int cb = 0; cb < 2; ++cb) {
      const int p = (wc * 2 + cb) * 16 + lr;
      const int s = (p & 7) << 3;
      const int kb = wr * 16 + lg * 4;
      const int e = p * 64 + (kb ^ s);
      *(uint2*)&sH[0][e] = make_uint2(
          (unsigned)f2bf(outr[cb][0]) | ((unsigned)f2bf(outr[cb][1]) << 16),
          (unsigned)f2bf(outr[cb][2]) | ((unsigned)f2bf(outr[cb][3]) << 16));
      *(uint2*)&sH[1][e] = make_uint2(
          (unsigned)f2bf(outi[cb][0]) | ((unsigned)f2bf(outi[cb][1]) << 16),
          (unsigned)f2bf(outi[cb][2]) | ((unsigned)f2bf(outi[cb][3]) << 16));
    }
    __syncthreads();   // sH visible

    // ---- GEMM2: acc2 += W2[:, chunk] . Ht, K=64 ----
    #pragma unroll
    for (int ks2 = 0; ks2 < 2; ++ks2) {
      const int k8 = ks2 * 32 + lg * 8;
      bf16x8 br2[2], bi2[2];
      #pragma unroll
      for (int cb = 0; cb < 2; ++cb) {
        const int p = (wc * 2 + cb) * 16 + lr;
        const int s = (p & 7) << 3;
        br2[cb] = *(const bf16x8*)&sH[0][p * 64 + (k8 ^ s)];
        bi2[cb] = *(const bf16x8*)&sH[1][p * 64 + (k8 ^ s)];
      }
      #pragma unroll
      for (int ob = 0; ob < 3; ++ob) {
        const int row = (wr * 3 + ob) * 16 + lr;
        bf16x8 a2r, a2i;
        if constexpr (PK) {
          a2r = *(const bf16x8*)(wpk + OW2_R + (size_t)row * C4 + hc * 64 + k8);
          a2i = *(const bf16x8*)(wpk + OW2_I + (size_t)row * C4 + hc * 64 + k8);
        } else {
          const size_t wbase = (size_t)row * C4 + hc * 64 + k8;
          float a[8];
          *(float4*)&a[0] = *(const float4*)(w2_r + wbase);
          *(float4*)&a[4] = *(const float4*)(w2_r + wbase + 4);
          a2r = pack8(a);
          *(float4*)&a[0] = *(const float4*)(w2_i + wbase);
          *(float4*)&a[4] = *(const float4*)(w2_i + wbase + 4);
          a2i = pack8(a);
        }
        const bf16x8 a2in = negb(a2i);
        #pragma unroll
        for (int cb = 0; cb < 2; ++cb) {
          acc2r[ob][cb] = __builtin_amdgcn_mfma_f32_16x16x32_bf16(a2r,  br2[cb], acc2r[ob][cb], 0, 0, 0);
          acc2r[ob][cb] = __builtin_amdgcn_mfma_f32_16x16x32_bf16(a2in, bi2[cb], acc2r[ob][cb], 0, 0, 0);
          acc2i[ob][cb] = __builtin_amdgcn_mfma_f32_16x16x32_bf16(a2r,  bi2[cb], acc2i[ob][cb], 0, 0, 0);
          acc2i[ob][cb] = __builtin_amdgcn_mfma_f32_16x16x32_bf16(a2i,  br2[cb], acc2i[ob][cb], 0, 0, 0);
        }
      }
    }
  }

  // ---- epilogue: x2 = bn1(y) (from sXm, bf16) + acc2 ----
  #pragma unroll
  for (int ob = 0; ob < 3; ++ob) {
    #pragma unroll
    for (int cb = 0; cb < 2; ++cb) {
      const int pxl = (wc * 2 + cb) * 16 + lr;
      const int s = (pxl & 7) << 3;
      const int chb = (wr * 3 + ob) * 16 + lg * 4;
      const int ebase = pxl * 192 + (chb ^ s);
      const int px = p0 + pxl;
      #pragma unroll
      for (int r = 0; r < 4; ++r) {
        const int ch = chb + r;
        const size_t g = (size_t)(b * C + ch) * HW + px;
        outp[g] = bf2f(sXm[0][ebase + r]) + acc2r[ob][cb][r];
        outp[PLANE + g] = bf2f(sXm[1][ebase + r]) + acc2i[ob][cb][r];
      }
    }
  }
}

// In-place BN2 apply over d_out (both planes).
__global__ __launch_bounds__(256) void k_bnfinal(
    float* __restrict__ xo, const float* __restrict__ sc, const float* __restrict__ sh)
{
  const int total4 = (2 * PLANE) / 4;
  for (int i = blockIdx.x * blockDim.x + threadIdx.x; i < total4; i += gridDim.x * blockDim.x) {
    const int e = i * 4;
    const int plane = (e >= PLANE) ? 1 : 0;
    const int w = plane ? (e - PLANE) : e;
    const int ch = (w >> 14) % C;
    const float s = sc[plane * C + ch], hh = sh[plane * C + ch];
    float4 v = *(float4*)(xo + e);
    v.x = v.x * s + hh;
    v.y = v.y * s + hh;
    v.z = v.z * s + hh;
    v.w = v.w * s + hh;
    *(float4*)(xo + e) = v;
  }
}

}  // namespace

extern "C" void kernel_launch(void* const* d_in, const int* in_sizes, int n_in,
                              void* d_out, int out_size, void* d_ws, size_t ws_size,
                              hipStream_t stream)
{
  (void)in_sizes; (void)n_in; (void)out_size;
  const float* x_real  = (const float*)d_in[0];
  const float* x_imag  = (const float*)d_in[1];
  const float* qkv_wr  = (const float*)d_in[2];
  const float* qkv_wi  = (const float*)d_in[3];
  const float* proj_wr = (const float*)d_in[4];
  const float* proj_wi = (const float*)d_in[5];
  const float* rpb     = (const float*)d_in[6];
  const float* n1_gr   = (const float*)d_in[7];
  const float* n1_br   = (const float*)d_in[8];
  const float* n1_gi   = (const float*)d_in[9];
  const float* n1_bi   = (const float*)d_in[10];
  const float* mlp1_wr = (const float*)d_in[11];
  const float* mlp1_wi = (const float*)d_in[12];
  const float* mlp2_wr = (const float*)d_in[13];
  const float* mlp2_wi = (const float*)d_in[14];
  const float* n2_gr   = (const float*)d_in[15];
  const float* n2_br   = (const float*)d_in[16];
  const float* n2_gi   = (const float*)d_in[17];
  const float* n2_bi   = (const float*)d_in[18];

  const size_t pkBytes = (size_t)PK_TOTAL * 2;          // 1769472
  const bool pk = ws_size >= pkBytes + 3072 * 4;

  short* wpk = (short*)d_ws;
  float* st = pk ? (float*)((char*)d_ws + pkBytes) : (float*)d_ws;
  float* mean1 = st;          float* rstd1 = st + 384;
  float* sc1   = st + 768;    float* sh1   = st + 1152;
  float* mean2 = st + 1536;   float* rstd2 = st + 1920;
  float* sc2   = st + 2304;   float* sh2   = st + 2688;

  float* outp = (float*)d_out;
  float* yr = outp;
  float* yi = outp + PLANE;

  if (pk) {
    k_pack<<<1024, 256, 0, stream>>>(qkv_wr, qkv_wi, proj_wr, proj_wi,
                                     mlp1_wr, mlp1_wi, mlp2_wr, mlp2_wi, wpk);
    k_attn<true><<<1024, 768, 0, stream>>>(x_real, x_imag, qkv_wr, qkv_wi,
                                           proj_wr, proj_wi, wpk, rpb, yr, yi);
  } else {
    k_attn<false><<<1024, 768, 0, stream>>>(x_real, x_imag, qkv_wr, qkv_wi,
                                            proj_wr, proj_wi, nullptr, rpb, yr, yi);
  }
  k_stats<<<dim3(C, 2), 256, 0, stream>>>(yr, yi, mean1, rstd1);
  k_bnpar<<<2, 192, 0, stream>>>(mean1, rstd1, n1_gr, n1_br, n1_gi, n1_bi, sc1, sh1);
  if (pk) {
    k_mlp<true><<<Bn * HW / 64, 512, 0, stream>>>(outp, mlp1_wr, mlp1_wi,
                                                  mlp2_wr, mlp2_wi, wpk, sc1, sh1);
  } else {
    k_mlp<false><<<Bn * HW / 64, 512, 0, stream>>>(outp, mlp1_wr, mlp1_wi,
                                                   mlp2_wr, mlp2_wi, nullptr, sc1, sh1);
  }
  k_stats<<<dim3(C, 2), 256, 0, stream>>>(outp, outp + PLANE, mean2, rstd2);
  k_bnpar<<<2, 192, 0, stream>>>(mean2, rstd2, n2_gr, n2_br, n2_gi, n2_bi, sc2, sh2);
  k_bnfinal<<<2048, 256, 0, stream>>>(outp, sc2, sh2);
}

// Round 9
// 524.601 us; speedup vs baseline: 11.1126x; 1.2737x over previous
//
#include <hip/hip_runtime.h>

namespace {

constexpr int Bn = 4;
constexpr int C  = 192;
constexpr int Wd = 128;
constexpr int HW = 16384;            // 128*128
constexpr int PLANE = Bn * C * HW;   // 12582912
constexpr int NH = 6;
constexpr int HD = 32;
constexpr int C4 = 4 * C;            // 768
constexpr float SCALE = 0.17677669529663687f;  // 32^-0.5

// packed bf16 weight layout in d_ws (short offsets)
constexpr int OQKV_R = 0;            // 576*192
constexpr int OQKV_I = 110592;
constexpr int OPROJ_R = 221184;      // 192*192
constexpr int OPROJ_I = 258048;
constexpr int OW1_R = 294912;        // 768*192
constexpr int OW1_I = 442368;
constexpr int OW2_R = 589824;        // 192*768
constexpr int OW2_I = 737280;
constexpr int PK_TOTAL = 884736;
constexpr int ZS = 8;                // stats split factor

typedef short bf16x8 __attribute__((ext_vector_type(8)));
typedef float f32x4 __attribute__((ext_vector_type(4)));

__device__ inline unsigned short f2bf(float f) {
  union { float f; unsigned u; } v; v.f = f;
  const unsigned r = v.u + 0x7FFFu + ((v.u >> 16) & 1u);
  return (unsigned short)(r >> 16);
}

__device__ inline float bf2f(short s) {
  union { unsigned u; float f; } v;
  v.u = ((unsigned)(unsigned short)s) << 16;
  return v.f;
}

__device__ inline bf16x8 pack8(const float* f) {
  union { bf16x8 v; unsigned short s[8]; } x;
#pragma unroll
  for (int j = 0; j < 8; ++j) x.s[j] = f2bf(f[j]);
  return x.v;
}

__device__ inline uint2 pack4(const f32x4 v) {
  return make_uint2((unsigned)f2bf(v[0]) | ((unsigned)f2bf(v[1]) << 16),
                    (unsigned)f2bf(v[2]) | ((unsigned)f2bf(v[3]) << 16));
}

__device__ inline bf16x8 negb(bf16x8 a) {
  union { bf16x8 v; unsigned u[4]; } x;
  x.v = a;
#pragma unroll
  for (int j = 0; j < 4; ++j) x.u[j] ^= 0x80008000u;
  return x.v;
}

// Phi(m) = 0.5(1+erf(m/sqrt2)), m>=0. Abramowitz-Stegun 7.1.26, |err|<1.5e-7.
__device__ inline float phi_gelu(float m) {
  const float x = m * 0.70710678f;
  const float tt = 1.0f / (1.0f + 0.3275911f * x);
  const float poly = tt * (0.254829592f + tt * (-0.284496736f +
                     tt * (1.421413741f + tt * (-1.453152027f + tt * 1.061405429f))));
  return 1.0f - 0.5f * poly * __expf(-x * x);
}

// ---------------------------------------------------------------------------
// Pack all weights to bf16 into ws (one pass, ~900K elements).
// ---------------------------------------------------------------------------
__global__ __launch_bounds__(256) void k_pack(
    const float* __restrict__ s0, const float* __restrict__ s1,
    const float* __restrict__ s2, const float* __restrict__ s3,
    const float* __restrict__ s4, const float* __restrict__ s5,
    const float* __restrict__ s6, const float* __restrict__ s7,
    short* __restrict__ dst)
{
  for (int i = blockIdx.x * 256 + threadIdx.x; i < PK_TOTAL; i += gridDim.x * 256) {
    const float* s; int off;
    if (i < OPROJ_R) {
      if (i < OQKV_I) { s = s0; off = i; } else { s = s1; off = i - OQKV_I; }
    } else if (i < OW1_R) {
      if (i < OPROJ_I) { s = s2; off = i - OPROJ_R; } else { s = s3; off = i - OPROJ_I; }
    } else if (i < OW2_R) {
      if (i < OW1_I) { s = s4; off = i - OW1_R; } else { s = s5; off = i - OW1_I; }
    } else {
      if (i < OW2_I) { s = s6; off = i - OW2_R; } else { s = s7; off = i - OW2_I; }
    }
    dst[i] = (short)f2bf(s[off]);
  }
}

// ---------------------------------------------------------------------------
// Stage 1 (MFMA): windowed complex attention + proj + residual -> y in d_out.
// Block = 2 windows (64 px), 768 threads (12 waves). (unchanged from R7/R8)
// ---------------------------------------------------------------------------
template <bool PK>
__global__ __launch_bounds__(768) void k_attn(
    const float* __restrict__ xr, const float* __restrict__ xi,
    const float* __restrict__ wqkv_r, const float* __restrict__ wqkv_i,
    const float* __restrict__ wp_r, const float* __restrict__ wp_i,
    const short* __restrict__ wpk,
    const float* __restrict__ rpb,
    float* __restrict__ yr, float* __restrict__ yi)
{
  __shared__ short sX[2][64 * 192];   // x window bf16 [px][c^s]
  __shared__ short sQ[2][64 * 64];    // q head-pair [px][cc^s]
  __shared__ short sK[2][64 * 64];    // k head-pair [px][cc^s]
  __shared__ short sV[2][64 * 64];    // v head-pair [cc][px^s]
  __shared__ short sAO[2][64 * 64];   // attn-out head-pair [px][cc^s]
  __shared__ short sAT[2][4][1024];   // attn weights per task [n][m^s]
  __shared__ float sB[640];           // rpb table

  const int t = threadIdx.x;
  const int b = blockIdx.x >> 8;
  const int rem = blockIdx.x & 255;
  const int r0 = (rem >> 4) << 3;
  const int c0 = (rem & 15) << 3;     // two 4-wide windows: c0, c0+4
  const int gbase = b * C * HW + r0 * Wd + c0;

  #pragma unroll
  for (int it = 0; it < 4; ++it) {
    const int idx = t + it * 768;          // 0..3071
    const int c = idx >> 4;
    const int q4 = (idx & 15) << 2;        // px base, mult of 4
    const int wvs = q4 >> 5;
    const int row = (q4 & 31) >> 2;
    const int goff = gbase + c * HW + row * Wd + wvs * 4;
    const float4 vr = *(const float4*)(xr + goff);
    const float4 vi = *(const float4*)(xi + goff);
    const float fr[4] = {vr.x, vr.y, vr.z, vr.w};
    const float fi[4] = {vi.x, vi.y, vi.z, vi.w};
    #pragma unroll
    for (int j = 0; j < 4; ++j) {
      const int p = q4 + j;
      const int s = (p & 7) << 3;
      sX[0][p * 192 + (c ^ s)] = (short)f2bf(fr[j]);
      sX[1][p * 192 + (c ^ s)] = (short)f2bf(fi[j]);
    }
  }
  for (int i = t; i < 630; i += 768) sB[i] = rpb[i];
  __syncthreads();

  const int lane = t & 63;
  const int w = t >> 6;           // 0..11
  const int lr = lane & 15;
  const int lg = lane >> 4;

  f32x4 apr[4] = {}, api[4] = {};   // proj accumulators (persist; rows w*16)

  for (int g = 0; g < 3; ++g) {
    // ======== QKV GEMM: 192 rows (q64,k64,v64 of head pair) x 64 px ========
    {
      const int lrow = w * 16;             // 0..176
      const int sec = lrow >> 6;           // 0=q 1=k 2=v
      const int ccb = lrow & 63;
      const int R = sec * 192 + g * 64 + ccb + lr;
      f32x4 dr[4] = {}, di[4] = {};
      #pragma unroll
      for (int ks = 0; ks < 6; ++ks) {
        const int k8 = ks * 32 + lg * 8;
        bf16x8 ar, ai;
        if constexpr (PK) {
          ar = *(const bf16x8*)(wpk + OQKV_R + (size_t)R * C + k8);
          ai = *(const bf16x8*)(wpk + OQKV_I + (size_t)R * C + k8);
        } else {
          const float* wrp = wqkv_r + (size_t)R * C;
          const float* wip = wqkv_i + (size_t)R * C;
          float a[8];
          *(float4*)&a[0] = *(const float4*)(wrp + k8);
          *(float4*)&a[4] = *(const float4*)(wrp + k8 + 4);
          ar = pack8(a);
          *(float4*)&a[0] = *(const float4*)(wip + k8);
          *(float4*)&a[4] = *(const float4*)(wip + k8 + 4);
          ai = pack8(a);
        }
        const bf16x8 ain = negb(ai);
        #pragma unroll
        for (int cb = 0; cb < 4; ++cb) {
          const int px = cb * 16 + lr;
          const int s = (px & 7) << 3;
          const bf16x8 br = *(const bf16x8*)&sX[0][px * 192 + (k8 ^ s)];
          const bf16x8 bi = *(const bf16x8*)&sX[1][px * 192 + (k8 ^ s)];
          dr[cb] = __builtin_amdgcn_mfma_f32_16x16x32_bf16(ar,  br, dr[cb], 0, 0, 0);
          dr[cb] = __builtin_amdgcn_mfma_f32_16x16x32_bf16(ain, bi, dr[cb], 0, 0, 0);
          di[cb] = __builtin_amdgcn_mfma_f32_16x16x32_bf16(ar,  bi, di[cb], 0, 0, 0);
          di[cb] = __builtin_amdgcn_mfma_f32_16x16x32_bf16(ai,  br, di[cb], 0, 0, 0);
        }
      }
      if (sec < 2) {
        short* d0 = sec ? sK[0] : sQ[0];
        short* d1 = sec ? sK[1] : sQ[1];
        #pragma unroll
        for (int cb = 0; cb < 4; ++cb) {
          const int px = cb * 16 + lr;
          const int e = px * 64 + ((ccb + lg * 4) ^ ((px & 7) << 3));
          *(uint2*)&d0[e] = pack4(dr[cb]);
          *(uint2*)&d1[e] = pack4(di[cb]);
        }
      } else {
        #pragma unroll
        for (int cb = 0; cb < 4; ++cb) {
          const int px = cb * 16 + lr;
          #pragma unroll
          for (int r = 0; r < 4; ++r) {
            const int dd = ccb + lg * 4 + r;
            const int e = dd * 64 + (px ^ ((dd & 7) << 3));
            sV[0][e] = (short)f2bf(dr[cb][r]);
            sV[1][e] = (short)f2bf(di[cb][r]);
          }
        }
      }
    }
    __syncthreads();   // bar A: qkv visible

    // ======== attention: waves 0..7 = (task, half); waves 8..11 idle ========
    if (w < 8) {
      const int task = w >> 1;
      const int half = w & 1;
      const int hloc = task >> 1;
      const int wv = task & 1;
      const int ccq = hloc * 32;
      const int h = 2 * g + hloc;
      bf16x8 aqr, aqi, bkr[2], bki[2];
      {
        const int pxq = wv * 32 + half * 16 + lr;
        const int eq = pxq * 64 + ((ccq + lg * 8) ^ ((pxq & 7) << 3));
        aqr = *(const bf16x8*)&sQ[0][eq];
        aqi = *(const bf16x8*)&sQ[1][eq];
      }
      #pragma unroll
      for (int j = 0; j < 2; ++j) {
        const int pxk = wv * 32 + j * 16 + lr;
        const int ek = pxk * 64 + ((ccq + lg * 8) ^ ((pxk & 7) << 3));
        bkr[j] = *(const bf16x8*)&sK[0][ek];
        bki[j] = *(const bf16x8*)&sK[1][ek];
      }
      f32x4 sre[2], sim[2];
      #pragma unroll
      for (int j = 0; j < 2; ++j) {
        f32x4 z = {};
        f32x4 re = __builtin_amdgcn_mfma_f32_16x16x32_bf16(aqr, bkr[j], z, 0, 0, 0);
        re = __builtin_amdgcn_mfma_f32_16x16x32_bf16(aqi, bki[j], re, 0, 0, 0);
        f32x4 im = __builtin_amdgcn_mfma_f32_16x16x32_bf16(aqi, bkr[j], z, 0, 0, 0);
        im = __builtin_amdgcn_mfma_f32_16x16x32_bf16(negb(aqr), bki[j], im, 0, 0, 0);
        sre[j] = re;
        sim[j] = im;
      }
      float re_[2][4], im_[2][4], mg_[2][4];
      #pragma unroll
      for (int j = 0; j < 2; ++j) {
        const int m = j * 16 + lr;
        #pragma unroll
        for (int r = 0; r < 4; ++r) {
          const int n = half * 16 + lg * 4 + r;
          const int bidx = ((n >> 2) - (m >> 2) + 7) * 7 + ((n & 3) - (m & 3) + 3);
          const float re = sre[j][r] * SCALE + sB[bidx * NH + h];
          const float im = sim[j][r] * SCALE;
          re_[j][r] = re;
          im_[j][r] = im;
          mg_[j][r] = sqrtf(re * re + im * im);
        }
      }
      #pragma unroll
      for (int r = 0; r < 4; ++r) {
        float mx = fmaxf(mg_[0][r], mg_[1][r]);
        mx = fmaxf(mx, __shfl_xor(mx, 1));
        mx = fmaxf(mx, __shfl_xor(mx, 2));
        mx = fmaxf(mx, __shfl_xor(mx, 4));
        mx = fmaxf(mx, __shfl_xor(mx, 8));
        const float e0 = expf(mg_[0][r] - mx);
        const float e1 = expf(mg_[1][r] - mx);
        float se = e0 + e1;
        se += __shfl_xor(se, 1);
        se += __shfl_xor(se, 2);
        se += __shfl_xor(se, 4);
        se += __shfl_xor(se, 8);
        const float inv = 1.f / se;
        const float f0 = e0 * inv / (mg_[0][r] + 1e-8f);
        const float f1 = e1 * inv / (mg_[1][r] + 1e-8f);
        const int n = half * 16 + lg * 4 + r;
        const int sw = (n & 3) << 3;
        sAT[0][task][n * 32 + (lr ^ sw)]        = (short)f2bf(re_[0][r] * f0);
        sAT[1][task][n * 32 + (lr ^ sw)]        = (short)f2bf(im_[0][r] * f0);
        sAT[0][task][n * 32 + ((16 + lr) ^ sw)] = (short)f2bf(re_[1][r] * f1);
        sAT[1][task][n * 32 + ((16 + lr) ^ sw)] = (short)f2bf(im_[1][r] * f1);
      }
      bf16x8 bar_, bai_;
      {
        const int n = half * 16 + lr;
        const int e = n * 32 + ((lg * 8) ^ ((n & 3) << 3));
        bar_ = *(const bf16x8*)&sAT[0][task][e];
        bai_ = *(const bf16x8*)&sAT[1][task][e];
      }
      #pragma unroll
      for (int i2 = 0; i2 < 2; ++i2) {
        const int dd = ccq + i2 * 16 + lr;
        const int e = dd * 64 + ((wv * 32 + lg * 8) ^ ((dd & 7) << 3));
        const bf16x8 avr = *(const bf16x8*)&sV[0][e];
        const bf16x8 avi = *(const bf16x8*)&sV[1][e];
        const bf16x8 avin = negb(avi);
        f32x4 z = {};
        f32x4 pr = __builtin_amdgcn_mfma_f32_16x16x32_bf16(avr, bar_, z, 0, 0, 0);
        pr = __builtin_amdgcn_mfma_f32_16x16x32_bf16(avin, bai_, pr, 0, 0, 0);
        f32x4 pi = __builtin_amdgcn_mfma_f32_16x16x32_bf16(avr, bai_, z, 0, 0, 0);
        pi = __builtin_amdgcn_mfma_f32_16x16x32_bf16(avi, bar_, pi, 0, 0, 0);
        const int px = wv * 32 + half * 16 + lr;
        const int e2 = px * 64 + ((ccq + i2 * 16 + lg * 4) ^ ((px & 7) << 3));
        *(uint2*)&sAO[0][e2] = pack4(pr);
        *(uint2*)&sAO[1][e2] = pack4(pi);
      }
    }

    // prefetch proj A-frags so their latency lands in bar B's drain (PK path)
    const int o = w * 16 + lr;
    bf16x8 ppr[2], ppi[2];
    if constexpr (PK) {
      #pragma unroll
      for (int ks = 0; ks < 2; ++ks) {
        const int k8 = ks * 32 + lg * 8;
        ppr[ks] = *(const bf16x8*)(wpk + OPROJ_R + (size_t)o * C + g * 64 + k8);
        ppi[ks] = *(const bf16x8*)(wpk + OPROJ_I + (size_t)o * C + g * 64 + k8);
      }
    }
    __syncthreads();   // bar B: attn-out visible

    // ======== proj accumulation: K = 64 (head pair), rows w*16 ========
    #pragma unroll
    for (int ks = 0; ks < 2; ++ks) {
      const int k8 = ks * 32 + lg * 8;
      bf16x8 pbr[4], pbi[4];
      #pragma unroll
      for (int cb = 0; cb < 4; ++cb) {
        const int px = cb * 16 + lr;
        const int e = px * 64 + (k8 ^ ((px & 7) << 3));
        pbr[cb] = *(const bf16x8*)&sAO[0][e];
        pbi[cb] = *(const bf16x8*)&sAO[1][e];
      }
      bf16x8 ar, ai;
      if constexpr (PK) {
        ar = ppr[ks];
        ai = ppi[ks];
      } else {
        const size_t wb = (size_t)o * C + g * 64 + k8;
        float a[8];
        *(float4*)&a[0] = *(const float4*)(wp_r + wb);
        *(float4*)&a[4] = *(const float4*)(wp_r + wb + 4);
        ar = pack8(a);
        *(float4*)&a[0] = *(const float4*)(wp_i + wb);
        *(float4*)&a[4] = *(const float4*)(wp_i + wb + 4);
        ai = pack8(a);
      }
      const bf16x8 ain = negb(ai);
      #pragma unroll
      for (int cb = 0; cb < 4; ++cb) {
        apr[cb] = __builtin_amdgcn_mfma_f32_16x16x32_bf16(ar,  pbr[cb], apr[cb], 0, 0, 0);
        apr[cb] = __builtin_amdgcn_mfma_f32_16x16x32_bf16(ain, pbi[cb], apr[cb], 0, 0, 0);
        api[cb] = __builtin_amdgcn_mfma_f32_16x16x32_bf16(ar,  pbi[cb], api[cb], 0, 0, 0);
        api[cb] = __builtin_amdgcn_mfma_f32_16x16x32_bf16(ai,  pbr[cb], api[cb], 0, 0, 0);
      }
    }
  }

  // ======== epilogue: y = x + proj_out (residual from sX, bf16) ========
  #pragma unroll
  for (int cb = 0; cb < 4; ++cb) {
    const int px = cb * 16 + lr;
    const int n = px & 31;
    const int off0 = gbase + (n >> 2) * Wd + (px >> 5) * 4 + (n & 3);
    const int s = (px & 7) << 3;
    #pragma unroll
    for (int r = 0; r < 4; ++r) {
      const int c = w * 16 + lg * 4 + r;
      const size_t gg = (size_t)off0 + (size_t)c * HW;
      yr[gg] = bf2f(sX[0][px * 192 + (c ^ s)]) + apr[cb][r];
      yi[gg] = bf2f(sX[1][px * 192 + (c ^ s)]) + api[cb][r];
    }
  }
}

// ---------------------------------------------------------------------------
// Split BN stats: grid (C, 2, ZS). Deterministic partials (no atomics).
// ---------------------------------------------------------------------------
__global__ __launch_bounds__(256) void k_statsp(
    const float* __restrict__ src_r, const float* __restrict__ src_i,
    double* __restrict__ part)
{
  const int c = blockIdx.x;
  const int plane = blockIdx.y;
  const int z = blockIdx.z;
  const float* src = plane ? src_i : src_r;
  const int t = threadIdx.x;
  double s = 0.0, s2 = 0.0;
  for (int b = 0; b < Bn; ++b) {
    const float* p = src + (size_t)(b * C + c) * HW + (size_t)z * (HW / ZS);
    #pragma unroll
    for (int it = 0; it < 2; ++it) {
      const float4 v = *(const float4*)(p + t * 4 + it * 1024);
      s += (double)v.x + (double)v.y + (double)v.z + (double)v.w;
      s2 += (double)v.x * v.x + (double)v.y * v.y +
            (double)v.z * v.z + (double)v.w * v.w;
    }
  }
  __shared__ double ls[256], ls2[256];
  ls[t] = s; ls2[t] = s2;
  __syncthreads();
  for (int off = 128; off > 0; off >>= 1) {
    if (t < off) { ls[t] += ls[t + off]; ls2[t] += ls2[t + off]; }
    __syncthreads();
  }
  if (t == 0) {
    const int e = ((z * 2 + plane) * C + c) * 2;
    part[e] = ls[0];
    part[e + 1] = ls2[0];
  }
}

// Reduce partials -> folded BN scale/shift. grid 2 x 192.
__global__ void k_bnpar2(const double* __restrict__ part,
                         const float* __restrict__ g_r, const float* __restrict__ b_r,
                         const float* __restrict__ g_i, const float* __restrict__ b_i,
                         float* __restrict__ sc, float* __restrict__ sh)
{
  const int plane = blockIdx.x;
  const int c = threadIdx.x;
  double s = 0.0, s2 = 0.0;
  #pragma unroll
  for (int z = 0; z < ZS; ++z) {
    const int e = ((z * 2 + plane) * C + c) * 2;
    s += part[e];
    s2 += part[e + 1];
  }
  const double inv = 1.0 / (double)(Bn * HW);
  const double m = s * inv;
  const double var = s2 * inv - m * m;
  const double rstd = 1.0 / sqrt(var + 1e-5);
  const float g = plane ? g_i[c] : g_r[c];
  const float bb = plane ? b_i[c] : b_r[c];
  const float sf = (float)(rstd) * g;
  sc[plane * C + c] = sf;
  sh[plane * C + c] = bb - (float)m * sf;
}

// ---------------------------------------------------------------------------
// Legacy monolithic stats (fallback when ws too small for partials).
// ---------------------------------------------------------------------------
__global__ __launch_bounds__(256) void k_stats(
    const float* __restrict__ src_r, const float* __restrict__ src_i,
    float* __restrict__ mean, float* __restrict__ rstd)
{
  const int c = blockIdx.x;
  const int plane = blockIdx.y;
  const float* src = plane ? src_i : src_r;
  const int t = threadIdx.x;
  double s = 0.0, s2 = 0.0;
  for (int b = 0; b < Bn; ++b) {
    const float* p = src + (size_t)(b * C + c) * HW;
    for (int i = t; i < HW; i += 256) {
      const double v = (double)p[i];
      s += v;
      s2 += v * v;
    }
  }
  __shared__ double ls[256], ls2[256];
  ls[t] = s; ls2[t] = s2;
  __syncthreads();
  for (int off = 128; off > 0; off >>= 1) {
    if (t < off) { ls[t] += ls[t + off]; ls2[t] += ls2[t + off]; }
    __syncthreads();
  }
  if (t == 0) {
    const double inv = 1.0 / (double)(Bn * HW);
    const double m = ls[0] * inv;
    const double var = ls2[0] * inv - m * m;
    mean[plane * C + c] = (float)m;
    rstd[plane * C + c] = (float)(1.0 / sqrt(var + 1e-5));
  }
}

__global__ void k_bnpar(const float* __restrict__ mean, const float* __restrict__ rstd,
                        const float* __restrict__ g_r, const float* __restrict__ b_r,
                        const float* __restrict__ g_i, const float* __restrict__ b_i,
                        float* __restrict__ sc, float* __restrict__ sh)
{
  const int i = blockIdx.x * blockDim.x + threadIdx.x;
  if (i >= 2 * C) return;
  const int plane = i / C, c = i % C;
  const float g = plane ? g_i[c] : g_r[c];
  const float bb = plane ? b_i[c] : b_r[c];
  const float s = rstd[i] * g;
  sc[i] = s;
  sh[i] = bb - mean[i] * s;
}

// ---------------------------------------------------------------------------
// Fused MFMA MLP v3: 128 px/block (512 blocks), 512 threads (8 waves),
// 128 KB LDS (1 block/CU, 2 waves/SIMD). Per pixel: half the barriers and
// half the weight passes of the 64-px version; 2x MFMA burst per wave.
// ---------------------------------------------------------------------------
template <bool PK>
__global__ __launch_bounds__(512) void k_mlp(
    float* __restrict__ outp,
    const float* __restrict__ w1_r, const float* __restrict__ w1_i,
    const float* __restrict__ w2_r, const float* __restrict__ w2_i,
    const short* __restrict__ wpk,
    const float* __restrict__ sc1, const float* __restrict__ sh1)
{
  __shared__ short sXm[2][128 * 192];  // 96 KB
  __shared__ short sH[2][128 * 64];    // 32 KB

  const int t = threadIdx.x;
  const int pix0 = blockIdx.x * 128;
  const int b = pix0 >> 14;
  const int p0 = pix0 & (HW - 1);
  const float* yrp = outp;
  const float* yip = outp + PLANE;

  // stage bn1(y) tile: 192 c x 32 quads = 6144 float4-pairs
  #pragma unroll
  for (int it = 0; it < 12; ++it) {
    const int idx = t + it * 512;
    const int c = idx >> 5;
    const int q = (idx & 31) << 2;
    const size_t g = (size_t)(b * C + c) * HW + p0 + q;
    const float4 vr = *(const float4*)(yrp + g);
    const float4 vi = *(const float4*)(yip + g);
    const float srr = sc1[c], hrr = sh1[c];
    const float sii = sc1[C + c], hii = sh1[C + c];
    const float fr[4] = {vr.x * srr + hrr, vr.y * srr + hrr, vr.z * srr + hrr, vr.w * srr + hrr};
    const float fi[4] = {vi.x * sii + hii, vi.y * sii + hii, vi.z * sii + hii, vi.w * sii + hii};
    #pragma unroll
    for (int i2 = 0; i2 < 4; ++i2) {
      const int p = q + i2;
      const int s = (p & 7) << 3;
      sXm[0][p * 192 + (c ^ s)] = (short)f2bf(fr[i2]);
      sXm[1][p * 192 + (c ^ s)] = (short)f2bf(fi[i2]);
    }
  }
  __syncthreads();

  const int lane = t & 63;
  const int w = t >> 6;         // 0..7
  const int lr = lane & 15;
  const int lg = lane >> 4;
  const int wr = w >> 1;        // 0..3 row tiles
  const int wc = w & 1;         // 0..1 px half (64 px each)

  f32x4 acc2r[3][4] = {};
  f32x4 acc2i[3][4] = {};

  for (int hc = 0; hc < 12; ++hc) {
    // ---- GEMM1: h rows [hc*64 + wr*16, +16) x 64 px (wc half), K=192 ----
    f32x4 hfr[4] = {}, hfi[4] = {};
    #pragma unroll
    for (int ks = 0; ks < 6; ++ks) {
      const int k8 = ks * 32 + lg * 8;
      bf16x8 a1r, a1i;
      if constexpr (PK) {
        a1r = *(const bf16x8*)(wpk + OW1_R + (size_t)(hc * 64 + wr * 16 + lr) * C + k8);
        a1i = *(const bf16x8*)(wpk + OW1_I + (size_t)(hc * 64 + wr * 16 + lr) * C + k8);
      } else {
        const float* w1rp = w1_r + (size_t)(hc * 64 + wr * 16 + lr) * C;
        const float* w1ip = w1_i + (size_t)(hc * 64 + wr * 16 + lr) * C;
        float a[8];
        *(float4*)&a[0] = *(const float4*)(w1rp + k8);
        *(float4*)&a[4] = *(const float4*)(w1rp + k8 + 4);
        a1r = pack8(a);
        *(float4*)&a[0] = *(const float4*)(w1ip + k8);
        *(float4*)&a[4] = *(const float4*)(w1ip + k8 + 4);
        a1i = pack8(a);
      }
      const bf16x8 a1in = negb(a1i);
      #pragma unroll
      for (int cb = 0; cb < 4; ++cb) {
        const int p = wc * 64 + cb * 16 + lr;
        const int s = (p & 7) << 3;
        const bf16x8 br = *(const bf16x8*)&sXm[0][p * 192 + (k8 ^ s)];
        const bf16x8 bi = *(const bf16x8*)&sXm[1][p * 192 + (k8 ^ s)];
        hfr[cb] = __builtin_amdgcn_mfma_f32_16x16x32_bf16(a1r,  br, hfr[cb], 0, 0, 0);
        hfr[cb] = __builtin_amdgcn_mfma_f32_16x16x32_bf16(a1in, bi, hfr[cb], 0, 0, 0);
        hfi[cb] = __builtin_amdgcn_mfma_f32_16x16x32_bf16(a1r,  bi, hfi[cb], 0, 0, 0);
        hfi[cb] = __builtin_amdgcn_mfma_f32_16x16x32_bf16(a1i,  br, hfi[cb], 0, 0, 0);
      }
    }

    // ---- magnitude GELU (h * Phi(m), fast poly) ----
    float outr[4][4], outi[4][4];
    #pragma unroll
    for (int cb = 0; cb < 4; ++cb) {
      #pragma unroll
      for (int r = 0; r < 4; ++r) {
        const float re = hfr[cb][r], im = hfi[cb][r];
        const float f = phi_gelu(sqrtf(re * re + im * im));
        outr[cb][r] = re * f;
        outi[cb][r] = im * f;
      }
    }
    __syncthreads();   // previous chunk's GEMM2 reads complete
    #pragma unroll
    for (int cb = 0; cb < 4; ++cb) {
      const int p = wc * 64 + cb * 16 + lr;
      const int s = (p & 7) << 3;
      const int kb = wr * 16 + lg * 4;
      const int e = p * 64 + (kb ^ s);
      *(uint2*)&sH[0][e] = make_uint2(
          (unsigned)f2bf(outr[cb][0]) | ((unsigned)f2bf(outr[cb][1]) << 16),
          (unsigned)f2bf(outr[cb][2]) | ((unsigned)f2bf(outr[cb][3]) << 16));
      *(uint2*)&sH[1][e] = make_uint2(
          (unsigned)f2bf(outi[cb][0]) | ((unsigned)f2bf(outi[cb][1]) << 16),
          (unsigned)f2bf(outi[cb][2]) | ((unsigned)f2bf(outi[cb][3]) << 16));
    }
    __syncthreads();   // sH visible

    // ---- GEMM2: acc2 += W2[:, chunk] . Ht, K=64 ----
    #pragma unroll
    for (int ks2 = 0; ks2 < 2; ++ks2) {
      const int k8 = ks2 * 32 + lg * 8;
      bf16x8 br2[4], bi2[4];
      #pragma unroll
      for (int cb = 0; cb < 4; ++cb) {
        const int p = wc * 64 + cb * 16 + lr;
        const int s = (p & 7) << 3;
        br2[cb] = *(const bf16x8*)&sH[0][p * 64 + (k8 ^ s)];
        bi2[cb] = *(const bf16x8*)&sH[1][p * 64 + (k8 ^ s)];
      }
      #pragma unroll
      for (int ob = 0; ob < 3; ++ob) {
        const int row = (wr * 3 + ob) * 16 + lr;
        bf16x8 a2r, a2i;
        if constexpr (PK) {
          a2r = *(const bf16x8*)(wpk + OW2_R + (size_t)row * C4 + hc * 64 + k8);
          a2i = *(const bf16x8*)(wpk + OW2_I + (size_t)row * C4 + hc * 64 + k8);
        } else {
          const size_t wbase = (size_t)row * C4 + hc * 64 + k8;
          float a[8];
          *(float4*)&a[0] = *(const float4*)(w2_r + wbase);
          *(float4*)&a[4] = *(const float4*)(w2_r + wbase + 4);
          a2r = pack8(a);
          *(float4*)&a[0] = *(const float4*)(w2_i + wbase);
          *(float4*)&a[4] = *(const float4*)(w2_i + wbase + 4);
          a2i = pack8(a);
        }
        const bf16x8 a2in = negb(a2i);
        #pragma unroll
        for (int cb = 0; cb < 4; ++cb) {
          acc2r[ob][cb] = __builtin_amdgcn_mfma_f32_16x16x32_bf16(a2r,  br2[cb], acc2r[ob][cb], 0, 0, 0);
          acc2r[ob][cb] = __builtin_amdgcn_mfma_f32_16x16x32_bf16(a2in, bi2[cb], acc2r[ob][cb], 0, 0, 0);
          acc2i[ob][cb] = __builtin_amdgcn_mfma_f32_16x16x32_bf16(a2r,  bi2[cb], acc2i[ob][cb], 0, 0, 0);
          acc2i[ob][cb] = __builtin_amdgcn_mfma_f32_16x16x32_bf16(a2i,  br2[cb], acc2i[ob][cb], 0, 0, 0);
        }
      }
    }
  }

  // ---- epilogue: x2 = bn1(y) (from sXm, bf16) + acc2 ----
  #pragma unroll
  for (int ob = 0; ob < 3; ++ob) {
    #pragma unroll
    for (int cb = 0; cb < 4; ++cb) {
      const int pxl = wc * 64 + cb * 16 + lr;
      const int s = (pxl & 7) << 3;
      const int chb = (wr * 3 + ob) * 16 + lg * 4;
      const int ebase = pxl * 192 + (chb ^ s);
      const int px = p0 + pxl;
      #pragma unroll
      for (int r = 0; r < 4; ++r) {
        const int ch = chb + r;
        const size_t g = (size_t)(b * C + ch) * HW + px;
        outp[g] = bf2f(sXm[0][ebase + r]) + acc2r[ob][cb][r];
        outp[PLANE + g] = bf2f(sXm[1][ebase + r]) + acc2i[ob][cb][r];
      }
    }
  }
}

// In-place BN2 apply over d_out (both planes).
__global__ __launch_bounds__(256) void k_bnfinal(
    float* __restrict__ xo, const float* __restrict__ sc, const float* __restrict__ sh)
{
  const int total4 = (2 * PLANE) / 4;
  for (int i = blockIdx.x * blockDim.x + threadIdx.x; i < total4; i += gridDim.x * blockDim.x) {
    const int e = i * 4;
    const int plane = (e >= PLANE) ? 1 : 0;
    const int w = plane ? (e - PLANE) : e;
    const int ch = (w >> 14) % C;
    const float s = sc[plane * C + ch], hh = sh[plane * C + ch];
    float4 v = *(float4*)(xo + e);
    v.x = v.x * s + hh;
    v.y = v.y * s + hh;
    v.z = v.z * s + hh;
    v.w = v.w * s + hh;
    *(float4*)(xo + e) = v;
  }
}

}  // namespace

extern "C" void kernel_launch(void* const* d_in, const int* in_sizes, int n_in,
                              void* d_out, int out_size, void* d_ws, size_t ws_size,
                              hipStream_t stream)
{
  (void)in_sizes; (void)n_in; (void)out_size;
  const float* x_real  = (const float*)d_in[0];
  const float* x_imag  = (const float*)d_in[1];
  const float* qkv_wr  = (const float*)d_in[2];
  const float* qkv_wi  = (const float*)d_in[3];
  const float* proj_wr = (const float*)d_in[4];
  const float* proj_wi = (const float*)d_in[5];
  const float* rpb     = (const float*)d_in[6];
  const float* n1_gr   = (const float*)d_in[7];
  const float* n1_br   = (const float*)d_in[8];
  const float* n1_gi   = (const float*)d_in[9];
  const float* n1_bi   = (const float*)d_in[10];
  const float* mlp1_wr = (const float*)d_in[11];
  const float* mlp1_wi = (const float*)d_in[12];
  const float* mlp2_wr = (const float*)d_in[13];
  const float* mlp2_wi = (const float*)d_in[14];
  const float* n2_gr   = (const float*)d_in[15];
  const float* n2_br   = (const float*)d_in[16];
  const float* n2_gi   = (const float*)d_in[17];
  const float* n2_bi   = (const float*)d_in[18];

  const size_t pkBytes = (size_t)PK_TOTAL * 2;               // 1769472
  const size_t partBytes = (size_t)ZS * 2 * C * 2 * 8;       // 49152
  const bool pk = ws_size >= pkBytes + partBytes + 8192;

  float* outp = (float*)d_out;
  float* yr = outp;
  float* yi = outp + PLANE;

  if (pk) {
    short* wpk = (short*)d_ws;
    double* part = (double*)((char*)d_ws + pkBytes);
    float* st = (float*)((char*)d_ws + pkBytes + partBytes);
    float* sc1 = st;        float* sh1 = st + 384;
    float* sc2 = st + 768;  float* sh2 = st + 1152;

    k_pack<<<1024, 256, 0, stream>>>(qkv_wr, qkv_wi, proj_wr, proj_wi,
                                     mlp1_wr, mlp1_wi, mlp2_wr, mlp2_wi, wpk);
    k_attn<true><<<1024, 768, 0, stream>>>(x_real, x_imag, qkv_wr, qkv_wi,
                                           proj_wr, proj_wi, wpk, rpb, yr, yi);
    k_statsp<<<dim3(C, 2, ZS), 256, 0, stream>>>(yr, yi, part);
    k_bnpar2<<<2, 192, 0, stream>>>(part, n1_gr, n1_br, n1_gi, n1_bi, sc1, sh1);
    k_mlp<true><<<Bn * HW / 128, 512, 0, stream>>>(outp, mlp1_wr, mlp1_wi,
                                                   mlp2_wr, mlp2_wi, wpk, sc1, sh1);
    k_statsp<<<dim3(C, 2, ZS), 256, 0, stream>>>(outp, outp + PLANE, part);
    k_bnpar2<<<2, 192, 0, stream>>>(part, n2_gr, n2_br, n2_gi, n2_bi, sc2, sh2);
    k_bnfinal<<<2048, 256, 0, stream>>>(outp, sc2, sh2);
  } else {
    float* st = (float*)d_ws;
    float* mean1 = st;          float* rstd1 = st + 384;
    float* sc1   = st + 768;    float* sh1   = st + 1152;
    float* mean2 = st + 1536;   float* rstd2 = st + 1920;
    float* sc2   = st + 2304;   float* sh2   = st + 2688;

    k_attn<false><<<1024, 768, 0, stream>>>(x_real, x_imag, qkv_wr, qkv_wi,
                                            proj_wr, proj_wi, nullptr, rpb, yr, yi);
    k_stats<<<dim3(C, 2), 256, 0, stream>>>(yr, yi, mean1, rstd1);
    k_bnpar<<<2, 192, 0, stream>>>(mean1, rstd1, n1_gr, n1_br, n1_gi, n1_bi, sc1, sh1);
    k_mlp<false><<<Bn * HW / 128, 512, 0, stream>>>(outp, mlp1_wr, mlp1_wi,
                                                    mlp2_wr, mlp2_wi, nullptr, sc1, sh1);
    k_stats<<<dim3(C, 2), 256, 0, stream>>>(outp, outp + PLANE, mean2, rstd2);
    k_bnpar<<<2, 192, 0, stream>>>(mean2, rstd2, n2_gr, n2_br, n2_gi, n2_bi, sc2, sh2);
    k_bnfinal<<<2048, 256, 0, stream>>>(outp, sc2, sh2);
  }
}